// Round 18
// baseline (770.556 us; speedup 1.0000x reference)
//
#include <hip/hip_runtime.h>

#define LEAKY(v) ((v) >= 0.f ? (v) : 0.2f*(v))

static const int B_ = 16;
static const int N_ = 1024;
static const int P_ = 16384;   // B*N
static const int KNN = 20;

typedef __attribute__((ext_vector_type(8))) short short8v;
typedef __attribute__((ext_vector_type(4))) float f32x4;

__device__ inline ushort f2bf(float f) {
    unsigned u = __float_as_uint(f);
    unsigned r = u + 0x7FFFu + ((u >> 16) & 1u);
    return (ushort)(r >> 16);
}
__device__ inline float bf2f(ushort h) {
    return __uint_as_float(((unsigned)h) << 16);
}

// ---------------- prep: W2 = [wA ; wB - wA] fp32 (layer-1 only) -------------
__global__ void prep_w2(const float* __restrict__ w, float* __restrict__ W2, int O, int C) {
    int i = blockIdx.x * 256 + threadIdx.x;
    int total = 2 * O * C;
    if (i < total) {
        int row = i / C, c = i % C;
        float val;
        if (row < O) val = w[row * 2 * C + c];
        else { int o = row - O; val = w[o * 2 * C + C + c] - w[o * 2 * C + c]; }
        W2[i] = val;
    }
}

// ---------------- prep W2 and split to bf16 [h|l|h] in one pass (L>=1) ------
__global__ void prep_w2_split(const float* __restrict__ w, ushort* __restrict__ WB2, int O, int C) {
    int i = blockIdx.x * 256 + threadIdx.x;
    int cpr = C >> 2;
    if (i >= 2 * O * cpr) return;
    int row = i / cpr, c4 = (i % cpr) * 4;
    float vv[4];
    #pragma unroll
    for (int j = 0; j < 4; j++) {
        int c = c4 + j;
        if (row < O) vv[j] = w[row * 2 * C + c];
        else { int o = row - O; vv[j] = w[o * 2 * C + C + c] - w[o * 2 * C + c]; }
    }
    ushort4 h, l;
    h.x = f2bf(vv[0]); l.x = f2bf(vv[0] - bf2f(h.x));
    h.y = f2bf(vv[1]); l.y = f2bf(vv[1] - bf2f(h.y));
    h.z = f2bf(vv[2]); l.z = f2bf(vv[2] - bf2f(h.z));
    h.w = f2bf(vv[3]); l.w = f2bf(vv[3] - bf2f(h.w));
    ushort* rowp = WB2 + (size_t)row * 3 * C + c4;
    *(ushort4*)(rowp)         = h;
    *(ushort4*)(rowp + C)     = l;
    *(ushort4*)(rowp + 2 * C) = h;
}

// ---------------- squared norms ----------------
__global__ void sqnorm(const float* __restrict__ x, int lda, int C, float* __restrict__ xx) {
    int p = blockIdx.x * 256 + threadIdx.x;
    if (p < P_) {
        const float* r = x + (size_t)p * lda;
        float s = 0.f;
        for (int c = 0; c < C; c++) s += r[c] * r[c];
        xx[p] = s;
    }
}

// ---------------- fp32 -> split-bf16 rows. mode0: [h|h|l], mode1: [h|l|h] ---
__global__ void conv_split(const float* __restrict__ src, int ld, int C, int rows,
                           ushort* __restrict__ dst, int mode) {
    int i = blockIdx.x * 256 + threadIdx.x;
    int cpr = C >> 2;
    if (i >= rows * cpr) return;
    int p = i / cpr, c4 = (i % cpr) * 4;
    float4 v = *(const float4*)(src + (size_t)p * ld + c4);
    ushort4 h, l;
    h.x = f2bf(v.x); l.x = f2bf(v.x - bf2f(h.x));
    h.y = f2bf(v.y); l.y = f2bf(v.y - bf2f(h.y));
    h.z = f2bf(v.z); l.z = f2bf(v.z - bf2f(h.z));
    h.w = f2bf(v.w); l.w = f2bf(v.w - bf2f(h.w));
    ushort* row = dst + (size_t)p * 3 * C + c4;
    if (mode == 0) {
        *(ushort4*)(row)         = h;
        *(ushort4*)(row + C)     = h;
        *(ushort4*)(row + 2 * C) = l;
    } else {
        *(ushort4*)(row)         = h;
        *(ushort4*)(row + C)     = l;
        *(ushort4*)(row + 2 * C) = h;
    }
}

// ---------------- fp32 dist (all layers): 2*dot - xx_n - xx_m ---------------
// 64x64 tile, 4x4/thread, LDS-transposed mirror store; triangular linear grid.
// fp32 mandatory: split-bf16 dist flips near-tie kNN (R3).
__global__ void dist_kernel(const float* __restrict__ x, int lda, int C,
                            const float* __restrict__ xx, float* __restrict__ dist) {
    int t = blockIdx.x;
    int mi = (int)((sqrtf(8.f * (float)t + 1.f) - 1.f) * 0.5f);
    while ((mi + 1) * (mi + 2) / 2 <= t) mi++;
    while (mi * (mi + 1) / 2 > t) mi--;
    int nj = t - mi * (mi + 1) / 2;
    int m0 = mi * 64, n0 = nj * 64;
    __shared__ float As[16][68];
    __shared__ float Bs[16][68];
    __shared__ float Ts[64][68];
    int b = blockIdx.y;
    const float* xb = x + (size_t)b * N_ * lda;
    int tid = threadIdx.x;
    int tx = tid & 15, ty = tid >> 4;
    float acc[4][4] = {};
    for (int k0 = 0; k0 < C; k0 += 16) {
        for (int l = tid; l < 1024; l += 256) {
            int r = l >> 4, kk = l & 15, kg = k0 + kk;
            As[kk][r] = (kg < C) ? xb[(size_t)(n0 + r) * lda + kg] : 0.f;
            Bs[kk][r] = (kg < C) ? xb[(size_t)(m0 + r) * lda + kg] : 0.f;
        }
        __syncthreads();
        #pragma unroll
        for (int kk = 0; kk < 16; kk++) {
            float4 a4 = *(const float4*)&As[kk][ty * 4];
            float4 w4 = *(const float4*)&Bs[kk][tx * 4];
            float a[4] = {a4.x, a4.y, a4.z, a4.w};
            float w[4] = {w4.x, w4.y, w4.z, w4.w};
            #pragma unroll
            for (int i = 0; i < 4; i++)
                #pragma unroll
                for (int j = 0; j < 4; j++) acc[i][j] += a[i] * w[j];
        }
        __syncthreads();
    }
    size_t prow = (size_t)b * N_;
    #pragma unroll
    for (int i = 0; i < 4; i++) {
        int n = n0 + ty * 4 + i;
        float xn = xx[b * N_ + n];
        float4 v4;
        float vt[4];
        #pragma unroll
        for (int j = 0; j < 4; j++) {
            int m = m0 + tx * 4 + j;
            float v = 2.f * acc[i][j] - xn - xx[b * N_ + m];
            vt[j] = v;
            Ts[tx * 4 + j][ty * 4 + i] = v;   // Ts[m - m0][n - n0]
        }
        v4.x = vt[0]; v4.y = vt[1]; v4.z = vt[2]; v4.w = vt[3];
        *(float4*)&dist[(prow + n) * N_ + m0 + tx * 4] = v4;
    }
    if (m0 != n0) {
        __syncthreads();
        #pragma unroll
        for (int i = 0; i < 4; i++) {
            int mi2 = ty * 4 + i;
            float4 v4 = *(const float4*)&Ts[mi2][tx * 4];
            *(float4*)&dist[(prow + m0 + mi2) * N_ + n0 + tx * 4] = v4;
        }
    }
}

// ---------------- top-k=20 per row; one wave per row, LDS-backed ------------
// R16/R17: both register-array and named-scalar forms spilled (VGPR=24) —
// the allocator insists on scratch at its default occupancy target. Fix:
// keep the 16 per-lane values in LDS (lane-private columns, dynamic indexing
// is native there), cache only the running local max (bv,bs) in registers.
// Winner lane evicts its LDS slot (-inf) and rescans 16 slots; all other
// lanes keep their cached max. Slot order == ascending col for fixed lane,
// so strict > preserves lax.top_k tie order; cols unique -> exact winner.
__global__ __launch_bounds__(256)
void topk_kernel(const float* __restrict__ dist, int* __restrict__ idx) {
    __shared__ float val[4 * 16 * 68];   // [wave][slot][lane(+pad)]
    int tid = threadIdx.x;
    int wv = tid >> 6, lane = tid & 63;
    int wave = blockIdx.x * 4 + wv;      // grid = P_/4 exactly
    const float* row = dist + (size_t)wave * N_;
    float* V = &val[wv * 16 * 68];

    float bv = -3.4e38f; int bs = 0;
    #pragma unroll
    for (int g = 0; g < 4; g++) {
        float4 q = *(const float4*)&row[g * 256 + lane * 4];
        V[(g * 4 + 0) * 68 + lane] = q.x;
        V[(g * 4 + 1) * 68 + lane] = q.y;
        V[(g * 4 + 2) * 68 + lane] = q.z;
        V[(g * 4 + 3) * 68 + lane] = q.w;
        // strict > keeps lowest slot (= lowest col) on ties
        if (q.x > bv) { bv = q.x; bs = g * 4 + 0; }
        if (q.y > bv) { bv = q.y; bs = g * 4 + 1; }
        if (q.z > bv) { bv = q.z; bs = g * 4 + 2; }
        if (q.w > bv) { bv = q.w; bs = g * 4 + 3; }
    }

    int* out = idx + (size_t)wave * KNN;
    #pragma unroll 1
    for (int it = 0; it < KNN; it++) {
        int cand = (bs >> 2) * 256 + lane * 4 + (bs & 3);   // this lane's col
        float sv = bv; int sc = cand;
        #pragma unroll
        for (int off = 32; off > 0; off >>= 1) {
            float ov = __shfl_xor(sv, off, 64);
            int   oc = __shfl_xor(sc, off, 64);
            if (ov > sv || (ov == sv && oc < sc)) { sv = ov; sc = oc; }
        }
        if (lane == 0) out[it] = sc;
        int wc = __builtin_amdgcn_readfirstlane(sc);
        if (cand == wc) {            // winner lane (cols unique)
            V[bs * 68 + lane] = -3.4e38f;
            bv = -3.4e38f; bs = 0;
            #pragma unroll
            for (int s = 0; s < 16; s++) {
                float v = V[s * 68 + lane];
                if (v > bv) { bv = v; bs = s; }
            }
        }
    }
}

// ---------------- fp32 GEMM (layer-1 uv only, K=3) --------------------------
__global__ void gemm_wt(const float* __restrict__ A, int lda,
                        const float* __restrict__ W, int ldw,
                        float* __restrict__ out, int ldo, int K) {
    __shared__ float As[16][68];
    __shared__ float Ws[16][68];
    int m0 = blockIdx.y * 64, n0 = blockIdx.x * 64;
    int tid = threadIdx.x;
    int tx = tid & 15, ty = tid >> 4;
    float acc[4][4] = {};
    for (int k0 = 0; k0 < K; k0 += 16) {
        for (int l = tid; l < 1024; l += 256) {
            int r = l >> 4, kk = l & 15, kg = k0 + kk;
            As[kk][r] = (kg < K) ? A[(size_t)(m0 + r) * lda + kg] : 0.f;
            Ws[kk][r] = (kg < K) ? W[(size_t)(n0 + r) * ldw + kg] : 0.f;
        }
        __syncthreads();
        #pragma unroll
        for (int kk = 0; kk < 16; kk++) {
            float4 a4 = *(const float4*)&As[kk][ty * 4];
            float4 w4 = *(const float4*)&Ws[kk][tx * 4];
            float a[4] = {a4.x, a4.y, a4.z, a4.w};
            float w[4] = {w4.x, w4.y, w4.z, w4.w};
            #pragma unroll
            for (int i = 0; i < 4; i++)
                #pragma unroll
                for (int j = 0; j < 4; j++) acc[i][j] += a[i] * w[j];
        }
        __syncthreads();
    }
    for (int i = 0; i < 4; i++) {
        int m = m0 + ty * 4 + i;
        for (int j = 0; j < 4; j++) {
            int n = n0 + tx * 4 + j;
            out[(size_t)m * ldo + n] = acc[i][j];
        }
    }
}

// ---------------- unified split-bf16 MFMA GEMM ------------------------------
// MODE 0: uv; MODE 2: final conv + fused transposed col stats.
// Bijective XCD swizzle (R12): each XCD owns a contiguous y-band.
template<int MODE>
__global__ __launch_bounds__(256, 2)
void gemm_mfma(const ushort* __restrict__ A, const ushort* __restrict__ Bw,
               int K, int nkt, float* __restrict__ out, int ldo,
               float* __restrict__ part) {
    __shared__ ushort lA[128 * 64];
    __shared__ ushort lB[128 * 64];
    int tid = threadIdx.x;
    int lane = tid & 63;
    int wid = tid >> 6;
    int wr = wid >> 1, wc = wid & 1;

    int nx = gridDim.x;
    int ypb = gridDim.y >> 3;
    int bid = blockIdx.y * nx + blockIdx.x;
    int xcd = bid & 7, pos = bid >> 3;
    int yy = xcd * ypb + pos / nx;
    int xx2 = pos % nx;
    int m0 = yy * 128, n0 = xx2 * 128;

    const ushort* pA = A + (size_t)m0 * K;
    const ushort* pB = Bw + (size_t)n0 * K;
    int rowu = tid >> 3, kcu = (tid & 7) * 8;

    f32x4 acc[4][4] = {};
    short8v ra[4], rb[4];
    #pragma unroll
    for (int j = 0; j < 4; j++) {
        int row = rowu + j * 32;
        ra[j] = *(const short8v*)(pA + (size_t)row * K + kcu);
        rb[j] = *(const short8v*)(pB + (size_t)row * K + kcu);
    }

    for (int kt = 0; kt < nkt; kt++) {
        __syncthreads();
        #pragma unroll
        for (int j = 0; j < 4; j++) {
            int row = rowu + j * 32;
            int off = (row * 128 + kcu * 2) ^ ((row & 7) << 4);
            *(short8v*)((char*)lA + off) = ra[j];
            *(short8v*)((char*)lB + off) = rb[j];
        }
        __syncthreads();
        if (kt < nkt - 1) {
            int kbase = (kt + 1) * 64 + kcu;
            #pragma unroll
            for (int j = 0; j < 4; j++) {
                int row = rowu + j * 32;
                ra[j] = *(const short8v*)(pA + (size_t)row * K + kbase);
                rb[j] = *(const short8v*)(pB + (size_t)row * K + kbase);
            }
        }
        #pragma unroll
        for (int ks = 0; ks < 2; ks++) {
            short8v af[4], bg[4];
            int kb2 = (ks * 32 + ((lane >> 4) << 3)) * 2;
            #pragma unroll
            for (int mb = 0; mb < 4; mb++) {
                int row = wr * 64 + mb * 16 + (lane & 15);
                int off = (row * 128 + kb2) ^ ((row & 7) << 4);
                af[mb] = *(const short8v*)((const char*)lA + off);
            }
            #pragma unroll
            for (int nb = 0; nb < 4; nb++) {
                int row = wc * 64 + nb * 16 + (lane & 15);
                int off = (row * 128 + kb2) ^ ((row & 7) << 4);
                bg[nb] = *(const short8v*)((const char*)lB + off);
            }
            #pragma unroll
            for (int mb = 0; mb < 4; mb++)
                #pragma unroll
                for (int nb = 0; nb < 4; nb++)
                    acc[mb][nb] = __builtin_amdgcn_mfma_f32_16x16x32_bf16(af[mb], bg[nb], acc[mb][nb], 0, 0, 0);
        }
    }

    int rbase = m0 + wr * 64 + ((lane >> 4) << 2);
    int cbase = n0 + wc * 64 + (lane & 15);

    if (MODE == 0) {
        #pragma unroll
        for (int mb = 0; mb < 4; mb++)
            #pragma unroll
            for (int nb = 0; nb < 4; nb++)
                #pragma unroll
                for (int r = 0; r < 4; r++)
                    out[(size_t)(rbase + mb * 16 + r) * ldo + cbase + nb * 16] = acc[mb][nb][r];
    } else {
        float* smS = (float*)lA;
        float* smQ = (float*)lB;
        __syncthreads();
        #pragma unroll
        for (int nb = 0; nb < 4; nb++) {
            float s = 0.f, q = 0.f;
            #pragma unroll
            for (int mb = 0; mb < 4; mb++)
                #pragma unroll
                for (int r = 0; r < 4; r++) {
                    float v = acc[mb][nb][r];
                    out[(size_t)(rbase + mb * 16 + r) * ldo + cbase + nb * 16] = v;
                    s += v; q += v * v;
                }
            s += __shfl_xor(s, 16, 64); s += __shfl_xor(s, 32, 64);
            q += __shfl_xor(q, 16, 64); q += __shfl_xor(q, 32, 64);
            if ((lane >> 4) == 0) {
                smS[wid * 64 + nb * 16 + lane] = s;
                smQ[wid * 64 + nb * 16 + lane] = q;
            }
        }
        __syncthreads();
        if (tid < 128) {
            int wcs = tid >> 6, c = tid & 63;
            float s = smS[wcs * 64 + c] + smS[(2 + wcs) * 64 + c];
            float q = smQ[wcs * 64 + c] + smQ[(2 + wcs) * 64 + c];
            int col = n0 + wcs * 64 + c;
            part[(size_t)col * 128 + yy] = s;
            part[131072 + (size_t)col * 128 + yy] = q;
        }
    }
}

// ---------------- gather neighbors, per-(p,o) max/min, per-channel stats ----
__global__ void gather_stats(const float* __restrict__ uv, const int* __restrict__ idx, int O,
                             float* __restrict__ ymax, float* __restrict__ ymin,
                             double* __restrict__ part, int ppb) {
    __shared__ double sd[256], sd2[256];
    int t = threadIdx.x;
    int R = 256 / O;
    int o = t % O;
    int q = t / O;
    double s = 0.0, s2 = 0.0;
    int p0 = blockIdx.x * ppb;
    int ld = 2 * O;
    for (int lp = q; lp < ppb; lp += R) {
        int p = p0 + lp;
        int b = p >> 10;
        const int* ir = idx + (size_t)p * KNN;
        float v = uv[(size_t)p * ld + O + o];
        float mx = -3.4e38f, mn = 3.4e38f;
        for (int kk = 0; kk < KNN; kk++) {
            int j = ir[kk];
            float u = uv[((size_t)((b << 10) + j)) * ld + o];
            float y = u + v;
            mx = fmaxf(mx, y); mn = fminf(mn, y);
            s += (double)y; s2 += (double)y * (double)y;
        }
        ymax[(size_t)p * O + o] = mx;
        ymin[(size_t)p * O + o] = mn;
    }
    sd[t] = s; sd2[t] = s2;
    __syncthreads();
    if (t < O) {
        double a = 0.0, a2 = 0.0;
        for (int qq = 0; qq < R; qq++) { a += sd[qq * O + t]; a2 += sd2[qq * O + t]; }
        part[(size_t)t * 1024 + blockIdx.x] = a;
        part[(size_t)(O + t) * 1024 + blockIdx.x] = a2;
    }
}

// ---------------- parallel finalize: one block per channel ------------------
__global__ void finalize_t(const double* __restrict__ part, int O,
                           const float* __restrict__ g, const float* __restrict__ bt,
                           float* __restrict__ scale, float* __restrict__ shift, double invCount) {
    __shared__ double sa[4], sb[4];
    int o = blockIdx.x;
    int t = threadIdx.x;
    int lane = t & 63, w = t >> 6;
    const double* ps = part + (size_t)o * 1024;
    const double* pq = part + (size_t)(O + o) * 1024;
    double s = 0.0, s2 = 0.0;
    #pragma unroll
    for (int b = 0; b < 4; b++) { s += ps[t + b * 256]; s2 += pq[t + b * 256]; }
    #pragma unroll
    for (int off = 32; off > 0; off >>= 1) { s += __shfl_xor(s, off, 64); s2 += __shfl_xor(s2, off, 64); }
    if (lane == 0) { sa[w] = s; sb[w] = s2; }
    __syncthreads();
    if (t == 0) {
        s = sa[0] + sa[1] + sa[2] + sa[3];
        s2 = sb[0] + sb[1] + sb[2] + sb[3];
        double mean = s * invCount;
        double var = s2 * invCount - mean * mean;
        if (var < 0.0) var = 0.0;
        float sc = (float)(1.0 / sqrt(var + 1e-5)) * g[o];
        scale[o] = sc;
        shift[o] = bt[o] - (float)mean * sc;
    }
}

// ---------------- parallel finalize for float partials (final conv) ---------
__global__ void finalize_f_t(const float* __restrict__ part,
                             const float* __restrict__ g, const float* __restrict__ bt,
                             float* __restrict__ scale, float* __restrict__ shift, double invCount) {
    __shared__ double sa[2], sb[2];
    int o = blockIdx.x;
    int t = threadIdx.x;   // 128 threads
    int lane = t & 63, w = t >> 6;
    double s  = (double)part[(size_t)o * 128 + t];
    double s2 = (double)part[131072 + (size_t)o * 128 + t];
    #pragma unroll
    for (int off = 32; off > 0; off >>= 1) { s += __shfl_xor(s, off, 64); s2 += __shfl_xor(s2, off, 64); }
    if (lane == 0) { sa[w] = s; sb[w] = s2; }
    __syncthreads();
    if (t == 0) {
        s = sa[0] + sa[1];
        s2 = sb[0] + sb[1];
        double mean = s * invCount;
        double var = s2 * invCount - mean * mean;
        if (var < 0.0) var = 0.0;
        float sc = (float)(1.0 / sqrt(var + 1e-5)) * g[o];
        scale[o] = sc;
        shift[o] = bt[o] - (float)mean * sc;
    }
}

// ---------------- edge conv epilogue: BN + leaky (max over k done) ----------
__global__ void apply_edge(const float* __restrict__ ymax, const float* __restrict__ ymin,
                           const float* __restrict__ scale, const float* __restrict__ shift,
                           float* __restrict__ xcat, int O, int off) {
    int i = blockIdx.x * 256 + threadIdx.x;
    if (i < P_ * O) {
        int p = i / O, o = i % O;
        float sc = scale[o];
        float y = (sc >= 0.f) ? ymax[i] : ymin[i];
        float val = y * sc + shift[o];
        xcat[(size_t)p * 512 + off + o] = LEAKY(val);
    }
}

// ---------------- pool partials: grid (16b, 16og, 4nz) = 1024 blocks --------
__global__ void pool_part(const float* __restrict__ h, const float* __restrict__ scale,
                          const float* __restrict__ shift,
                          float* __restrict__ pmax, double* __restrict__ psum) {
    __shared__ float smax[256];
    __shared__ double ssum[256];
    int b = blockIdx.x, og = blockIdx.y, nz = blockIdx.z;
    int t = threadIdx.x;
    int o = og * 64 + (t & 63);
    int ch = t >> 6;
    float sc = scale[o], sh = shift[o];
    float mx = -3.4e38f;
    double sm = 0.0;
    int n0 = nz * 256 + ch * 64;
    #pragma unroll 4
    for (int n = n0; n < n0 + 64; n++) {
        float y = h[((size_t)b * N_ + n) * 1024 + o] * sc + sh;
        y = LEAKY(y);
        mx = fmaxf(mx, y);
        sm += (double)y;
    }
    smax[t] = mx; ssum[t] = sm;
    __syncthreads();
    if (t < 64) {
        for (int c = 1; c < 4; c++) { mx = fmaxf(mx, smax[c * 64 + t]); sm += ssum[c * 64 + t]; }
        size_t pi = ((size_t)b * 4 + nz) * 1024 + o;
        pmax[pi] = mx;
        psum[pi] = sm;
    }
}

// ---------------- pool final: reduce 4 nz partials -> max / mean ------------
__global__ void pool_fin(const float* __restrict__ pmax, const double* __restrict__ psum,
                         float* __restrict__ pooled) {
    int b = blockIdx.x, og = blockIdx.y;
    int o = og * 256 + threadIdx.x;
    size_t base = (size_t)b * 4 * 1024 + o;
    float mx = pmax[base];
    double sm = psum[base];
    #pragma unroll
    for (int nz = 1; nz < 4; nz++) {
        mx = fmaxf(mx, pmax[base + nz * 1024]);
        sm += psum[base + nz * 1024];
    }
    pooled[(size_t)b * 2048 + o] = mx;
    pooled[(size_t)b * 2048 + 1024 + o] = (float)(sm * (1.0 / N_));
}

// ---------------- small FC: one wave per output -----------------------------
__global__ void fc_kernel(const float* __restrict__ in, int ldi,
                          const float* __restrict__ w, int ldw,
                          const float* __restrict__ bias,
                          float* __restrict__ out, int M, int Nn, int K) {
    int gw = (blockIdx.x * 256 + threadIdx.x) >> 6;
    int lane = threadIdx.x & 63;
    if (gw >= M * Nn) return;
    int m = gw / Nn, n = gw % Nn;
    const float* a = in + (size_t)m * ldi;
    const float* ww = w + (size_t)n * ldw;
    float s = 0.f;
    for (int kk = lane; kk < K; kk += 64) s += a[kk] * ww[kk];
    #pragma unroll
    for (int off = 32; off > 0; off >>= 1) s += __shfl_xor(s, off, 64);
    if (lane == 0) out[(size_t)m * Nn + n] = s + bias[n];
}

// ---------------- BN over batch axis (M=16) + leaky, in place ---------------
__global__ void bn_rows(float* __restrict__ z, int M, int O,
                        const float* __restrict__ g, const float* __restrict__ bt) {
    int o = blockIdx.x * 256 + threadIdx.x;
    if (o >= O) return;
    double s = 0.0, s2 = 0.0;
    for (int m = 0; m < M; m++) {
        float y = z[(size_t)m * O + o];
        s += (double)y; s2 += (double)y * (double)y;
    }
    double mean = s / M;
    double var = s2 / M - mean * mean;
    if (var < 0.0) var = 0.0;
    float sc = (float)(1.0 / sqrt(var + 1e-5)) * g[o];
    float sh = bt[o] - (float)mean * sc;
    for (int m = 0; m < M; m++) {
        float y = z[(size_t)m * O + o] * sc + sh;
        z[(size_t)m * O + o] = LEAKY(y);
    }
}

extern "C" void kernel_launch(void* const* d_in, const int* in_sizes, int n_in,
                              void* d_out, int out_size, void* d_ws, size_t ws_size,
                              hipStream_t stream) {
    const float* cloud = (const float*)d_in[0];
    const float* wf  = (const float*)d_in[17];
    const float* gf  = (const float*)d_in[19];
    const float* btf = (const float*)d_in[20];
    const float* wl1 = (const float*)d_in[21];
    const float* bl1 = (const float*)d_in[22];
    const float* gl1 = (const float*)d_in[23];
    const float* btl1= (const float*)d_in[24];
    const float* wl2 = (const float*)d_in[25];
    const float* bl2 = (const float*)d_in[26];
    const float* gl2 = (const float*)d_in[27];
    const float* btl2= (const float*)d_in[28];
    const float* wl3 = (const float*)d_in[29];
    const float* bl3 = (const float*)d_in[30];

    // workspace layout (bytes)
    const size_t OFF_XCAT  = 0;                        // 33554432
    const size_t OFF_UV    = 33554432;                 // 33554432 (A2 aliases UV+YMAX)
    const size_t OFF_YMAX  = 67108864;                 // 16777216 (xA alias: 12.6MB max)
    const size_t OFF_YMIN  = 83886080;                 // 16777216 (B2 alias)
    const size_t OFF_DIST  = 100663296;                // 67108864 (aliased as hraw)
    const size_t OFF_IDX   = 167772160;                // 1310720
    const size_t OFF_XX    = 169082880;                // 65536
    const size_t OFF_W2    = 169148416;                // 524288
    const size_t OFF_PART  = 169676800;                // 4194304: part doubles / partf / pool partials
    const size_t OFF_SCALE = 173871104;                // 4096
    const size_t OFF_SHIFT = 173875200;                // 4096
    const size_t OFF_POOL  = 173879296;                // 131072
    const size_t OFF_Z1    = 174010368;                // 32768
    const size_t OFF_Z2    = 174043136;                // 16384
    const size_t TOTAL     = 174059520;
    if (ws_size < TOTAL) return;

    char* ws = (char*)d_ws;
    float* xcat  = (float*)(ws + OFF_XCAT);
    float* uv    = (float*)(ws + OFF_UV);
    float* ymax  = (float*)(ws + OFF_YMAX);
    float* ymin  = (float*)(ws + OFF_YMIN);
    float* dist  = (float*)(ws + OFF_DIST);
    float* hraw  = (float*)(ws + OFF_DIST);
    ushort* A2   = (ushort*)(ws + OFF_UV);
    ushort* B2   = (ushort*)(ws + OFF_YMIN);
    ushort* xA   = (ushort*)(ws + OFF_YMAX);
    ushort* WB2  = (ushort*)(ws + OFF_PART);
    int*   idx   = (int*)  (ws + OFF_IDX);
    float* xx    = (float*)(ws + OFF_XX);
    float* W2    = (float*)(ws + OFF_W2);
    double* part = (double*)(ws + OFF_PART);
    float* partf = (float*)(ws + OFF_PART);
    float* ppmax = (float*)(ws + OFF_PART + 2097152);   // 16*4*1024 f = 256KB
    double* ppsum= (double*)(ws + OFF_PART + 2359296);  // 16*4*1024 d = 512KB
    float* scale = (float*)(ws + OFF_SCALE);
    float* shift = (float*)(ws + OFF_SHIFT);
    float* pooled= (float*)(ws + OFF_POOL);
    float* z1    = (float*)(ws + OFF_Z1);
    float* z2    = (float*)(ws + OFF_Z2);

    const int Cs[4]   = {3, 64, 64, 128};
    const int Os[4]   = {64, 64, 128, 256};
    const int offs[4] = {0, 64, 128, 256};

    for (int L = 0; L < 4; L++) {
        int C = Cs[L], O = Os[L];
        const float* w  = (const float*)d_in[1 + 4 * L];
        const float* g  = (const float*)d_in[3 + 4 * L];
        const float* bt = (const float*)d_in[4 + 4 * L];
        const float* x  = (L == 0) ? cloud : (xcat + offs[L - 1]);
        int lda = (L == 0) ? 3 : 512;

        sqnorm<<<(P_ + 255) / 256, 256, 0, stream>>>(x, lda, C, xx);
        dist_kernel<<<dim3(136, 16), 256, 0, stream>>>(x, lda, C, xx, dist);
        topk_kernel<<<P_ / 4, 256, 0, stream>>>(dist, idx);

        if (L == 0) {
            prep_w2<<<(2 * O * C + 255) / 256, 256, 0, stream>>>(w, W2, O, C);
            gemm_wt<<<dim3(2 * O / 64, P_ / 64), 256, 0, stream>>>(x, lda, W2, C, uv, 2 * O, C);
        } else {
            int K3 = 3 * C, nkt = K3 / 64;
            conv_split<<<(P_ * (C / 4) + 255) / 256, 256, 0, stream>>>(x, lda, C, P_, xA, 0);
            prep_w2_split<<<(2 * O * (C / 4) + 255) / 256, 256, 0, stream>>>(w, WB2, O, C);
            gemm_mfma<0><<<dim3(2 * O / 128, 128), 256, 0, stream>>>(xA, WB2, K3, nkt, uv, 2 * O, nullptr);
        }

        gather_stats<<<1024, 256, 0, stream>>>(uv, idx, O, ymax, ymin, part, 16);
        finalize_t<<<O, 256, 0, stream>>>(part, O, g, bt, scale, shift, 1.0 / ((double)P_ * KNN));
        apply_edge<<<(P_ * O + 255) / 256, 256, 0, stream>>>(ymax, ymin, scale, shift, xcat, O, offs[L]);
    }

    // final 1x1 conv via split-bf16 MFMA GEMM with fused (transposed) col stats
    conv_split<<<(P_ * 128 + 255) / 256, 256, 0, stream>>>(xcat, 512, 512, P_, A2, 0);
    conv_split<<<(1024 * 128 + 255) / 256, 256, 0, stream>>>(wf, 512, 512, 1024, B2, 1);
    gemm_mfma<2><<<dim3(8, 128), 256, 0, stream>>>(A2, B2, 1536, 24, hraw, 1024, partf);

    finalize_f_t<<<1024, 128, 0, stream>>>(partf, gf, btf, scale, shift, 1.0 / (double)P_);
    pool_part<<<dim3(16, 16, 4), 256, 0, stream>>>(hraw, scale, shift, ppmax, ppsum);
    pool_fin<<<dim3(16, 4), 256, 0, stream>>>(ppmax, ppsum, pooled);

    // MLP head
    fc_kernel<<<(16 * 512 * 64) / 256, 256, 0, stream>>>(pooled, 2048, wl1, 2048, bl1, z1, 16, 512, 2048);
    bn_rows<<<2, 256, 0, stream>>>(z1, 16, 512, gl1, btl1);
    fc_kernel<<<(16 * 256 * 64) / 256, 256, 0, stream>>>(z1, 512, wl2, 512, bl2, z2, 16, 256, 512);
    bn_rows<<<1, 256, 0, stream>>>(z2, 16, 256, gl2, btl2);
    fc_kernel<<<(16 * 40 * 64 + 255) / 256, 256, 0, stream>>>(z2, 256, wl3, 256, bl3, (float*)d_out, 16, 40, 256);
}

// Round 19
// 717.160 us; speedup vs baseline: 1.0745x; 1.0745x over previous
//
#include <hip/hip_runtime.h>

#define LEAKY(v) ((v) >= 0.f ? (v) : 0.2f*(v))

static const int B_ = 16;
static const int N_ = 1024;
static const int P_ = 16384;   // B*N
static const int KNN = 20;

typedef __attribute__((ext_vector_type(8))) short short8v;
typedef __attribute__((ext_vector_type(4))) float f32x4;

__device__ inline ushort f2bf(float f) {
    unsigned u = __float_as_uint(f);
    unsigned r = u + 0x7FFFu + ((u >> 16) & 1u);
    return (ushort)(r >> 16);
}
__device__ inline float bf2f(ushort h) {
    return __uint_as_float(((unsigned)h) << 16);
}

// ---------------- prep: W2 = [wA ; wB - wA] fp32 (layer-1 only) -------------
__global__ void prep_w2(const float* __restrict__ w, float* __restrict__ W2, int O, int C) {
    int i = blockIdx.x * 256 + threadIdx.x;
    int total = 2 * O * C;
    if (i < total) {
        int row = i / C, c = i % C;
        float val;
        if (row < O) val = w[row * 2 * C + c];
        else { int o = row - O; val = w[o * 2 * C + C + c] - w[o * 2 * C + c]; }
        W2[i] = val;
    }
}

// ---------------- prep W2 and split to bf16 [h|l|h] in one pass (L>=1) ------
__global__ void prep_w2_split(const float* __restrict__ w, ushort* __restrict__ WB2, int O, int C) {
    int i = blockIdx.x * 256 + threadIdx.x;
    int cpr = C >> 2;
    if (i >= 2 * O * cpr) return;
    int row = i / cpr, c4 = (i % cpr) * 4;
    float vv[4];
    #pragma unroll
    for (int j = 0; j < 4; j++) {
        int c = c4 + j;
        if (row < O) vv[j] = w[row * 2 * C + c];
        else { int o = row - O; vv[j] = w[o * 2 * C + C + c] - w[o * 2 * C + c]; }
    }
    ushort4 h, l;
    h.x = f2bf(vv[0]); l.x = f2bf(vv[0] - bf2f(h.x));
    h.y = f2bf(vv[1]); l.y = f2bf(vv[1] - bf2f(h.y));
    h.z = f2bf(vv[2]); l.z = f2bf(vv[2] - bf2f(h.z));
    h.w = f2bf(vv[3]); l.w = f2bf(vv[3] - bf2f(h.w));
    ushort* rowp = WB2 + (size_t)row * 3 * C + c4;
    *(ushort4*)(rowp)         = h;
    *(ushort4*)(rowp + C)     = l;
    *(ushort4*)(rowp + 2 * C) = h;
}

// ---------------- squared norms ----------------
__global__ void sqnorm(const float* __restrict__ x, int lda, int C, float* __restrict__ xx) {
    int p = blockIdx.x * 256 + threadIdx.x;
    if (p < P_) {
        const float* r = x + (size_t)p * lda;
        float s = 0.f;
        for (int c = 0; c < C; c++) s += r[c] * r[c];
        xx[p] = s;
    }
}

// ---------------- fp32 -> split-bf16 rows. mode0: [h|h|l], mode1: [h|l|h] ---
__global__ void conv_split(const float* __restrict__ src, int ld, int C, int rows,
                           ushort* __restrict__ dst, int mode) {
    int i = blockIdx.x * 256 + threadIdx.x;
    int cpr = C >> 2;
    if (i >= rows * cpr) return;
    int p = i / cpr, c4 = (i % cpr) * 4;
    float4 v = *(const float4*)(src + (size_t)p * ld + c4);
    ushort4 h, l;
    h.x = f2bf(v.x); l.x = f2bf(v.x - bf2f(h.x));
    h.y = f2bf(v.y); l.y = f2bf(v.y - bf2f(h.y));
    h.z = f2bf(v.z); l.z = f2bf(v.z - bf2f(h.z));
    h.w = f2bf(v.w); l.w = f2bf(v.w - bf2f(h.w));
    ushort* row = dst + (size_t)p * 3 * C + c4;
    if (mode == 0) {
        *(ushort4*)(row)         = h;
        *(ushort4*)(row + C)     = h;
        *(ushort4*)(row + 2 * C) = l;
    } else {
        *(ushort4*)(row)         = h;
        *(ushort4*)(row + C)     = l;
        *(ushort4*)(row + 2 * C) = h;
    }
}

// ---------------- fp32 dist (all layers): 2*dot - xx_n - xx_m ---------------
// 64x64 tile, 4x4/thread, LDS-transposed mirror store; triangular linear grid.
// fp32 mandatory: split-bf16 dist flips near-tie kNN (R3).
__global__ void dist_kernel(const float* __restrict__ x, int lda, int C,
                            const float* __restrict__ xx, float* __restrict__ dist) {
    int t = blockIdx.x;
    int mi = (int)((sqrtf(8.f * (float)t + 1.f) - 1.f) * 0.5f);
    while ((mi + 1) * (mi + 2) / 2 <= t) mi++;
    while (mi * (mi + 1) / 2 > t) mi--;
    int nj = t - mi * (mi + 1) / 2;
    int m0 = mi * 64, n0 = nj * 64;
    __shared__ float As[16][68];
    __shared__ float Bs[16][68];
    __shared__ float Ts[64][68];
    int b = blockIdx.y;
    const float* xb = x + (size_t)b * N_ * lda;
    int tid = threadIdx.x;
    int tx = tid & 15, ty = tid >> 4;
    float acc[4][4] = {};
    for (int k0 = 0; k0 < C; k0 += 16) {
        for (int l = tid; l < 1024; l += 256) {
            int r = l >> 4, kk = l & 15, kg = k0 + kk;
            As[kk][r] = (kg < C) ? xb[(size_t)(n0 + r) * lda + kg] : 0.f;
            Bs[kk][r] = (kg < C) ? xb[(size_t)(m0 + r) * lda + kg] : 0.f;
        }
        __syncthreads();
        #pragma unroll
        for (int kk = 0; kk < 16; kk++) {
            float4 a4 = *(const float4*)&As[kk][ty * 4];
            float4 w4 = *(const float4*)&Bs[kk][tx * 4];
            float a[4] = {a4.x, a4.y, a4.z, a4.w};
            float w[4] = {w4.x, w4.y, w4.z, w4.w};
            #pragma unroll
            for (int i = 0; i < 4; i++)
                #pragma unroll
                for (int j = 0; j < 4; j++) acc[i][j] += a[i] * w[j];
        }
        __syncthreads();
    }
    size_t prow = (size_t)b * N_;
    #pragma unroll
    for (int i = 0; i < 4; i++) {
        int n = n0 + ty * 4 + i;
        float xn = xx[b * N_ + n];
        float4 v4;
        float vt[4];
        #pragma unroll
        for (int j = 0; j < 4; j++) {
            int m = m0 + tx * 4 + j;
            float v = 2.f * acc[i][j] - xn - xx[b * N_ + m];
            vt[j] = v;
            Ts[tx * 4 + j][ty * 4 + i] = v;   // Ts[m - m0][n - n0]
        }
        v4.x = vt[0]; v4.y = vt[1]; v4.z = vt[2]; v4.w = vt[3];
        *(float4*)&dist[(prow + n) * N_ + m0 + tx * 4] = v4;
    }
    if (m0 != n0) {
        __syncthreads();
        #pragma unroll
        for (int i = 0; i < 4; i++) {
            int mi2 = ty * 4 + i;
            float4 v4 = *(const float4*)&Ts[mi2][tx * 4];
            *(float4*)&dist[(prow + m0 + mi2) * N_ + n0 + tx * 4] = v4;
        }
    }
}

// ---------------- top-k=20 per row; one wave per row ------------------------
// R17 named-scalar form + __launch_bounds__(256,4): R16/R17 spilled because
// the allocator capped VGPR at 24 for its default occupancy target; raising
// the cap to 128 (4 waves/EU) lets all 32 named scalars stay in registers.
#define CE(a,b,up) { bool p_ = (v##b > v##a) || (v##b == v##a && c##b < c##a); \
                     bool s_ = (up) ? p_ : !p_; \
                     float tv_ = v##a; int tc_ = c##a; \
                     v##a = s_ ? v##b : v##a; c##a = s_ ? c##b : c##a; \
                     v##b = s_ ? tv_ : v##b;  c##b = s_ ? tc_ : c##b; }
__global__ __launch_bounds__(256, 4)
void topk_kernel(const float* __restrict__ dist, int* __restrict__ idx) {
    int wave = (blockIdx.x * 256 + threadIdx.x) >> 6;
    int lane = threadIdx.x & 63;
    if (wave >= P_) return;
    const float* row = dist + (size_t)wave * N_;
    int cb = lane * 4;
    float4 q0 = *(const float4*)&row[cb];
    float4 q1 = *(const float4*)&row[256 + cb];
    float4 q2 = *(const float4*)&row[512 + cb];
    float4 q3 = *(const float4*)&row[768 + cb];
    float v0 = q0.x, v1 = q0.y, v2 = q0.z, v3 = q0.w;
    float v4 = q1.x, v5 = q1.y, v6 = q1.z, v7 = q1.w;
    float v8 = q2.x, v9 = q2.y, v10 = q2.z, v11 = q2.w;
    float v12 = q3.x, v13 = q3.y, v14 = q3.z, v15 = q3.w;
    int c0 = cb, c1 = cb + 1, c2 = cb + 2, c3 = cb + 3;
    int c4 = 256 + cb, c5 = 256 + cb + 1, c6 = 256 + cb + 2, c7 = 256 + cb + 3;
    int c8 = 512 + cb, c9 = 512 + cb + 1, c10 = 512 + cb + 2, c11 = 512 + cb + 3;
    int c12 = 768 + cb, c13 = 768 + cb + 1, c14 = 768 + cb + 2, c15 = 768 + cb + 3;

    // bitonic sort, best-first by (value desc, col asc)
    CE(0,1,true) CE(2,3,false) CE(4,5,true) CE(6,7,false)
    CE(8,9,true) CE(10,11,false) CE(12,13,true) CE(14,15,false)
    CE(0,2,true) CE(1,3,true) CE(4,6,false) CE(5,7,false)
    CE(8,10,true) CE(9,11,true) CE(12,14,false) CE(13,15,false)
    CE(0,1,true) CE(2,3,true) CE(4,5,false) CE(6,7,false)
    CE(8,9,true) CE(10,11,true) CE(12,13,false) CE(14,15,false)
    CE(0,4,true) CE(1,5,true) CE(2,6,true) CE(3,7,true)
    CE(8,12,false) CE(9,13,false) CE(10,14,false) CE(11,15,false)
    CE(0,2,true) CE(1,3,true) CE(4,6,true) CE(5,7,true)
    CE(8,10,false) CE(9,11,false) CE(12,14,false) CE(13,15,false)
    CE(0,1,true) CE(2,3,true) CE(4,5,true) CE(6,7,true)
    CE(8,9,false) CE(10,11,false) CE(12,13,false) CE(14,15,false)
    CE(0,8,true) CE(1,9,true) CE(2,10,true) CE(3,11,true)
    CE(4,12,true) CE(5,13,true) CE(6,14,true) CE(7,15,true)
    CE(0,4,true) CE(1,5,true) CE(2,6,true) CE(3,7,true)
    CE(8,12,true) CE(9,13,true) CE(10,14,true) CE(11,15,true)
    CE(0,2,true) CE(1,3,true) CE(4,6,true) CE(5,7,true)
    CE(8,10,true) CE(9,11,true) CE(12,14,true) CE(13,15,true)
    CE(0,1,true) CE(2,3,true) CE(4,5,true) CE(6,7,true)
    CE(8,9,true) CE(10,11,true) CE(12,13,true) CE(14,15,true)

    int* out = idx + (size_t)wave * KNN;
    #pragma unroll 1
    for (int it = 0; it < KNN; it++) {
        float bv = v0; int bc = c0;
        #pragma unroll
        for (int off = 32; off > 0; off >>= 1) {
            float ov = __shfl_xor(bv, off, 64);
            int   oc = __shfl_xor(bc, off, 64);
            if (ov > bv || (ov == bv && oc < bc)) { bv = ov; bc = oc; }
        }
        if (lane == 0) out[it] = bc;
        int wc = __builtin_amdgcn_readfirstlane(bc);
        bool mine = (c0 == wc);
        v0 = mine ? v1 : v0;   c0 = mine ? c1 : c0;
        v1 = mine ? v2 : v1;   c1 = mine ? c2 : c1;
        v2 = mine ? v3 : v2;   c2 = mine ? c3 : c2;
        v3 = mine ? v4 : v3;   c3 = mine ? c4 : c3;
        v4 = mine ? v5 : v4;   c4 = mine ? c5 : c4;
        v5 = mine ? v6 : v5;   c5 = mine ? c6 : c5;
        v6 = mine ? v7 : v6;   c6 = mine ? c7 : c6;
        v7 = mine ? v8 : v7;   c7 = mine ? c8 : c7;
        v8 = mine ? v9 : v8;   c8 = mine ? c9 : c8;
        v9 = mine ? v10 : v9;  c9 = mine ? c10 : c9;
        v10 = mine ? v11 : v10; c10 = mine ? c11 : c10;
        v11 = mine ? v12 : v11; c11 = mine ? c12 : c11;
        v12 = mine ? v13 : v12; c12 = mine ? c13 : c12;
        v13 = mine ? v14 : v13; c13 = mine ? c14 : c13;
        v14 = mine ? v15 : v14; c14 = mine ? c15 : c14;
        v15 = mine ? -3.4e38f : v15;
    }
}
#undef CE

// ---------------- fp32 GEMM (layer-1 uv only, K=3) --------------------------
__global__ void gemm_wt(const float* __restrict__ A, int lda,
                        const float* __restrict__ W, int ldw,
                        float* __restrict__ out, int ldo, int K) {
    __shared__ float As[16][68];
    __shared__ float Ws[16][68];
    int m0 = blockIdx.y * 64, n0 = blockIdx.x * 64;
    int tid = threadIdx.x;
    int tx = tid & 15, ty = tid >> 4;
    float acc[4][4] = {};
    for (int k0 = 0; k0 < K; k0 += 16) {
        for (int l = tid; l < 1024; l += 256) {
            int r = l >> 4, kk = l & 15, kg = k0 + kk;
            As[kk][r] = (kg < K) ? A[(size_t)(m0 + r) * lda + kg] : 0.f;
            Ws[kk][r] = (kg < K) ? W[(size_t)(n0 + r) * ldw + kg] : 0.f;
        }
        __syncthreads();
        #pragma unroll
        for (int kk = 0; kk < 16; kk++) {
            float4 a4 = *(const float4*)&As[kk][ty * 4];
            float4 w4 = *(const float4*)&Ws[kk][tx * 4];
            float a[4] = {a4.x, a4.y, a4.z, a4.w};
            float w[4] = {w4.x, w4.y, w4.z, w4.w};
            #pragma unroll
            for (int i = 0; i < 4; i++)
                #pragma unroll
                for (int j = 0; j < 4; j++) acc[i][j] += a[i] * w[j];
        }
        __syncthreads();
    }
    for (int i = 0; i < 4; i++) {
        int m = m0 + ty * 4 + i;
        for (int j = 0; j < 4; j++) {
            int n = n0 + tx * 4 + j;
            out[(size_t)m * ldo + n] = acc[i][j];
        }
    }
}

// ---------------- unified split-bf16 MFMA GEMM ------------------------------
// MODE 0: uv; MODE 2: final conv + fused transposed col stats.
// Bijective XCD swizzle (R12): each XCD owns a contiguous y-band.
template<int MODE>
__global__ __launch_bounds__(256, 2)
void gemm_mfma(const ushort* __restrict__ A, const ushort* __restrict__ Bw,
               int K, int nkt, float* __restrict__ out, int ldo,
               float* __restrict__ part) {
    __shared__ ushort lA[128 * 64];
    __shared__ ushort lB[128 * 64];
    int tid = threadIdx.x;
    int lane = tid & 63;
    int wid = tid >> 6;
    int wr = wid >> 1, wc = wid & 1;

    int nx = gridDim.x;
    int ypb = gridDim.y >> 3;
    int bid = blockIdx.y * nx + blockIdx.x;
    int xcd = bid & 7, pos = bid >> 3;
    int yy = xcd * ypb + pos / nx;
    int xx2 = pos % nx;
    int m0 = yy * 128, n0 = xx2 * 128;

    const ushort* pA = A + (size_t)m0 * K;
    const ushort* pB = Bw + (size_t)n0 * K;
    int rowu = tid >> 3, kcu = (tid & 7) * 8;

    f32x4 acc[4][4] = {};
    short8v ra[4], rb[4];
    #pragma unroll
    for (int j = 0; j < 4; j++) {
        int row = rowu + j * 32;
        ra[j] = *(const short8v*)(pA + (size_t)row * K + kcu);
        rb[j] = *(const short8v*)(pB + (size_t)row * K + kcu);
    }

    for (int kt = 0; kt < nkt; kt++) {
        __syncthreads();
        #pragma unroll
        for (int j = 0; j < 4; j++) {
            int row = rowu + j * 32;
            int off = (row * 128 + kcu * 2) ^ ((row & 7) << 4);
            *(short8v*)((char*)lA + off) = ra[j];
            *(short8v*)((char*)lB + off) = rb[j];
        }
        __syncthreads();
        if (kt < nkt - 1) {
            int kbase = (kt + 1) * 64 + kcu;
            #pragma unroll
            for (int j = 0; j < 4; j++) {
                int row = rowu + j * 32;
                ra[j] = *(const short8v*)(pA + (size_t)row * K + kbase);
                rb[j] = *(const short8v*)(pB + (size_t)row * K + kbase);
            }
        }
        #pragma unroll
        for (int ks = 0; ks < 2; ks++) {
            short8v af[4], bg[4];
            int kb2 = (ks * 32 + ((lane >> 4) << 3)) * 2;
            #pragma unroll
            for (int mb = 0; mb < 4; mb++) {
                int row = wr * 64 + mb * 16 + (lane & 15);
                int off = (row * 128 + kb2) ^ ((row & 7) << 4);
                af[mb] = *(const short8v*)((const char*)lA + off);
            }
            #pragma unroll
            for (int nb = 0; nb < 4; nb++) {
                int row = wc * 64 + nb * 16 + (lane & 15);
                int off = (row * 128 + kb2) ^ ((row & 7) << 4);
                bg[nb] = *(const short8v*)((const char*)lB + off);
            }
            #pragma unroll
            for (int mb = 0; mb < 4; mb++)
                #pragma unroll
                for (int nb = 0; nb < 4; nb++)
                    acc[mb][nb] = __builtin_amdgcn_mfma_f32_16x16x32_bf16(af[mb], bg[nb], acc[mb][nb], 0, 0, 0);
        }
    }

    int rbase = m0 + wr * 64 + ((lane >> 4) << 2);
    int cbase = n0 + wc * 64 + (lane & 15);

    if (MODE == 0) {
        #pragma unroll
        for (int mb = 0; mb < 4; mb++)
            #pragma unroll
            for (int nb = 0; nb < 4; nb++)
                #pragma unroll
                for (int r = 0; r < 4; r++)
                    out[(size_t)(rbase + mb * 16 + r) * ldo + cbase + nb * 16] = acc[mb][nb][r];
    } else {
        float* smS = (float*)lA;
        float* smQ = (float*)lB;
        __syncthreads();
        #pragma unroll
        for (int nb = 0; nb < 4; nb++) {
            float s = 0.f, q = 0.f;
            #pragma unroll
            for (int mb = 0; mb < 4; mb++)
                #pragma unroll
                for (int r = 0; r < 4; r++) {
                    float v = acc[mb][nb][r];
                    out[(size_t)(rbase + mb * 16 + r) * ldo + cbase + nb * 16] = v;
                    s += v; q += v * v;
                }
            s += __shfl_xor(s, 16, 64); s += __shfl_xor(s, 32, 64);
            q += __shfl_xor(q, 16, 64); q += __shfl_xor(q, 32, 64);
            if ((lane >> 4) == 0) {
                smS[wid * 64 + nb * 16 + lane] = s;
                smQ[wid * 64 + nb * 16 + lane] = q;
            }
        }
        __syncthreads();
        if (tid < 128) {
            int wcs = tid >> 6, c = tid & 63;
            float s = smS[wcs * 64 + c] + smS[(2 + wcs) * 64 + c];
            float q = smQ[wcs * 64 + c] + smQ[(2 + wcs) * 64 + c];
            int col = n0 + wcs * 64 + c;
            part[(size_t)col * 128 + yy] = s;
            part[131072 + (size_t)col * 128 + yy] = q;
        }
    }
}

// ---------------- gather neighbors, per-(p,o) max/min, per-channel stats ----
// R19: preload the 20 neighbor indices as 5x int4 (80B rows are 16B-aligned)
// and issue gathers 4 at a time — breaks the idx-load -> gather dependency
// chain (was 1 load in flight). Accumulation order unchanged -> bit-identical.
__global__ void gather_stats(const float* __restrict__ uv, const int* __restrict__ idx, int O,
                             float* __restrict__ ymax, float* __restrict__ ymin,
                             double* __restrict__ part, int ppb) {
    __shared__ double sd[256], sd2[256];
    int t = threadIdx.x;
    int R = 256 / O;
    int o = t % O;
    int q = t / O;
    double s = 0.0, s2 = 0.0;
    int p0 = blockIdx.x * ppb;
    int ld = 2 * O;
    for (int lp = q; lp < ppb; lp += R) {
        int p = p0 + lp;
        int base = (p >> 10) << 10;
        const int* ir = idx + (size_t)p * KNN;
        int4 i0 = *(const int4*)(ir);
        int4 i1 = *(const int4*)(ir + 4);
        int4 i2 = *(const int4*)(ir + 8);
        int4 i3 = *(const int4*)(ir + 12);
        int4 i4 = *(const int4*)(ir + 16);
        float v = uv[(size_t)p * ld + O + o];
        float mx = -3.4e38f, mn = 3.4e38f;
        #define G4(iv) { \
            float u0_ = uv[(size_t)(base + (iv).x) * ld + o]; \
            float u1_ = uv[(size_t)(base + (iv).y) * ld + o]; \
            float u2_ = uv[(size_t)(base + (iv).z) * ld + o]; \
            float u3_ = uv[(size_t)(base + (iv).w) * ld + o]; \
            float y0_ = u0_ + v, y1_ = u1_ + v, y2_ = u2_ + v, y3_ = u3_ + v; \
            mx = fmaxf(mx, y0_); mn = fminf(mn, y0_); s += (double)y0_; s2 += (double)y0_ * (double)y0_; \
            mx = fmaxf(mx, y1_); mn = fminf(mn, y1_); s += (double)y1_; s2 += (double)y1_ * (double)y1_; \
            mx = fmaxf(mx, y2_); mn = fminf(mn, y2_); s += (double)y2_; s2 += (double)y2_ * (double)y2_; \
            mx = fmaxf(mx, y3_); mn = fminf(mn, y3_); s += (double)y3_; s2 += (double)y3_ * (double)y3_; }
        G4(i0) G4(i1) G4(i2) G4(i3) G4(i4)
        #undef G4
        ymax[(size_t)p * O + o] = mx;
        ymin[(size_t)p * O + o] = mn;
    }
    sd[t] = s; sd2[t] = s2;
    __syncthreads();
    if (t < O) {
        double a = 0.0, a2 = 0.0;
        for (int qq = 0; qq < R; qq++) { a += sd[qq * O + t]; a2 += sd2[qq * O + t]; }
        part[(size_t)t * 1024 + blockIdx.x] = a;
        part[(size_t)(O + t) * 1024 + blockIdx.x] = a2;
    }
}

// ---------------- parallel finalize: one block per channel ------------------
__global__ void finalize_t(const double* __restrict__ part, int O,
                           const float* __restrict__ g, const float* __restrict__ bt,
                           float* __restrict__ scale, float* __restrict__ shift, double invCount) {
    __shared__ double sa[4], sb[4];
    int o = blockIdx.x;
    int t = threadIdx.x;
    int lane = t & 63, w = t >> 6;
    const double* ps = part + (size_t)o * 1024;
    const double* pq = part + (size_t)(O + o) * 1024;
    double s = 0.0, s2 = 0.0;
    #pragma unroll
    for (int b = 0; b < 4; b++) { s += ps[t + b * 256]; s2 += pq[t + b * 256]; }
    #pragma unroll
    for (int off = 32; off > 0; off >>= 1) { s += __shfl_xor(s, off, 64); s2 += __shfl_xor(s2, off, 64); }
    if (lane == 0) { sa[w] = s; sb[w] = s2; }
    __syncthreads();
    if (t == 0) {
        s = sa[0] + sa[1] + sa[2] + sa[3];
        s2 = sb[0] + sb[1] + sb[2] + sb[3];
        double mean = s * invCount;
        double var = s2 * invCount - mean * mean;
        if (var < 0.0) var = 0.0;
        float sc = (float)(1.0 / sqrt(var + 1e-5)) * g[o];
        scale[o] = sc;
        shift[o] = bt[o] - (float)mean * sc;
    }
}

// ---------------- parallel finalize for float partials (final conv) ---------
__global__ void finalize_f_t(const float* __restrict__ part,
                             const float* __restrict__ g, const float* __restrict__ bt,
                             float* __restrict__ scale, float* __restrict__ shift, double invCount) {
    __shared__ double sa[2], sb[2];
    int o = blockIdx.x;
    int t = threadIdx.x;   // 128 threads
    int lane = t & 63, w = t >> 6;
    double s  = (double)part[(size_t)o * 128 + t];
    double s2 = (double)part[131072 + (size_t)o * 128 + t];
    #pragma unroll
    for (int off = 32; off > 0; off >>= 1) { s += __shfl_xor(s, off, 64); s2 += __shfl_xor(s2, off, 64); }
    if (lane == 0) { sa[w] = s; sb[w] = s2; }
    __syncthreads();
    if (t == 0) {
        s = sa[0] + sa[1];
        s2 = sb[0] + sb[1];
        double mean = s * invCount;
        double var = s2 * invCount - mean * mean;
        if (var < 0.0) var = 0.0;
        float sc = (float)(1.0 / sqrt(var + 1e-5)) * g[o];
        scale[o] = sc;
        shift[o] = bt[o] - (float)mean * sc;
    }
}

// ---------------- edge conv epilogue: BN + leaky (max over k done) ----------
__global__ void apply_edge(const float* __restrict__ ymax, const float* __restrict__ ymin,
                           const float* __restrict__ scale, const float* __restrict__ shift,
                           float* __restrict__ xcat, int O, int off) {
    int i = blockIdx.x * 256 + threadIdx.x;
    if (i < P_ * O) {
        int p = i / O, o = i % O;
        float sc = scale[o];
        float y = (sc >= 0.f) ? ymax[i] : ymin[i];
        float val = y * sc + shift[o];
        xcat[(size_t)p * 512 + off + o] = LEAKY(val);
    }
}

// ---------------- pool partials: grid (16b, 16og, 4nz) = 1024 blocks --------
__global__ void pool_part(const float* __restrict__ h, const float* __restrict__ scale,
                          const float* __restrict__ shift,
                          float* __restrict__ pmax, double* __restrict__ psum) {
    __shared__ float smax[256];
    __shared__ double ssum[256];
    int b = blockIdx.x, og = blockIdx.y, nz = blockIdx.z;
    int t = threadIdx.x;
    int o = og * 64 + (t & 63);
    int ch = t >> 6;
    float sc = scale[o], sh = shift[o];
    float mx = -3.4e38f;
    double sm = 0.0;
    int n0 = nz * 256 + ch * 64;
    #pragma unroll 4
    for (int n = n0; n < n0 + 64; n++) {
        float y = h[((size_t)b * N_ + n) * 1024 + o] * sc + sh;
        y = LEAKY(y);
        mx = fmaxf(mx, y);
        sm += (double)y;
    }
    smax[t] = mx; ssum[t] = sm;
    __syncthreads();
    if (t < 64) {
        for (int c = 1; c < 4; c++) { mx = fmaxf(mx, smax[c * 64 + t]); sm += ssum[c * 64 + t]; }
        size_t pi = ((size_t)b * 4 + nz) * 1024 + o;
        pmax[pi] = mx;
        psum[pi] = sm;
    }
}

// ---------------- pool final: reduce 4 nz partials -> max / mean ------------
__global__ void pool_fin(const float* __restrict__ pmax, const double* __restrict__ psum,
                         float* __restrict__ pooled) {
    int b = blockIdx.x, og = blockIdx.y;
    int o = og * 256 + threadIdx.x;
    size_t base = (size_t)b * 4 * 1024 + o;
    float mx = pmax[base];
    double sm = psum[base];
    #pragma unroll
    for (int nz = 1; nz < 4; nz++) {
        mx = fmaxf(mx, pmax[base + nz * 1024]);
        sm += psum[base + nz * 1024];
    }
    pooled[(size_t)b * 2048 + o] = mx;
    pooled[(size_t)b * 2048 + 1024 + o] = (float)(sm * (1.0 / N_));
}

// ---------------- small FC: one wave per output -----------------------------
__global__ void fc_kernel(const float* __restrict__ in, int ldi,
                          const float* __restrict__ w, int ldw,
                          const float* __restrict__ bias,
                          float* __restrict__ out, int M, int Nn, int K) {
    int gw = (blockIdx.x * 256 + threadIdx.x) >> 6;
    int lane = threadIdx.x & 63;
    if (gw >= M * Nn) return;
    int m = gw / Nn, n = gw % Nn;
    const float* a = in + (size_t)m * ldi;
    const float* ww = w + (size_t)n * ldw;
    float s = 0.f;
    for (int kk = lane; kk < K; kk += 64) s += a[kk] * ww[kk];
    #pragma unroll
    for (int off = 32; off > 0; off >>= 1) s += __shfl_xor(s, off, 64);
    if (lane == 0) out[(size_t)m * Nn + n] = s + bias[n];
}

// ---------------- BN over batch axis (M=16) + leaky, in place ---------------
__global__ void bn_rows(float* __restrict__ z, int M, int O,
                        const float* __restrict__ g, const float* __restrict__ bt) {
    int o = blockIdx.x * 256 + threadIdx.x;
    if (o >= O) return;
    double s = 0.0, s2 = 0.0;
    for (int m = 0; m < M; m++) {
        float y = z[(size_t)m * O + o];
        s += (double)y; s2 += (double)y * (double)y;
    }
    double mean = s / M;
    double var = s2 / M - mean * mean;
    if (var < 0.0) var = 0.0;
    float sc = (float)(1.0 / sqrt(var + 1e-5)) * g[o];
    float sh = bt[o] - (float)mean * sc;
    for (int m = 0; m < M; m++) {
        float y = z[(size_t)m * O + o] * sc + sh;
        z[(size_t)m * O + o] = LEAKY(y);
    }
}

extern "C" void kernel_launch(void* const* d_in, const int* in_sizes, int n_in,
                              void* d_out, int out_size, void* d_ws, size_t ws_size,
                              hipStream_t stream) {
    const float* cloud = (const float*)d_in[0];
    const float* wf  = (const float*)d_in[17];
    const float* gf  = (const float*)d_in[19];
    const float* btf = (const float*)d_in[20];
    const float* wl1 = (const float*)d_in[21];
    const float* bl1 = (const float*)d_in[22];
    const float* gl1 = (const float*)d_in[23];
    const float* btl1= (const float*)d_in[24];
    const float* wl2 = (const float*)d_in[25];
    const float* bl2 = (const float*)d_in[26];
    const float* gl2 = (const float*)d_in[27];
    const float* btl2= (const float*)d_in[28];
    const float* wl3 = (const float*)d_in[29];
    const float* bl3 = (const float*)d_in[30];

    // workspace layout (bytes)
    const size_t OFF_XCAT  = 0;                        // 33554432
    const size_t OFF_UV    = 33554432;                 // 33554432 (A2 aliases UV+YMAX)
    const size_t OFF_YMAX  = 67108864;                 // 16777216 (xA alias: 12.6MB max)
    const size_t OFF_YMIN  = 83886080;                 // 16777216 (B2 alias)
    const size_t OFF_DIST  = 100663296;                // 67108864 (aliased as hraw)
    const size_t OFF_IDX   = 167772160;                // 1310720
    const size_t OFF_XX    = 169082880;                // 65536
    const size_t OFF_W2    = 169148416;                // 524288
    const size_t OFF_PART  = 169676800;                // 4194304: part doubles / partf / pool partials
    const size_t OFF_SCALE = 173871104;                // 4096
    const size_t OFF_SHIFT = 173875200;                // 4096
    const size_t OFF_POOL  = 173879296;                // 131072
    const size_t OFF_Z1    = 174010368;                // 32768
    const size_t OFF_Z2    = 174043136;                // 16384
    const size_t TOTAL     = 174059520;
    if (ws_size < TOTAL) return;

    char* ws = (char*)d_ws;
    float* xcat  = (float*)(ws + OFF_XCAT);
    float* uv    = (float*)(ws + OFF_UV);
    float* ymax  = (float*)(ws + OFF_YMAX);
    float* ymin  = (float*)(ws + OFF_YMIN);
    float* dist  = (float*)(ws + OFF_DIST);
    float* hraw  = (float*)(ws + OFF_DIST);
    ushort* A2   = (ushort*)(ws + OFF_UV);
    ushort* B2   = (ushort*)(ws + OFF_YMIN);
    ushort* xA   = (ushort*)(ws + OFF_YMAX);
    ushort* WB2  = (ushort*)(ws + OFF_PART);
    int*   idx   = (int*)  (ws + OFF_IDX);
    float* xx    = (float*)(ws + OFF_XX);
    float* W2    = (float*)(ws + OFF_W2);
    double* part = (double*)(ws + OFF_PART);
    float* partf = (float*)(ws + OFF_PART);
    float* ppmax = (float*)(ws + OFF_PART + 2097152);   // 16*4*1024 f = 256KB
    double* ppsum= (double*)(ws + OFF_PART + 2359296);  // 16*4*1024 d = 512KB
    float* scale = (float*)(ws + OFF_SCALE);
    float* shift = (float*)(ws + OFF_SHIFT);
    float* pooled= (float*)(ws + OFF_POOL);
    float* z1    = (float*)(ws + OFF_Z1);
    float* z2    = (float*)(ws + OFF_Z2);

    const int Cs[4]   = {3, 64, 64, 128};
    const int Os[4]   = {64, 64, 128, 256};
    const int offs[4] = {0, 64, 128, 256};

    for (int L = 0; L < 4; L++) {
        int C = Cs[L], O = Os[L];
        const float* w  = (const float*)d_in[1 + 4 * L];
        const float* g  = (const float*)d_in[3 + 4 * L];
        const float* bt = (const float*)d_in[4 + 4 * L];
        const float* x  = (L == 0) ? cloud : (xcat + offs[L - 1]);
        int lda = (L == 0) ? 3 : 512;

        sqnorm<<<(P_ + 255) / 256, 256, 0, stream>>>(x, lda, C, xx);
        dist_kernel<<<dim3(136, 16), 256, 0, stream>>>(x, lda, C, xx, dist);
        topk_kernel<<<(P_ * 64) / 256, 256, 0, stream>>>(dist, idx);

        if (L == 0) {
            prep_w2<<<(2 * O * C + 255) / 256, 256, 0, stream>>>(w, W2, O, C);
            gemm_wt<<<dim3(2 * O / 64, P_ / 64), 256, 0, stream>>>(x, lda, W2, C, uv, 2 * O, C);
        } else {
            int K3 = 3 * C, nkt = K3 / 64;
            conv_split<<<(P_ * (C / 4) + 255) / 256, 256, 0, stream>>>(x, lda, C, P_, xA, 0);
            prep_w2_split<<<(2 * O * (C / 4) + 255) / 256, 256, 0, stream>>>(w, WB2, O, C);
            gemm_mfma<0><<<dim3(2 * O / 128, 128), 256, 0, stream>>>(xA, WB2, K3, nkt, uv, 2 * O, nullptr);
        }

        gather_stats<<<1024, 256, 0, stream>>>(uv, idx, O, ymax, ymin, part, 16);
        finalize_t<<<O, 256, 0, stream>>>(part, O, g, bt, scale, shift, 1.0 / ((double)P_ * KNN));
        apply_edge<<<(P_ * O + 255) / 256, 256, 0, stream>>>(ymax, ymin, scale, shift, xcat, O, offs[L]);
    }

    // final 1x1 conv via split-bf16 MFMA GEMM with fused (transposed) col stats
    conv_split<<<(P_ * 128 + 255) / 256, 256, 0, stream>>>(xcat, 512, 512, P_, A2, 0);
    conv_split<<<(1024 * 128 + 255) / 256, 256, 0, stream>>>(wf, 512, 512, 1024, B2, 1);
    gemm_mfma<2><<<dim3(8, 128), 256, 0, stream>>>(A2, B2, 1536, 24, hraw, 1024, partf);

    finalize_f_t<<<1024, 128, 0, stream>>>(partf, gf, btf, scale, shift, 1.0 / (double)P_);
    pool_part<<<dim3(16, 16, 4), 256, 0, stream>>>(hraw, scale, shift, ppmax, ppsum);
    pool_fin<<<dim3(16, 4), 256, 0, stream>>>(ppmax, ppsum, pooled);

    // MLP head
    fc_kernel<<<(16 * 512 * 64) / 256, 256, 0, stream>>>(pooled, 2048, wl1, 2048, bl1, z1, 16, 512, 2048);
    bn_rows<<<2, 256, 0, stream>>>(z1, 16, 512, gl1, btl1);
    fc_kernel<<<(16 * 256 * 64) / 256, 256, 0, stream>>>(z1, 512, wl2, 512, bl2, z2, 16, 256, 512);
    bn_rows<<<1, 256, 0, stream>>>(z2, 16, 256, gl2, btl2);
    fc_kernel<<<(16 * 40 * 64 + 255) / 256, 256, 0, stream>>>(z2, 256, wl3, 256, bl3, (float*)d_out, 16, 40, 256);
}

// Round 20
// 692.683 us; speedup vs baseline: 1.1124x; 1.0353x over previous
//
#include <hip/hip_runtime.h>

#define LEAKY(v) ((v) >= 0.f ? (v) : 0.2f*(v))

static const int B_ = 16;
static const int N_ = 1024;
static const int P_ = 16384;   // B*N
static const int KNN = 20;

typedef __attribute__((ext_vector_type(8))) short short8v;
typedef __attribute__((ext_vector_type(4))) float f32x4;

__device__ inline ushort f2bf(float f) {
    unsigned u = __float_as_uint(f);
    unsigned r = u + 0x7FFFu + ((u >> 16) & 1u);
    return (ushort)(r >> 16);
}
__device__ inline float bf2f(ushort h) {
    return __uint_as_float(((unsigned)h) << 16);
}

// ---------------- prep: W2 = [wA ; wB - wA] fp32 (layer-1 only) -------------
__global__ void prep_w2(const float* __restrict__ w, float* __restrict__ W2, int O, int C) {
    int i = blockIdx.x * 256 + threadIdx.x;
    int total = 2 * O * C;
    if (i < total) {
        int row = i / C, c = i % C;
        float val;
        if (row < O) val = w[row * 2 * C + c];
        else { int o = row - O; val = w[o * 2 * C + C + c] - w[o * 2 * C + c]; }
        W2[i] = val;
    }
}

// ---------------- prep W2 and split to bf16 [h|l|h] in one pass (L>=1) ------
__global__ void prep_w2_split(const float* __restrict__ w, ushort* __restrict__ WB2, int O, int C) {
    int i = blockIdx.x * 256 + threadIdx.x;
    int cpr = C >> 2;
    if (i >= 2 * O * cpr) return;
    int row = i / cpr, c4 = (i % cpr) * 4;
    float vv[4];
    #pragma unroll
    for (int j = 0; j < 4; j++) {
        int c = c4 + j;
        if (row < O) vv[j] = w[row * 2 * C + c];
        else { int o = row - O; vv[j] = w[o * 2 * C + C + c] - w[o * 2 * C + c]; }
    }
    ushort4 h, l;
    h.x = f2bf(vv[0]); l.x = f2bf(vv[0] - bf2f(h.x));
    h.y = f2bf(vv[1]); l.y = f2bf(vv[1] - bf2f(h.y));
    h.z = f2bf(vv[2]); l.z = f2bf(vv[2] - bf2f(h.z));
    h.w = f2bf(vv[3]); l.w = f2bf(vv[3] - bf2f(h.w));
    ushort* rowp = WB2 + (size_t)row * 3 * C + c4;
    *(ushort4*)(rowp)         = h;
    *(ushort4*)(rowp + C)     = l;
    *(ushort4*)(rowp + 2 * C) = h;
}

// ---------------- squared norms (float4 path for C>=4) ----------------------
__global__ void sqnorm(const float* __restrict__ x, int lda, int C, float* __restrict__ xx) {
    int p = blockIdx.x * 256 + threadIdx.x;
    if (p >= P_) return;
    const float* r = x + (size_t)p * lda;
    float s = 0.f;
    if ((C & 3) == 0) {
        for (int c = 0; c < C; c += 4) {
            float4 v = *(const float4*)&r[c];
            s += v.x * v.x + v.y * v.y + v.z * v.z + v.w * v.w;
        }
    } else {
        for (int c = 0; c < C; c++) s += r[c] * r[c];
    }
    xx[p] = s;
}

// ---------------- fp32 -> split-bf16 rows. mode0: [h|h|l], mode1: [h|l|h] ---
__global__ void conv_split(const float* __restrict__ src, int ld, int C, int rows,
                           ushort* __restrict__ dst, int mode) {
    int i = blockIdx.x * 256 + threadIdx.x;
    int cpr = C >> 2;
    if (i >= rows * cpr) return;
    int p = i / cpr, c4 = (i % cpr) * 4;
    float4 v = *(const float4*)(src + (size_t)p * ld + c4);
    ushort4 h, l;
    h.x = f2bf(v.x); l.x = f2bf(v.x - bf2f(h.x));
    h.y = f2bf(v.y); l.y = f2bf(v.y - bf2f(h.y));
    h.z = f2bf(v.z); l.z = f2bf(v.z - bf2f(h.z));
    h.w = f2bf(v.w); l.w = f2bf(v.w - bf2f(h.w));
    ushort* row = dst + (size_t)p * 3 * C + c4;
    if (mode == 0) {
        *(ushort4*)(row)         = h;
        *(ushort4*)(row + C)     = h;
        *(ushort4*)(row + 2 * C) = l;
    } else {
        *(ushort4*)(row)         = h;
        *(ushort4*)(row + C)     = l;
        *(ushort4*)(row + 2 * C) = h;
    }
}

// ---------------- fp32 dist (all layers): 2*dot - xx_n - xx_m ---------------
// 64x64 tile, 4x4/thread, LDS-transposed mirror store; triangular linear grid.
// fp32 mandatory: split-bf16 dist flips near-tie kNN (R3).
__global__ void dist_kernel(const float* __restrict__ x, int lda, int C,
                            const float* __restrict__ xx, float* __restrict__ dist) {
    int t = blockIdx.x;
    int mi = (int)((sqrtf(8.f * (float)t + 1.f) - 1.f) * 0.5f);
    while ((mi + 1) * (mi + 2) / 2 <= t) mi++;
    while (mi * (mi + 1) / 2 > t) mi--;
    int nj = t - mi * (mi + 1) / 2;
    int m0 = mi * 64, n0 = nj * 64;
    __shared__ float As[16][68];
    __shared__ float Bs[16][68];
    __shared__ float Ts[64][68];
    int b = blockIdx.y;
    const float* xb = x + (size_t)b * N_ * lda;
    int tid = threadIdx.x;
    int tx = tid & 15, ty = tid >> 4;
    float acc[4][4] = {};
    for (int k0 = 0; k0 < C; k0 += 16) {
        for (int l = tid; l < 1024; l += 256) {
            int r = l >> 4, kk = l & 15, kg = k0 + kk;
            As[kk][r] = (kg < C) ? xb[(size_t)(n0 + r) * lda + kg] : 0.f;
            Bs[kk][r] = (kg < C) ? xb[(size_t)(m0 + r) * lda + kg] : 0.f;
        }
        __syncthreads();
        #pragma unroll
        for (int kk = 0; kk < 16; kk++) {
            float4 a4 = *(const float4*)&As[kk][ty * 4];
            float4 w4 = *(const float4*)&Bs[kk][tx * 4];
            float a[4] = {a4.x, a4.y, a4.z, a4.w};
            float w[4] = {w4.x, w4.y, w4.z, w4.w};
            #pragma unroll
            for (int i = 0; i < 4; i++)
                #pragma unroll
                for (int j = 0; j < 4; j++) acc[i][j] += a[i] * w[j];
        }
        __syncthreads();
    }
    size_t prow = (size_t)b * N_;
    #pragma unroll
    for (int i = 0; i < 4; i++) {
        int n = n0 + ty * 4 + i;
        float xn = xx[b * N_ + n];
        float4 v4;
        float vt[4];
        #pragma unroll
        for (int j = 0; j < 4; j++) {
            int m = m0 + tx * 4 + j;
            float v = 2.f * acc[i][j] - xn - xx[b * N_ + m];
            vt[j] = v;
            Ts[tx * 4 + j][ty * 4 + i] = v;   // Ts[m - m0][n - n0]
        }
        v4.x = vt[0]; v4.y = vt[1]; v4.z = vt[2]; v4.w = vt[3];
        *(float4*)&dist[(prow + n) * N_ + m0 + tx * 4] = v4;
    }
    if (m0 != n0) {
        __syncthreads();
        #pragma unroll
        for (int i = 0; i < 4; i++) {
            int mi2 = ty * 4 + i;
            float4 v4 = *(const float4*)&Ts[mi2][tx * 4];
            *(float4*)&dist[(prow + m0 + mi2) * N_ + n0 + tx * 4] = v4;
        }
    }
}

// ---------------- top-k=20 per row; one wave per row ------------------------
// Named-scalar bitonic + head-extract (best measured form; VALU-bound ~69us).
#define CE(a,b,up) { bool p_ = (v##b > v##a) || (v##b == v##a && c##b < c##a); \
                     bool s_ = (up) ? p_ : !p_; \
                     float tv_ = v##a; int tc_ = c##a; \
                     v##a = s_ ? v##b : v##a; c##a = s_ ? c##b : c##a; \
                     v##b = s_ ? tv_ : v##b;  c##b = s_ ? tc_ : c##b; }
__global__ __launch_bounds__(256, 4)
void topk_kernel(const float* __restrict__ dist, int* __restrict__ idx) {
    int wave = (blockIdx.x * 256 + threadIdx.x) >> 6;
    int lane = threadIdx.x & 63;
    if (wave >= P_) return;
    const float* row = dist + (size_t)wave * N_;
    int cb = lane * 4;
    float4 q0 = *(const float4*)&row[cb];
    float4 q1 = *(const float4*)&row[256 + cb];
    float4 q2 = *(const float4*)&row[512 + cb];
    float4 q3 = *(const float4*)&row[768 + cb];
    float v0 = q0.x, v1 = q0.y, v2 = q0.z, v3 = q0.w;
    float v4 = q1.x, v5 = q1.y, v6 = q1.z, v7 = q1.w;
    float v8 = q2.x, v9 = q2.y, v10 = q2.z, v11 = q2.w;
    float v12 = q3.x, v13 = q3.y, v14 = q3.z, v15 = q3.w;
    int c0 = cb, c1 = cb + 1, c2 = cb + 2, c3 = cb + 3;
    int c4 = 256 + cb, c5 = 256 + cb + 1, c6 = 256 + cb + 2, c7 = 256 + cb + 3;
    int c8 = 512 + cb, c9 = 512 + cb + 1, c10 = 512 + cb + 2, c11 = 512 + cb + 3;
    int c12 = 768 + cb, c13 = 768 + cb + 1, c14 = 768 + cb + 2, c15 = 768 + cb + 3;

    CE(0,1,true) CE(2,3,false) CE(4,5,true) CE(6,7,false)
    CE(8,9,true) CE(10,11,false) CE(12,13,true) CE(14,15,false)
    CE(0,2,true) CE(1,3,true) CE(4,6,false) CE(5,7,false)
    CE(8,10,true) CE(9,11,true) CE(12,14,false) CE(13,15,false)
    CE(0,1,true) CE(2,3,true) CE(4,5,false) CE(6,7,false)
    CE(8,9,true) CE(10,11,true) CE(12,13,false) CE(14,15,false)
    CE(0,4,true) CE(1,5,true) CE(2,6,true) CE(3,7,true)
    CE(8,12,false) CE(9,13,false) CE(10,14,false) CE(11,15,false)
    CE(0,2,true) CE(1,3,true) CE(4,6,true) CE(5,7,true)
    CE(8,10,false) CE(9,11,false) CE(12,14,false) CE(13,15,false)
    CE(0,1,true) CE(2,3,true) CE(4,5,true) CE(6,7,true)
    CE(8,9,false) CE(10,11,false) CE(12,13,false) CE(14,15,false)
    CE(0,8,true) CE(1,9,true) CE(2,10,true) CE(3,11,true)
    CE(4,12,true) CE(5,13,true) CE(6,14,true) CE(7,15,true)
    CE(0,4,true) CE(1,5,true) CE(2,6,true) CE(3,7,true)
    CE(8,12,true) CE(9,13,true) CE(10,14,true) CE(11,15,true)
    CE(0,2,true) CE(1,3,true) CE(4,6,true) CE(5,7,true)
    CE(8,10,true) CE(9,11,true) CE(12,14,true) CE(13,15,true)
    CE(0,1,true) CE(2,3,true) CE(4,5,true) CE(6,7,true)
    CE(8,9,true) CE(10,11,true) CE(12,13,true) CE(14,15,true)

    int* out = idx + (size_t)wave * KNN;
    #pragma unroll 1
    for (int it = 0; it < KNN; it++) {
        float bv = v0; int bc = c0;
        #pragma unroll
        for (int off = 32; off > 0; off >>= 1) {
            float ov = __shfl_xor(bv, off, 64);
            int   oc = __shfl_xor(bc, off, 64);
            if (ov > bv || (ov == bv && oc < bc)) { bv = ov; bc = oc; }
        }
        if (lane == 0) out[it] = bc;
        int wc = __builtin_amdgcn_readfirstlane(bc);
        bool mine = (c0 == wc);
        v0 = mine ? v1 : v0;   c0 = mine ? c1 : c0;
        v1 = mine ? v2 : v1;   c1 = mine ? c2 : c1;
        v2 = mine ? v3 : v2;   c2 = mine ? c3 : c2;
        v3 = mine ? v4 : v3;   c3 = mine ? c4 : c3;
        v4 = mine ? v5 : v4;   c4 = mine ? c5 : c4;
        v5 = mine ? v6 : v5;   c5 = mine ? c6 : c5;
        v6 = mine ? v7 : v6;   c6 = mine ? c7 : c6;
        v7 = mine ? v8 : v7;   c7 = mine ? c8 : c7;
        v8 = mine ? v9 : v8;   c8 = mine ? c9 : c8;
        v9 = mine ? v10 : v9;  c9 = mine ? c10 : c9;
        v10 = mine ? v11 : v10; c10 = mine ? c11 : c10;
        v11 = mine ? v12 : v11; c11 = mine ? c12 : c11;
        v12 = mine ? v13 : v12; c12 = mine ? c13 : c12;
        v13 = mine ? v14 : v13; c13 = mine ? c14 : c13;
        v14 = mine ? v15 : v14; c14 = mine ? c15 : c14;
        v15 = mine ? -3.4e38f : v15;
    }
}
#undef CE

// ---------------- fp32 GEMM (layer-1 uv only, K=3) --------------------------
__global__ void gemm_wt(const float* __restrict__ A, int lda,
                        const float* __restrict__ W, int ldw,
                        float* __restrict__ out, int ldo, int K) {
    __shared__ float As[16][68];
    __shared__ float Ws[16][68];
    int m0 = blockIdx.y * 64, n0 = blockIdx.x * 64;
    int tid = threadIdx.x;
    int tx = tid & 15, ty = tid >> 4;
    float acc[4][4] = {};
    for (int k0 = 0; k0 < K; k0 += 16) {
        for (int l = tid; l < 1024; l += 256) {
            int r = l >> 4, kk = l & 15, kg = k0 + kk;
            As[kk][r] = (kg < K) ? A[(size_t)(m0 + r) * lda + kg] : 0.f;
            Ws[kk][r] = (kg < K) ? W[(size_t)(n0 + r) * ldw + kg] : 0.f;
        }
        __syncthreads();
        #pragma unroll
        for (int kk = 0; kk < 16; kk++) {
            float4 a4 = *(const float4*)&As[kk][ty * 4];
            float4 w4 = *(const float4*)&Ws[kk][tx * 4];
            float a[4] = {a4.x, a4.y, a4.z, a4.w};
            float w[4] = {w4.x, w4.y, w4.z, w4.w};
            #pragma unroll
            for (int i = 0; i < 4; i++)
                #pragma unroll
                for (int j = 0; j < 4; j++) acc[i][j] += a[i] * w[j];
        }
        __syncthreads();
    }
    for (int i = 0; i < 4; i++) {
        int m = m0 + ty * 4 + i;
        for (int j = 0; j < 4; j++) {
            int n = n0 + tx * 4 + j;
            out[(size_t)m * ldo + n] = acc[i][j];
        }
    }
}

// ---------------- unified split-bf16 MFMA GEMM ------------------------------
// MODE 0: uv; MODE 2: final conv + fused transposed col stats.
// Bijective XCD swizzle (R12): each XCD owns a contiguous y-band.
template<int MODE>
__global__ __launch_bounds__(256, 2)
void gemm_mfma(const ushort* __restrict__ A, const ushort* __restrict__ Bw,
               int K, int nkt, float* __restrict__ out, int ldo,
               float* __restrict__ part) {
    __shared__ ushort lA[128 * 64];
    __shared__ ushort lB[128 * 64];
    int tid = threadIdx.x;
    int lane = tid & 63;
    int wid = tid >> 6;
    int wr = wid >> 1, wc = wid & 1;

    int nx = gridDim.x;
    int ypb = gridDim.y >> 3;
    int bid = blockIdx.y * nx + blockIdx.x;
    int xcd = bid & 7, pos = bid >> 3;
    int yy = xcd * ypb + pos / nx;
    int xx2 = pos % nx;
    int m0 = yy * 128, n0 = xx2 * 128;

    const ushort* pA = A + (size_t)m0 * K;
    const ushort* pB = Bw + (size_t)n0 * K;
    int rowu = tid >> 3, kcu = (tid & 7) * 8;

    f32x4 acc[4][4] = {};
    short8v ra[4], rb[4];
    #pragma unroll
    for (int j = 0; j < 4; j++) {
        int row = rowu + j * 32;
        ra[j] = *(const short8v*)(pA + (size_t)row * K + kcu);
        rb[j] = *(const short8v*)(pB + (size_t)row * K + kcu);
    }

    for (int kt = 0; kt < nkt; kt++) {
        __syncthreads();
        #pragma unroll
        for (int j = 0; j < 4; j++) {
            int row = rowu + j * 32;
            int off = (row * 128 + kcu * 2) ^ ((row & 7) << 4);
            *(short8v*)((char*)lA + off) = ra[j];
            *(short8v*)((char*)lB + off) = rb[j];
        }
        __syncthreads();
        if (kt < nkt - 1) {
            int kbase = (kt + 1) * 64 + kcu;
            #pragma unroll
            for (int j = 0; j < 4; j++) {
                int row = rowu + j * 32;
                ra[j] = *(const short8v*)(pA + (size_t)row * K + kbase);
                rb[j] = *(const short8v*)(pB + (size_t)row * K + kbase);
            }
        }
        #pragma unroll
        for (int ks = 0; ks < 2; ks++) {
            short8v af[4], bg[4];
            int kb2 = (ks * 32 + ((lane >> 4) << 3)) * 2;
            #pragma unroll
            for (int mb = 0; mb < 4; mb++) {
                int row = wr * 64 + mb * 16 + (lane & 15);
                int off = (row * 128 + kb2) ^ ((row & 7) << 4);
                af[mb] = *(const short8v*)((const char*)lA + off);
            }
            #pragma unroll
            for (int nb = 0; nb < 4; nb++) {
                int row = wc * 64 + nb * 16 + (lane & 15);
                int off = (row * 128 + kb2) ^ ((row & 7) << 4);
                bg[nb] = *(const short8v*)((const char*)lB + off);
            }
            #pragma unroll
            for (int mb = 0; mb < 4; mb++)
                #pragma unroll
                for (int nb = 0; nb < 4; nb++)
                    acc[mb][nb] = __builtin_amdgcn_mfma_f32_16x16x32_bf16(af[mb], bg[nb], acc[mb][nb], 0, 0, 0);
        }
    }

    int rbase = m0 + wr * 64 + ((lane >> 4) << 2);
    int cbase = n0 + wc * 64 + (lane & 15);

    if (MODE == 0) {
        #pragma unroll
        for (int mb = 0; mb < 4; mb++)
            #pragma unroll
            for (int nb = 0; nb < 4; nb++)
                #pragma unroll
                for (int r = 0; r < 4; r++)
                    out[(size_t)(rbase + mb * 16 + r) * ldo + cbase + nb * 16] = acc[mb][nb][r];
    } else {
        float* smS = (float*)lA;
        float* smQ = (float*)lB;
        __syncthreads();
        #pragma unroll
        for (int nb = 0; nb < 4; nb++) {
            float s = 0.f, q = 0.f;
            #pragma unroll
            for (int mb = 0; mb < 4; mb++)
                #pragma unroll
                for (int r = 0; r < 4; r++) {
                    float v = acc[mb][nb][r];
                    out[(size_t)(rbase + mb * 16 + r) * ldo + cbase + nb * 16] = v;
                    s += v; q += v * v;
                }
            s += __shfl_xor(s, 16, 64); s += __shfl_xor(s, 32, 64);
            q += __shfl_xor(q, 16, 64); q += __shfl_xor(q, 32, 64);
            if ((lane >> 4) == 0) {
                smS[wid * 64 + nb * 16 + lane] = s;
                smQ[wid * 64 + nb * 16 + lane] = q;
            }
        }
        __syncthreads();
        if (tid < 128) {
            int wcs = tid >> 6, c = tid & 63;
            float s = smS[wcs * 64 + c] + smS[(2 + wcs) * 64 + c];
            float q = smQ[wcs * 64 + c] + smQ[(2 + wcs) * 64 + c];
            int col = n0 + wcs * 64 + c;
            part[(size_t)col * 128 + yy] = s;
            part[131072 + (size_t)col * 128 + yy] = q;
        }
    }
}

// ---------------- gather neighbors, per-(p,o) max/min, per-channel stats ----
// int4-preloaded indices; gathers issued 4 at a time (R19, bit-identical).
__global__ void gather_stats(const float* __restrict__ uv, const int* __restrict__ idx, int O,
                             float* __restrict__ ymax, float* __restrict__ ymin,
                             double* __restrict__ part, int ppb) {
    __shared__ double sd[256], sd2[256];
    int t = threadIdx.x;
    int R = 256 / O;
    int o = t % O;
    int q = t / O;
    double s = 0.0, s2 = 0.0;
    int p0 = blockIdx.x * ppb;
    int ld = 2 * O;
    for (int lp = q; lp < ppb; lp += R) {
        int p = p0 + lp;
        int base = (p >> 10) << 10;
        const int* ir = idx + (size_t)p * KNN;
        int4 i0 = *(const int4*)(ir);
        int4 i1 = *(const int4*)(ir + 4);
        int4 i2 = *(const int4*)(ir + 8);
        int4 i3 = *(const int4*)(ir + 12);
        int4 i4 = *(const int4*)(ir + 16);
        float v = uv[(size_t)p * ld + O + o];
        float mx = -3.4e38f, mn = 3.4e38f;
        #define G4(iv) { \
            float u0_ = uv[(size_t)(base + (iv).x) * ld + o]; \
            float u1_ = uv[(size_t)(base + (iv).y) * ld + o]; \
            float u2_ = uv[(size_t)(base + (iv).z) * ld + o]; \
            float u3_ = uv[(size_t)(base + (iv).w) * ld + o]; \
            float y0_ = u0_ + v, y1_ = u1_ + v, y2_ = u2_ + v, y3_ = u3_ + v; \
            mx = fmaxf(mx, y0_); mn = fminf(mn, y0_); s += (double)y0_; s2 += (double)y0_ * (double)y0_; \
            mx = fmaxf(mx, y1_); mn = fminf(mn, y1_); s += (double)y1_; s2 += (double)y1_ * (double)y1_; \
            mx = fmaxf(mx, y2_); mn = fminf(mn, y2_); s += (double)y2_; s2 += (double)y2_ * (double)y2_; \
            mx = fmaxf(mx, y3_); mn = fminf(mn, y3_); s += (double)y3_; s2 += (double)y3_ * (double)y3_; }
        G4(i0) G4(i1) G4(i2) G4(i3) G4(i4)
        #undef G4
        ymax[(size_t)p * O + o] = mx;
        ymin[(size_t)p * O + o] = mn;
    }
    sd[t] = s; sd2[t] = s2;
    __syncthreads();
    if (t < O) {
        double a = 0.0, a2 = 0.0;
        for (int qq = 0; qq < R; qq++) { a += sd[qq * O + t]; a2 += sd2[qq * O + t]; }
        part[(size_t)t * 1024 + blockIdx.x] = a;
        part[(size_t)(O + t) * 1024 + blockIdx.x] = a2;
    }
}

// ---------------- parallel finalize: one block per channel ------------------
__global__ void finalize_t(const double* __restrict__ part, int O,
                           const float* __restrict__ g, const float* __restrict__ bt,
                           float* __restrict__ scale, float* __restrict__ shift, double invCount) {
    __shared__ double sa[4], sb[4];
    int o = blockIdx.x;
    int t = threadIdx.x;
    int lane = t & 63, w = t >> 6;
    const double* ps = part + (size_t)o * 1024;
    const double* pq = part + (size_t)(O + o) * 1024;
    double s = 0.0, s2 = 0.0;
    #pragma unroll
    for (int b = 0; b < 4; b++) { s += ps[t + b * 256]; s2 += pq[t + b * 256]; }
    #pragma unroll
    for (int off = 32; off > 0; off >>= 1) { s += __shfl_xor(s, off, 64); s2 += __shfl_xor(s2, off, 64); }
    if (lane == 0) { sa[w] = s; sb[w] = s2; }
    __syncthreads();
    if (t == 0) {
        s = sa[0] + sa[1] + sa[2] + sa[3];
        s2 = sb[0] + sb[1] + sb[2] + sb[3];
        double mean = s * invCount;
        double var = s2 * invCount - mean * mean;
        if (var < 0.0) var = 0.0;
        float sc = (float)(1.0 / sqrt(var + 1e-5)) * g[o];
        scale[o] = sc;
        shift[o] = bt[o] - (float)mean * sc;
    }
}

// ---------------- parallel finalize for float partials (final conv) ---------
__global__ void finalize_f_t(const float* __restrict__ part,
                             const float* __restrict__ g, const float* __restrict__ bt,
                             float* __restrict__ scale, float* __restrict__ shift, double invCount) {
    __shared__ double sa[2], sb[2];
    int o = blockIdx.x;
    int t = threadIdx.x;   // 128 threads
    int lane = t & 63, w = t >> 6;
    double s  = (double)part[(size_t)o * 128 + t];
    double s2 = (double)part[131072 + (size_t)o * 128 + t];
    #pragma unroll
    for (int off = 32; off > 0; off >>= 1) { s += __shfl_xor(s, off, 64); s2 += __shfl_xor(s2, off, 64); }
    if (lane == 0) { sa[w] = s; sb[w] = s2; }
    __syncthreads();
    if (t == 0) {
        s = sa[0] + sa[1];
        s2 = sb[0] + sb[1];
        double mean = s * invCount;
        double var = s2 * invCount - mean * mean;
        if (var < 0.0) var = 0.0;
        float sc = (float)(1.0 / sqrt(var + 1e-5)) * g[o];
        scale[o] = sc;
        shift[o] = bt[o] - (float)mean * sc;
    }
}

// ---------------- edge conv epilogue: BN + leaky, float4 (R20) --------------
__global__ void apply_edge(const float* __restrict__ ymax, const float* __restrict__ ymin,
                           const float* __restrict__ scale, const float* __restrict__ shift,
                           float* __restrict__ xcat, int O, int off) {
    int i = blockIdx.x * 256 + threadIdx.x;
    int oq = O >> 2;
    if (i >= P_ * oq) return;
    int p = i / oq, o4 = (i % oq) * 4;
    float4 mx = *(const float4*)&ymax[(size_t)p * O + o4];
    float4 mn = *(const float4*)&ymin[(size_t)p * O + o4];
    float4 sc = *(const float4*)&scale[off + o4] - *(const float4*)&scale[off + o4] + *(const float4*)&scale[o4 + 0];
    // NOTE: scale/shift are indexed by o within this layer (0..O), not off.
    sc = *(const float4*)&scale[o4];
    float4 sh = *(const float4*)&shift[o4];
    float4 r;
    float y0 = (sc.x >= 0.f) ? mx.x : mn.x;
    float y1 = (sc.y >= 0.f) ? mx.y : mn.y;
    float y2 = (sc.z >= 0.f) ? mx.z : mn.z;
    float y3 = (sc.w >= 0.f) ? mx.w : mn.w;
    float a0 = y0 * sc.x + sh.x, a1 = y1 * sc.y + sh.y;
    float a2 = y2 * sc.z + sh.z, a3 = y3 * sc.w + sh.w;
    r.x = LEAKY(a0); r.y = LEAKY(a1); r.z = LEAKY(a2); r.w = LEAKY(a3);
    *(float4*)&xcat[(size_t)p * 512 + off + o4] = r;
}

// ---------------- pool partials: grid (16b, 16og, 4nz) = 1024 blocks --------
__global__ void pool_part(const float* __restrict__ h, const float* __restrict__ scale,
                          const float* __restrict__ shift,
                          float* __restrict__ pmax, double* __restrict__ psum) {
    __shared__ float smax[256];
    __shared__ double ssum[256];
    int b = blockIdx.x, og = blockIdx.y, nz = blockIdx.z;
    int t = threadIdx.x;
    int o = og * 64 + (t & 63);
    int ch = t >> 6;
    float sc = scale[o], sh = shift[o];
    float mx = -3.4e38f;
    double sm = 0.0;
    int n0 = nz * 256 + ch * 64;
    #pragma unroll 4
    for (int n = n0; n < n0 + 64; n++) {
        float y = h[((size_t)b * N_ + n) * 1024 + o] * sc + sh;
        y = LEAKY(y);
        mx = fmaxf(mx, y);
        sm += (double)y;
    }
    smax[t] = mx; ssum[t] = sm;
    __syncthreads();
    if (t < 64) {
        for (int c = 1; c < 4; c++) { mx = fmaxf(mx, smax[c * 64 + t]); sm += ssum[c * 64 + t]; }
        size_t pi = ((size_t)b * 4 + nz) * 1024 + o;
        pmax[pi] = mx;
        psum[pi] = sm;
    }
}

// ---------------- pool final: reduce 4 nz partials -> max / mean ------------
__global__ void pool_fin(const float* __restrict__ pmax, const double* __restrict__ psum,
                         float* __restrict__ pooled) {
    int b = blockIdx.x, og = blockIdx.y;
    int o = og * 256 + threadIdx.x;
    size_t base = (size_t)b * 4 * 1024 + o;
    float mx = pmax[base];
    double sm = psum[base];
    #pragma unroll
    for (int nz = 1; nz < 4; nz++) {
        mx = fmaxf(mx, pmax[base + nz * 1024]);
        sm += psum[base + nz * 1024];
    }
    pooled[(size_t)b * 2048 + o] = mx;
    pooled[(size_t)b * 2048 + 1024 + o] = (float)(sm * (1.0 / N_));
}

// ---------------- small FC: one wave per output -----------------------------
__global__ void fc_kernel(const float* __restrict__ in, int ldi,
                          const float* __restrict__ w, int ldw,
                          const float* __restrict__ bias,
                          float* __restrict__ out, int M, int Nn, int K) {
    int gw = (blockIdx.x * 256 + threadIdx.x) >> 6;
    int lane = threadIdx.x & 63;
    if (gw >= M * Nn) return;
    int m = gw / Nn, n = gw % Nn;
    const float* a = in + (size_t)m * ldi;
    const float* ww = w + (size_t)n * ldw;
    float s = 0.f;
    for (int kk = lane; kk < K; kk += 64) s += a[kk] * ww[kk];
    #pragma unroll
    for (int off = 32; off > 0; off >>= 1) s += __shfl_xor(s, off, 64);
    if (lane == 0) out[(size_t)m * Nn + n] = s + bias[n];
}

// ---------------- BN over batch axis (M=16) + leaky, in place ---------------
__global__ void bn_rows(float* __restrict__ z, int M, int O,
                        const float* __restrict__ g, const float* __restrict__ bt) {
    int o = blockIdx.x * 256 + threadIdx.x;
    if (o >= O) return;
    double s = 0.0, s2 = 0.0;
    for (int m = 0; m < M; m++) {
        float y = z[(size_t)m * O + o];
        s += (double)y; s2 += (double)y * (double)y;
    }
    double mean = s / M;
    double var = s2 / M - mean * mean;
    if (var < 0.0) var = 0.0;
    float sc = (float)(1.0 / sqrt(var + 1e-5)) * g[o];
    float sh = bt[o] - (float)mean * sc;
    for (int m = 0; m < M; m++) {
        float y = z[(size_t)m * O + o] * sc + sh;
        z[(size_t)m * O + o] = LEAKY(y);
    }
}

extern "C" void kernel_launch(void* const* d_in, const int* in_sizes, int n_in,
                              void* d_out, int out_size, void* d_ws, size_t ws_size,
                              hipStream_t stream) {
    const float* cloud = (const float*)d_in[0];
    const float* wf  = (const float*)d_in[17];
    const float* gf  = (const float*)d_in[19];
    const float* btf = (const float*)d_in[20];
    const float* wl1 = (const float*)d_in[21];
    const float* bl1 = (const float*)d_in[22];
    const float* gl1 = (const float*)d_in[23];
    const float* btl1= (const float*)d_in[24];
    const float* wl2 = (const float*)d_in[25];
    const float* bl2 = (const float*)d_in[26];
    const float* gl2 = (const float*)d_in[27];
    const float* btl2= (const float*)d_in[28];
    const float* wl3 = (const float*)d_in[29];
    const float* bl3 = (const float*)d_in[30];

    // workspace layout (bytes)
    const size_t OFF_XCAT  = 0;                        // 33554432
    const size_t OFF_UV    = 33554432;                 // 33554432 (A2 aliases UV+YMAX)
    const size_t OFF_YMAX  = 67108864;                 // 16777216 (xA alias: 12.6MB max)
    const size_t OFF_YMIN  = 83886080;                 // 16777216 (B2 alias)
    const size_t OFF_DIST  = 100663296;                // 67108864 (aliased as hraw)
    const size_t OFF_IDX   = 167772160;                // 1310720
    const size_t OFF_XX    = 169082880;                // 65536
    const size_t OFF_W2    = 169148416;                // 524288
    const size_t OFF_PART  = 169676800;                // 4194304: part doubles / partf / pool partials
    const size_t OFF_SCALE = 173871104;                // 4096
    const size_t OFF_SHIFT = 173875200;                // 4096
    const size_t OFF_POOL  = 173879296;                // 131072
    const size_t OFF_Z1    = 174010368;                // 32768
    const size_t OFF_Z2    = 174043136;                // 16384
    const size_t TOTAL     = 174059520;
    if (ws_size < TOTAL) return;

    char* ws = (char*)d_ws;
    float* xcat  = (float*)(ws + OFF_XCAT);
    float* uv    = (float*)(ws + OFF_UV);
    float* ymax  = (float*)(ws + OFF_YMAX);
    float* ymin  = (float*)(ws + OFF_YMIN);
    float* dist  = (float*)(ws + OFF_DIST);
    float* hraw  = (float*)(ws + OFF_DIST);
    ushort* A2   = (ushort*)(ws + OFF_UV);
    ushort* B2   = (ushort*)(ws + OFF_YMIN);
    ushort* xA   = (ushort*)(ws + OFF_YMAX);
    ushort* WB2  = (ushort*)(ws + OFF_PART);
    int*   idx   = (int*)  (ws + OFF_IDX);
    float* xx    = (float*)(ws + OFF_XX);
    float* W2    = (float*)(ws + OFF_W2);
    double* part = (double*)(ws + OFF_PART);
    float* partf = (float*)(ws + OFF_PART);
    float* ppmax = (float*)(ws + OFF_PART + 2097152);   // 256KB
    double* ppsum= (double*)(ws + OFF_PART + 2359296);  // 512KB
    float* scale = (float*)(ws + OFF_SCALE);
    float* shift = (float*)(ws + OFF_SHIFT);
    float* pooled= (float*)(ws + OFF_POOL);
    float* z1    = (float*)(ws + OFF_Z1);
    float* z2    = (float*)(ws + OFF_Z2);

    const int Cs[4]   = {3, 64, 64, 128};
    const int Os[4]   = {64, 64, 128, 256};
    const int offs[4] = {0, 64, 128, 256};

    for (int L = 0; L < 4; L++) {
        int C = Cs[L], O = Os[L];
        const float* w  = (const float*)d_in[1 + 4 * L];
        const float* g  = (const float*)d_in[3 + 4 * L];
        const float* bt = (const float*)d_in[4 + 4 * L];
        const float* x  = (L == 0) ? cloud : (xcat + offs[L - 1]);
        int lda = (L == 0) ? 3 : 512;

        sqnorm<<<(P_ + 255) / 256, 256, 0, stream>>>(x, lda, C, xx);
        dist_kernel<<<dim3(136, 16), 256, 0, stream>>>(x, lda, C, xx, dist);
        topk_kernel<<<(P_ * 64) / 256, 256, 0, stream>>>(dist, idx);

        if (L == 0) {
            prep_w2<<<(2 * O * C + 255) / 256, 256, 0, stream>>>(w, W2, O, C);
            gemm_wt<<<dim3(2 * O / 64, P_ / 64), 256, 0, stream>>>(x, lda, W2, C, uv, 2 * O, C);
        } else {
            int K3 = 3 * C, nkt = K3 / 64;
            conv_split<<<(P_ * (C / 4) + 255) / 256, 256, 0, stream>>>(x, lda, C, P_, xA, 0);
            prep_w2_split<<<(2 * O * (C / 4) + 255) / 256, 256, 0, stream>>>(w, WB2, O, C);
            gemm_mfma<0><<<dim3(2 * O / 128, 128), 256, 0, stream>>>(xA, WB2, K3, nkt, uv, 2 * O, nullptr);
        }

        gather_stats<<<1024, 256, 0, stream>>>(uv, idx, O, ymax, ymin, part, 16);
        finalize_t<<<O, 256, 0, stream>>>(part, O, g, bt, scale, shift, 1.0 / ((double)P_ * KNN));
        apply_edge<<<(P_ * (O / 4) + 255) / 256, 256, 0, stream>>>(ymax, ymin, scale, shift, xcat, O, offs[L]);
    }

    // final 1x1 conv via split-bf16 MFMA GEMM with fused (transposed) col stats
    conv_split<<<(P_ * 128 + 255) / 256, 256, 0, stream>>>(xcat, 512, 512, P_, A2, 0);
    conv_split<<<(1024 * 128 + 255) / 256, 256, 0, stream>>>(wf, 512, 512, 1024, B2, 1);
    gemm_mfma<2><<<dim3(8, 128), 256, 0, stream>>>(A2, B2, 1536, 24, hraw, 1024, partf);

    finalize_f_t<<<1024, 128, 0, stream>>>(partf, gf, btf, scale, shift, 1.0 / (double)P_);
    pool_part<<<dim3(16, 16, 4), 256, 0, stream>>>(hraw, scale, shift, ppmax, ppsum);
    pool_fin<<<dim3(16, 4), 256, 0, stream>>>(ppmax, ppsum, pooled);

    // MLP head
    fc_kernel<<<(16 * 512 * 64) / 256, 256, 0, stream>>>(pooled, 2048, wl1, 2048, bl1, z1, 16, 512, 2048);
    bn_rows<<<2, 256, 0, stream>>>(z1, 16, 512, gl1, btl1);
    fc_kernel<<<(16 * 256 * 64) / 256, 256, 0, stream>>>(z1, 512, wl2, 512, bl2, z2, 16, 256, 512);
    bn_rows<<<1, 256, 0, stream>>>(z2, 16, 256, gl2, btl2);
    fc_kernel<<<(16 * 40 * 64 + 255) / 256, 256, 0, stream>>>(z2, 256, wl3, 256, bl3, (float*)d_out, 16, 40, 256);
}

// Round 21
// 656.719 us; speedup vs baseline: 1.1733x; 1.0548x over previous
//
#include <hip/hip_runtime.h>

#define LEAKY(v) ((v) >= 0.f ? (v) : 0.2f*(v))

static const int B_ = 16;
static const int N_ = 1024;
static const int P_ = 16384;   // B*N
static const int KNN = 20;

typedef __attribute__((ext_vector_type(8))) short short8v;
typedef __attribute__((ext_vector_type(4))) float f32x4;

__device__ inline ushort f2bf(float f) {
    unsigned u = __float_as_uint(f);
    unsigned r = u + 0x7FFFu + ((u >> 16) & 1u);
    return (ushort)(r >> 16);
}
__device__ inline float bf2f(ushort h) {
    return __uint_as_float(((unsigned)h) << 16);
}

// ---------------- prep: W2 = [wA ; wB - wA] fp32 (layer-1 only) -------------
__global__ void prep_w2(const float* __restrict__ w, float* __restrict__ W2, int O, int C) {
    int i = blockIdx.x * 256 + threadIdx.x;
    int total = 2 * O * C;
    if (i < total) {
        int row = i / C, c = i % C;
        float val;
        if (row < O) val = w[row * 2 * C + c];
        else { int o = row - O; val = w[o * 2 * C + C + c] - w[o * 2 * C + c]; }
        W2[i] = val;
    }
}

// ---------------- prep W2 and split to bf16 [h|l|h] in one pass (L>=1) ------
__global__ void prep_w2_split(const float* __restrict__ w, ushort* __restrict__ WB2, int O, int C) {
    int i = blockIdx.x * 256 + threadIdx.x;
    int cpr = C >> 2;
    if (i >= 2 * O * cpr) return;
    int row = i / cpr, c4 = (i % cpr) * 4;
    float vv[4];
    #pragma unroll
    for (int j = 0; j < 4; j++) {
        int c = c4 + j;
        if (row < O) vv[j] = w[row * 2 * C + c];
        else { int o = row - O; vv[j] = w[o * 2 * C + C + c] - w[o * 2 * C + c]; }
    }
    ushort4 h, l;
    h.x = f2bf(vv[0]); l.x = f2bf(vv[0] - bf2f(h.x));
    h.y = f2bf(vv[1]); l.y = f2bf(vv[1] - bf2f(h.y));
    h.z = f2bf(vv[2]); l.z = f2bf(vv[2] - bf2f(h.z));
    h.w = f2bf(vv[3]); l.w = f2bf(vv[3] - bf2f(h.w));
    ushort* rowp = WB2 + (size_t)row * 3 * C + c4;
    *(ushort4*)(rowp)         = h;
    *(ushort4*)(rowp + C)     = l;
    *(ushort4*)(rowp + 2 * C) = h;
}

// ---------------- squared norms (float4 path for C>=4) ----------------------
__global__ void sqnorm(const float* __restrict__ x, int lda, int C, float* __restrict__ xx) {
    int p = blockIdx.x * 256 + threadIdx.x;
    if (p >= P_) return;
    const float* r = x + (size_t)p * lda;
    float s = 0.f;
    if ((C & 3) == 0) {
        for (int c = 0; c < C; c += 4) {
            float4 v = *(const float4*)&r[c];
            s += v.x * v.x + v.y * v.y + v.z * v.z + v.w * v.w;
        }
    } else {
        for (int c = 0; c < C; c++) s += r[c] * r[c];
    }
    xx[p] = s;
}

// ---------------- fp32 -> split-bf16 rows. mode0: [h|h|l], mode1: [h|l|h] ---
__global__ void conv_split(const float* __restrict__ src, int ld, int C, int rows,
                           ushort* __restrict__ dst, int mode) {
    int i = blockIdx.x * 256 + threadIdx.x;
    int cpr = C >> 2;
    if (i >= rows * cpr) return;
    int p = i / cpr, c4 = (i % cpr) * 4;
    float4 v = *(const float4*)(src + (size_t)p * ld + c4);
    ushort4 h, l;
    h.x = f2bf(v.x); l.x = f2bf(v.x - bf2f(h.x));
    h.y = f2bf(v.y); l.y = f2bf(v.y - bf2f(h.y));
    h.z = f2bf(v.z); l.z = f2bf(v.z - bf2f(h.z));
    h.w = f2bf(v.w); l.w = f2bf(v.w - bf2f(h.w));
    ushort* row = dst + (size_t)p * 3 * C + c4;
    if (mode == 0) {
        *(ushort4*)(row)         = h;
        *(ushort4*)(row + C)     = h;
        *(ushort4*)(row + 2 * C) = l;
    } else {
        *(ushort4*)(row)         = h;
        *(ushort4*)(row + C)     = l;
        *(ushort4*)(row + 2 * C) = h;
    }
}

// ---------------- fp32 dist (all layers): 2*dot - xx_n - xx_m ---------------
// 64x64 tile, 4x4/thread, LDS-transposed mirror store; triangular linear grid.
// fp32 mandatory: split-bf16 dist flips near-tie kNN (R3).
__global__ void dist_kernel(const float* __restrict__ x, int lda, int C,
                            const float* __restrict__ xx, float* __restrict__ dist) {
    int t = blockIdx.x;
    int mi = (int)((sqrtf(8.f * (float)t + 1.f) - 1.f) * 0.5f);
    while ((mi + 1) * (mi + 2) / 2 <= t) mi++;
    while (mi * (mi + 1) / 2 > t) mi--;
    int nj = t - mi * (mi + 1) / 2;
    int m0 = mi * 64, n0 = nj * 64;
    __shared__ float As[16][68];
    __shared__ float Bs[16][68];
    __shared__ float Ts[64][68];
    int b = blockIdx.y;
    const float* xb = x + (size_t)b * N_ * lda;
    int tid = threadIdx.x;
    int tx = tid & 15, ty = tid >> 4;
    float acc[4][4] = {};
    for (int k0 = 0; k0 < C; k0 += 16) {
        for (int l = tid; l < 1024; l += 256) {
            int r = l >> 4, kk = l & 15, kg = k0 + kk;
            As[kk][r] = (kg < C) ? xb[(size_t)(n0 + r) * lda + kg] : 0.f;
            Bs[kk][r] = (kg < C) ? xb[(size_t)(m0 + r) * lda + kg] : 0.f;
        }
        __syncthreads();
        #pragma unroll
        for (int kk = 0; kk < 16; kk++) {
            float4 a4 = *(const float4*)&As[kk][ty * 4];
            float4 w4 = *(const float4*)&Bs[kk][tx * 4];
            float a[4] = {a4.x, a4.y, a4.z, a4.w};
            float w[4] = {w4.x, w4.y, w4.z, w4.w};
            #pragma unroll
            for (int i = 0; i < 4; i++)
                #pragma unroll
                for (int j = 0; j < 4; j++) acc[i][j] += a[i] * w[j];
        }
        __syncthreads();
    }
    size_t prow = (size_t)b * N_;
    #pragma unroll
    for (int i = 0; i < 4; i++) {
        int n = n0 + ty * 4 + i;
        float xn = xx[b * N_ + n];
        float4 v4;
        float vt[4];
        #pragma unroll
        for (int j = 0; j < 4; j++) {
            int m = m0 + tx * 4 + j;
            float v = 2.f * acc[i][j] - xn - xx[b * N_ + m];
            vt[j] = v;
            Ts[tx * 4 + j][ty * 4 + i] = v;   // Ts[m - m0][n - n0]
        }
        v4.x = vt[0]; v4.y = vt[1]; v4.z = vt[2]; v4.w = vt[3];
        *(float4*)&dist[(prow + n) * N_ + m0 + tx * 4] = v4;
    }
    if (m0 != n0) {
        __syncthreads();
        #pragma unroll
        for (int i = 0; i < 4; i++) {
            int mi2 = ty * 4 + i;
            float4 v4 = *(const float4*)&Ts[mi2][tx * 4];
            *(float4*)&dist[(prow + m0 + mi2) * N_ + n0 + tx * 4] = v4;
        }
    }
}

// ---------------- top-k=20 per row; one wave per row ------------------------
// R21: split the paired (value,col) butterfly into a pure fmax butterfly +
// ballot-equivalent min-col butterfly. Tie-break preserved exactly: within a
// lane the bitonic head is the lowest-col max; across lanes, min col among
// lanes whose head == vmax == lax.top_k order. Cols unique -> exact winner.
#define CE(a,b,up) { bool p_ = (v##b > v##a) || (v##b == v##a && c##b < c##a); \
                     bool s_ = (up) ? p_ : !p_; \
                     float tv_ = v##a; int tc_ = c##a; \
                     v##a = s_ ? v##b : v##a; c##a = s_ ? c##b : c##a; \
                     v##b = s_ ? tv_ : v##b;  c##b = s_ ? tc_ : c##b; }
__global__ __launch_bounds__(256, 4)
void topk_kernel(const float* __restrict__ dist, int* __restrict__ idx) {
    int wave = (blockIdx.x * 256 + threadIdx.x) >> 6;
    int lane = threadIdx.x & 63;
    if (wave >= P_) return;
    const float* row = dist + (size_t)wave * N_;
    int cb = lane * 4;
    float4 q0 = *(const float4*)&row[cb];
    float4 q1 = *(const float4*)&row[256 + cb];
    float4 q2 = *(const float4*)&row[512 + cb];
    float4 q3 = *(const float4*)&row[768 + cb];
    float v0 = q0.x, v1 = q0.y, v2 = q0.z, v3 = q0.w;
    float v4 = q1.x, v5 = q1.y, v6 = q1.z, v7 = q1.w;
    float v8 = q2.x, v9 = q2.y, v10 = q2.z, v11 = q2.w;
    float v12 = q3.x, v13 = q3.y, v14 = q3.z, v15 = q3.w;
    int c0 = cb, c1 = cb + 1, c2 = cb + 2, c3 = cb + 3;
    int c4 = 256 + cb, c5 = 256 + cb + 1, c6 = 256 + cb + 2, c7 = 256 + cb + 3;
    int c8 = 512 + cb, c9 = 512 + cb + 1, c10 = 512 + cb + 2, c11 = 512 + cb + 3;
    int c12 = 768 + cb, c13 = 768 + cb + 1, c14 = 768 + cb + 2, c15 = 768 + cb + 3;

    CE(0,1,true) CE(2,3,false) CE(4,5,true) CE(6,7,false)
    CE(8,9,true) CE(10,11,false) CE(12,13,true) CE(14,15,false)
    CE(0,2,true) CE(1,3,true) CE(4,6,false) CE(5,7,false)
    CE(8,10,true) CE(9,11,true) CE(12,14,false) CE(13,15,false)
    CE(0,1,true) CE(2,3,true) CE(4,5,false) CE(6,7,false)
    CE(8,9,true) CE(10,11,true) CE(12,13,false) CE(14,15,false)
    CE(0,4,true) CE(1,5,true) CE(2,6,true) CE(3,7,true)
    CE(8,12,false) CE(9,13,false) CE(10,14,false) CE(11,15,false)
    CE(0,2,true) CE(1,3,true) CE(4,6,true) CE(5,7,true)
    CE(8,10,false) CE(9,11,false) CE(12,14,false) CE(13,15,false)
    CE(0,1,true) CE(2,3,true) CE(4,5,true) CE(6,7,true)
    CE(8,9,false) CE(10,11,false) CE(12,13,false) CE(14,15,false)
    CE(0,8,true) CE(1,9,true) CE(2,10,true) CE(3,11,true)
    CE(4,12,true) CE(5,13,true) CE(6,14,true) CE(7,15,true)
    CE(0,4,true) CE(1,5,true) CE(2,6,true) CE(3,7,true)
    CE(8,12,true) CE(9,13,true) CE(10,14,true) CE(11,15,true)
    CE(0,2,true) CE(1,3,true) CE(4,6,true) CE(5,7,true)
    CE(8,10,true) CE(9,11,true) CE(12,14,true) CE(13,15,true)
    CE(0,1,true) CE(2,3,true) CE(4,5,true) CE(6,7,true)
    CE(8,9,true) CE(10,11,true) CE(12,13,true) CE(14,15,true)

    int* out = idx + (size_t)wave * KNN;
    #pragma unroll 1
    for (int it = 0; it < KNN; it++) {
        // pure value max-reduce (6 shfl + 6 fmax)
        float sv = v0;
        #pragma unroll
        for (int off = 32; off > 0; off >>= 1)
            sv = fmaxf(sv, __shfl_xor(sv, off, 64));
        // min-col among lanes holding the max (6 shfl + 6 min)
        int cc = (v0 == sv) ? c0 : 0x7FFFFFFF;
        #pragma unroll
        for (int off = 32; off > 0; off >>= 1) {
            int oc = __shfl_xor(cc, off, 64);
            cc = (oc < cc) ? oc : cc;
        }
        if (lane == 0) out[it] = cc;
        int wc = __builtin_amdgcn_readfirstlane(cc);
        bool mine = (c0 == wc);
        v0 = mine ? v1 : v0;   c0 = mine ? c1 : c0;
        v1 = mine ? v2 : v1;   c1 = mine ? c2 : c1;
        v2 = mine ? v3 : v2;   c2 = mine ? c3 : c2;
        v3 = mine ? v4 : v3;   c3 = mine ? c4 : c3;
        v4 = mine ? v5 : v4;   c4 = mine ? c5 : c4;
        v5 = mine ? v6 : v5;   c5 = mine ? c6 : c5;
        v6 = mine ? v7 : v6;   c6 = mine ? c7 : c6;
        v7 = mine ? v8 : v7;   c7 = mine ? c8 : c7;
        v8 = mine ? v9 : v8;   c8 = mine ? c9 : c8;
        v9 = mine ? v10 : v9;  c9 = mine ? c10 : c9;
        v10 = mine ? v11 : v10; c10 = mine ? c11 : c10;
        v11 = mine ? v12 : v11; c11 = mine ? c12 : c11;
        v12 = mine ? v13 : v12; c12 = mine ? c13 : c12;
        v13 = mine ? v14 : v13; c13 = mine ? c14 : c13;
        v14 = mine ? v15 : v14; c14 = mine ? c15 : c14;
        v15 = mine ? -3.4e38f : v15;
    }
}
#undef CE

// ---------------- fp32 GEMM (layer-1 uv only, K=3) --------------------------
__global__ void gemm_wt(const float* __restrict__ A, int lda,
                        const float* __restrict__ W, int ldw,
                        float* __restrict__ out, int ldo, int K) {
    __shared__ float As[16][68];
    __shared__ float Ws[16][68];
    int m0 = blockIdx.y * 64, n0 = blockIdx.x * 64;
    int tid = threadIdx.x;
    int tx = tid & 15, ty = tid >> 4;
    float acc[4][4] = {};
    for (int k0 = 0; k0 < K; k0 += 16) {
        for (int l = tid; l < 1024; l += 256) {
            int r = l >> 4, kk = l & 15, kg = k0 + kk;
            As[kk][r] = (kg < K) ? A[(size_t)(m0 + r) * lda + kg] : 0.f;
            Ws[kk][r] = (kg < K) ? W[(size_t)(n0 + r) * ldw + kg] : 0.f;
        }
        __syncthreads();
        #pragma unroll
        for (int kk = 0; kk < 16; kk++) {
            float4 a4 = *(const float4*)&As[kk][ty * 4];
            float4 w4 = *(const float4*)&Ws[kk][tx * 4];
            float a[4] = {a4.x, a4.y, a4.z, a4.w};
            float w[4] = {w4.x, w4.y, w4.z, w4.w};
            #pragma unroll
            for (int i = 0; i < 4; i++)
                #pragma unroll
                for (int j = 0; j < 4; j++) acc[i][j] += a[i] * w[j];
        }
        __syncthreads();
    }
    for (int i = 0; i < 4; i++) {
        int m = m0 + ty * 4 + i;
        for (int j = 0; j < 4; j++) {
            int n = n0 + tx * 4 + j;
            out[(size_t)m * ldo + n] = acc[i][j];
        }
    }
}

// ---------------- unified split-bf16 MFMA GEMM ------------------------------
// MODE 0: uv; MODE 2: final conv + fused transposed col stats.
// Bijective XCD swizzle (R12): each XCD owns a contiguous y-band.
template<int MODE>
__global__ __launch_bounds__(256, 2)
void gemm_mfma(const ushort* __restrict__ A, const ushort* __restrict__ Bw,
               int K, int nkt, float* __restrict__ out, int ldo,
               float* __restrict__ part) {
    __shared__ ushort lA[128 * 64];
    __shared__ ushort lB[128 * 64];
    int tid = threadIdx.x;
    int lane = tid & 63;
    int wid = tid >> 6;
    int wr = wid >> 1, wc = wid & 1;

    int nx = gridDim.x;
    int ypb = gridDim.y >> 3;
    int bid = blockIdx.y * nx + blockIdx.x;
    int xcd = bid & 7, pos = bid >> 3;
    int yy = xcd * ypb + pos / nx;
    int xx2 = pos % nx;
    int m0 = yy * 128, n0 = xx2 * 128;

    const ushort* pA = A + (size_t)m0 * K;
    const ushort* pB = Bw + (size_t)n0 * K;
    int rowu = tid >> 3, kcu = (tid & 7) * 8;

    f32x4 acc[4][4] = {};
    short8v ra[4], rb[4];
    #pragma unroll
    for (int j = 0; j < 4; j++) {
        int row = rowu + j * 32;
        ra[j] = *(const short8v*)(pA + (size_t)row * K + kcu);
        rb[j] = *(const short8v*)(pB + (size_t)row * K + kcu);
    }

    for (int kt = 0; kt < nkt; kt++) {
        __syncthreads();
        #pragma unroll
        for (int j = 0; j < 4; j++) {
            int row = rowu + j * 32;
            int off = (row * 128 + kcu * 2) ^ ((row & 7) << 4);
            *(short8v*)((char*)lA + off) = ra[j];
            *(short8v*)((char*)lB + off) = rb[j];
        }
        __syncthreads();
        if (kt < nkt - 1) {
            int kbase = (kt + 1) * 64 + kcu;
            #pragma unroll
            for (int j = 0; j < 4; j++) {
                int row = rowu + j * 32;
                ra[j] = *(const short8v*)(pA + (size_t)row * K + kbase);
                rb[j] = *(const short8v*)(pB + (size_t)row * K + kbase);
            }
        }
        #pragma unroll
        for (int ks = 0; ks < 2; ks++) {
            short8v af[4], bg[4];
            int kb2 = (ks * 32 + ((lane >> 4) << 3)) * 2;
            #pragma unroll
            for (int mb = 0; mb < 4; mb++) {
                int row = wr * 64 + mb * 16 + (lane & 15);
                int off = (row * 128 + kb2) ^ ((row & 7) << 4);
                af[mb] = *(const short8v*)((const char*)lA + off);
            }
            #pragma unroll
            for (int nb = 0; nb < 4; nb++) {
                int row = wc * 64 + nb * 16 + (lane & 15);
                int off = (row * 128 + kb2) ^ ((row & 7) << 4);
                bg[nb] = *(const short8v*)((const char*)lB + off);
            }
            #pragma unroll
            for (int mb = 0; mb < 4; mb++)
                #pragma unroll
                for (int nb = 0; nb < 4; nb++)
                    acc[mb][nb] = __builtin_amdgcn_mfma_f32_16x16x32_bf16(af[mb], bg[nb], acc[mb][nb], 0, 0, 0);
        }
    }

    int rbase = m0 + wr * 64 + ((lane >> 4) << 2);
    int cbase = n0 + wc * 64 + (lane & 15);

    if (MODE == 0) {
        #pragma unroll
        for (int mb = 0; mb < 4; mb++)
            #pragma unroll
            for (int nb = 0; nb < 4; nb++)
                #pragma unroll
                for (int r = 0; r < 4; r++)
                    out[(size_t)(rbase + mb * 16 + r) * ldo + cbase + nb * 16] = acc[mb][nb][r];
    } else {
        float* smS = (float*)lA;
        float* smQ = (float*)lB;
        __syncthreads();
        #pragma unroll
        for (int nb = 0; nb < 4; nb++) {
            float s = 0.f, q = 0.f;
            #pragma unroll
            for (int mb = 0; mb < 4; mb++)
                #pragma unroll
                for (int r = 0; r < 4; r++) {
                    float v = acc[mb][nb][r];
                    out[(size_t)(rbase + mb * 16 + r) * ldo + cbase + nb * 16] = v;
                    s += v; q += v * v;
                }
            s += __shfl_xor(s, 16, 64); s += __shfl_xor(s, 32, 64);
            q += __shfl_xor(q, 16, 64); q += __shfl_xor(q, 32, 64);
            if ((lane >> 4) == 0) {
                smS[wid * 64 + nb * 16 + lane] = s;
                smQ[wid * 64 + nb * 16 + lane] = q;
            }
        }
        __syncthreads();
        if (tid < 128) {
            int wcs = tid >> 6, c = tid & 63;
            float s = smS[wcs * 64 + c] + smS[(2 + wcs) * 64 + c];
            float q = smQ[wcs * 64 + c] + smQ[(2 + wcs) * 64 + c];
            int col = n0 + wcs * 64 + c;
            part[(size_t)col * 128 + yy] = s;
            part[131072 + (size_t)col * 128 + yy] = q;
        }
    }
}

// ---------------- gather neighbors, per-(p,o) max/min, per-channel stats ----
// int4-preloaded indices; gathers issued 4 at a time (R19, bit-identical).
__global__ void gather_stats(const float* __restrict__ uv, const int* __restrict__ idx, int O,
                             float* __restrict__ ymax, float* __restrict__ ymin,
                             double* __restrict__ part, int ppb) {
    __shared__ double sd[256], sd2[256];
    int t = threadIdx.x;
    int R = 256 / O;
    int o = t % O;
    int q = t / O;
    double s = 0.0, s2 = 0.0;
    int p0 = blockIdx.x * ppb;
    int ld = 2 * O;
    for (int lp = q; lp < ppb; lp += R) {
        int p = p0 + lp;
        int base = (p >> 10) << 10;
        const int* ir = idx + (size_t)p * KNN;
        int4 i0 = *(const int4*)(ir);
        int4 i1 = *(const int4*)(ir + 4);
        int4 i2 = *(const int4*)(ir + 8);
        int4 i3 = *(const int4*)(ir + 12);
        int4 i4 = *(const int4*)(ir + 16);
        float v = uv[(size_t)p * ld + O + o];
        float mx = -3.4e38f, mn = 3.4e38f;
        #define G4(iv) { \
            float u0_ = uv[(size_t)(base + (iv).x) * ld + o]; \
            float u1_ = uv[(size_t)(base + (iv).y) * ld + o]; \
            float u2_ = uv[(size_t)(base + (iv).z) * ld + o]; \
            float u3_ = uv[(size_t)(base + (iv).w) * ld + o]; \
            float y0_ = u0_ + v, y1_ = u1_ + v, y2_ = u2_ + v, y3_ = u3_ + v; \
            mx = fmaxf(mx, y0_); mn = fminf(mn, y0_); s += (double)y0_; s2 += (double)y0_ * (double)y0_; \
            mx = fmaxf(mx, y1_); mn = fminf(mn, y1_); s += (double)y1_; s2 += (double)y1_ * (double)y1_; \
            mx = fmaxf(mx, y2_); mn = fminf(mn, y2_); s += (double)y2_; s2 += (double)y2_ * (double)y2_; \
            mx = fmaxf(mx, y3_); mn = fminf(mn, y3_); s += (double)y3_; s2 += (double)y3_ * (double)y3_; }
        G4(i0) G4(i1) G4(i2) G4(i3) G4(i4)
        #undef G4
        ymax[(size_t)p * O + o] = mx;
        ymin[(size_t)p * O + o] = mn;
    }
    sd[t] = s; sd2[t] = s2;
    __syncthreads();
    if (t < O) {
        double a = 0.0, a2 = 0.0;
        for (int qq = 0; qq < R; qq++) { a += sd[qq * O + t]; a2 += sd2[qq * O + t]; }
        part[(size_t)t * 1024 + blockIdx.x] = a;
        part[(size_t)(O + t) * 1024 + blockIdx.x] = a2;
    }
}

// ---------------- parallel finalize: one block per channel ------------------
__global__ void finalize_t(const double* __restrict__ part, int O,
                           const float* __restrict__ g, const float* __restrict__ bt,
                           float* __restrict__ scale, float* __restrict__ shift, double invCount) {
    __shared__ double sa[4], sb[4];
    int o = blockIdx.x;
    int t = threadIdx.x;
    int lane = t & 63, w = t >> 6;
    const double* ps = part + (size_t)o * 1024;
    const double* pq = part + (size_t)(O + o) * 1024;
    double s = 0.0, s2 = 0.0;
    #pragma unroll
    for (int b = 0; b < 4; b++) { s += ps[t + b * 256]; s2 += pq[t + b * 256]; }
    #pragma unroll
    for (int off = 32; off > 0; off >>= 1) { s += __shfl_xor(s, off, 64); s2 += __shfl_xor(s2, off, 64); }
    if (lane == 0) { sa[w] = s; sb[w] = s2; }
    __syncthreads();
    if (t == 0) {
        s = sa[0] + sa[1] + sa[2] + sa[3];
        s2 = sb[0] + sb[1] + sb[2] + sb[3];
        double mean = s * invCount;
        double var = s2 * invCount - mean * mean;
        if (var < 0.0) var = 0.0;
        float sc = (float)(1.0 / sqrt(var + 1e-5)) * g[o];
        scale[o] = sc;
        shift[o] = bt[o] - (float)mean * sc;
    }
}

// ---------------- parallel finalize for float partials (final conv) ---------
__global__ void finalize_f_t(const float* __restrict__ part,
                             const float* __restrict__ g, const float* __restrict__ bt,
                             float* __restrict__ scale, float* __restrict__ shift, double invCount) {
    __shared__ double sa[2], sb[2];
    int o = blockIdx.x;
    int t = threadIdx.x;   // 128 threads
    int lane = t & 63, w = t >> 6;
    double s  = (double)part[(size_t)o * 128 + t];
    double s2 = (double)part[131072 + (size_t)o * 128 + t];
    #pragma unroll
    for (int off = 32; off > 0; off >>= 1) { s += __shfl_xor(s, off, 64); s2 += __shfl_xor(s2, off, 64); }
    if (lane == 0) { sa[w] = s; sb[w] = s2; }
    __syncthreads();
    if (t == 0) {
        s = sa[0] + sa[1];
        s2 = sb[0] + sb[1];
        double mean = s * invCount;
        double var = s2 * invCount - mean * mean;
        if (var < 0.0) var = 0.0;
        float sc = (float)(1.0 / sqrt(var + 1e-5)) * g[o];
        scale[o] = sc;
        shift[o] = bt[o] - (float)mean * sc;
    }
}

// ---------------- edge conv epilogue: BN + leaky, float4 --------------------
__global__ void apply_edge(const float* __restrict__ ymax, const float* __restrict__ ymin,
                           const float* __restrict__ scale, const float* __restrict__ shift,
                           float* __restrict__ xcat, int O, int off) {
    int i = blockIdx.x * 256 + threadIdx.x;
    int oq = O >> 2;
    if (i >= P_ * oq) return;
    int p = i / oq, o4 = (i % oq) * 4;
    float4 mx = *(const float4*)&ymax[(size_t)p * O + o4];
    float4 mn = *(const float4*)&ymin[(size_t)p * O + o4];
    float4 sc = *(const float4*)&scale[o4];
    float4 sh = *(const float4*)&shift[o4];
    float4 r;
    float y0 = (sc.x >= 0.f) ? mx.x : mn.x;
    float y1 = (sc.y >= 0.f) ? mx.y : mn.y;
    float y2 = (sc.z >= 0.f) ? mx.z : mn.z;
    float y3 = (sc.w >= 0.f) ? mx.w : mn.w;
    float a0 = y0 * sc.x + sh.x, a1 = y1 * sc.y + sh.y;
    float a2 = y2 * sc.z + sh.z, a3 = y3 * sc.w + sh.w;
    r.x = LEAKY(a0); r.y = LEAKY(a1); r.z = LEAKY(a2); r.w = LEAKY(a3);
    *(float4*)&xcat[(size_t)p * 512 + off + o4] = r;
}

// ---------------- pool partials: grid (16b, 16og, 4nz) = 1024 blocks --------
__global__ void pool_part(const float* __restrict__ h, const float* __restrict__ scale,
                          const float* __restrict__ shift,
                          float* __restrict__ pmax, double* __restrict__ psum) {
    __shared__ float smax[256];
    __shared__ double ssum[256];
    int b = blockIdx.x, og = blockIdx.y, nz = blockIdx.z;
    int t = threadIdx.x;
    int o = og * 64 + (t & 63);
    int ch = t >> 6;
    float sc = scale[o], sh = shift[o];
    float mx = -3.4e38f;
    double sm = 0.0;
    int n0 = nz * 256 + ch * 64;
    #pragma unroll 4
    for (int n = n0; n < n0 + 64; n++) {
        float y = h[((size_t)b * N_ + n) * 1024 + o] * sc + sh;
        y = LEAKY(y);
        mx = fmaxf(mx, y);
        sm += (double)y;
    }
    smax[t] = mx; ssum[t] = sm;
    __syncthreads();
    if (t < 64) {
        for (int c = 1; c < 4; c++) { mx = fmaxf(mx, smax[c * 64 + t]); sm += ssum[c * 64 + t]; }
        size_t pi = ((size_t)b * 4 + nz) * 1024 + o;
        pmax[pi] = mx;
        psum[pi] = sm;
    }
}

// ---------------- pool final: reduce 4 nz partials -> max / mean ------------
__global__ void pool_fin(const float* __restrict__ pmax, const double* __restrict__ psum,
                         float* __restrict__ pooled) {
    int b = blockIdx.x, og = blockIdx.y;
    int o = og * 256 + threadIdx.x;
    size_t base = (size_t)b * 4 * 1024 + o;
    float mx = pmax[base];
    double sm = psum[base];
    #pragma unroll
    for (int nz = 1; nz < 4; nz++) {
        mx = fmaxf(mx, pmax[base + nz * 1024]);
        sm += psum[base + nz * 1024];
    }
    pooled[(size_t)b * 2048 + o] = mx;
    pooled[(size_t)b * 2048 + 1024 + o] = (float)(sm * (1.0 / N_));
}

// ---------------- small FC: one wave per output -----------------------------
__global__ void fc_kernel(const float* __restrict__ in, int ldi,
                          const float* __restrict__ w, int ldw,
                          const float* __restrict__ bias,
                          float* __restrict__ out, int M, int Nn, int K) {
    int gw = (blockIdx.x * 256 + threadIdx.x) >> 6;
    int lane = threadIdx.x & 63;
    if (gw >= M * Nn) return;
    int m = gw / Nn, n = gw % Nn;
    const float* a = in + (size_t)m * ldi;
    const float* ww = w + (size_t)n * ldw;
    float s = 0.f;
    for (int kk = lane; kk < K; kk += 64) s += a[kk] * ww[kk];
    #pragma unroll
    for (int off = 32; off > 0; off >>= 1) s += __shfl_xor(s, off, 64);
    if (lane == 0) out[(size_t)m * Nn + n] = s + bias[n];
}

// ---------------- BN over batch axis (M=16) + leaky, in place ---------------
__global__ void bn_rows(float* __restrict__ z, int M, int O,
                        const float* __restrict__ g, const float* __restrict__ bt) {
    int o = blockIdx.x * 256 + threadIdx.x;
    if (o >= O) return;
    double s = 0.0, s2 = 0.0;
    for (int m = 0; m < M; m++) {
        float y = z[(size_t)m * O + o];
        s += (double)y; s2 += (double)y * (double)y;
    }
    double mean = s / M;
    double var = s2 / M - mean * mean;
    if (var < 0.0) var = 0.0;
    float sc = (float)(1.0 / sqrt(var + 1e-5)) * g[o];
    float sh = bt[o] - (float)mean * sc;
    for (int m = 0; m < M; m++) {
        float y = z[(size_t)m * O + o] * sc + sh;
        z[(size_t)m * O + o] = LEAKY(y);
    }
}

extern "C" void kernel_launch(void* const* d_in, const int* in_sizes, int n_in,
                              void* d_out, int out_size, void* d_ws, size_t ws_size,
                              hipStream_t stream) {
    const float* cloud = (const float*)d_in[0];
    const float* wf  = (const float*)d_in[17];
    const float* gf  = (const float*)d_in[19];
    const float* btf = (const float*)d_in[20];
    const float* wl1 = (const float*)d_in[21];
    const float* bl1 = (const float*)d_in[22];
    const float* gl1 = (const float*)d_in[23];
    const float* btl1= (const float*)d_in[24];
    const float* wl2 = (const float*)d_in[25];
    const float* bl2 = (const float*)d_in[26];
    const float* gl2 = (const float*)d_in[27];
    const float* btl2= (const float*)d_in[28];
    const float* wl3 = (const float*)d_in[29];
    const float* bl3 = (const float*)d_in[30];

    // workspace layout (bytes)
    const size_t OFF_XCAT  = 0;                        // 33554432
    const size_t OFF_UV    = 33554432;                 // 33554432 (A2 aliases UV+YMAX)
    const size_t OFF_YMAX  = 67108864;                 // 16777216 (xA alias: 12.6MB max)
    const size_t OFF_YMIN  = 83886080;                 // 16777216 (B2 alias)
    const size_t OFF_DIST  = 100663296;                // 67108864 (aliased as hraw)
    const size_t OFF_IDX   = 167772160;                // 1310720
    const size_t OFF_XX    = 169082880;                // 65536
    const size_t OFF_W2    = 169148416;                // 524288
    const size_t OFF_PART  = 169676800;                // 4194304: part doubles / partf / pool partials
    const size_t OFF_SCALE = 173871104;                // 4096
    const size_t OFF_SHIFT = 173875200;                // 4096
    const size_t OFF_POOL  = 173879296;                // 131072
    const size_t OFF_Z1    = 174010368;                // 32768
    const size_t OFF_Z2    = 174043136;                // 16384
    const size_t TOTAL     = 174059520;
    if (ws_size < TOTAL) return;

    char* ws = (char*)d_ws;
    float* xcat  = (float*)(ws + OFF_XCAT);
    float* uv    = (float*)(ws + OFF_UV);
    float* ymax  = (float*)(ws + OFF_YMAX);
    float* ymin  = (float*)(ws + OFF_YMIN);
    float* dist  = (float*)(ws + OFF_DIST);
    float* hraw  = (float*)(ws + OFF_DIST);
    ushort* A2   = (ushort*)(ws + OFF_UV);
    ushort* B2   = (ushort*)(ws + OFF_YMIN);
    ushort* xA   = (ushort*)(ws + OFF_YMAX);
    ushort* WB2  = (ushort*)(ws + OFF_PART);
    int*   idx   = (int*)  (ws + OFF_IDX);
    float* xx    = (float*)(ws + OFF_XX);
    float* W2    = (float*)(ws + OFF_W2);
    double* part = (double*)(ws + OFF_PART);
    float* partf = (float*)(ws + OFF_PART);
    float* ppmax = (float*)(ws + OFF_PART + 2097152);   // 256KB
    double* ppsum= (double*)(ws + OFF_PART + 2359296);  // 512KB
    float* scale = (float*)(ws + OFF_SCALE);
    float* shift = (float*)(ws + OFF_SHIFT);
    float* pooled= (float*)(ws + OFF_POOL);
    float* z1    = (float*)(ws + OFF_Z1);
    float* z2    = (float*)(ws + OFF_Z2);

    const int Cs[4]   = {3, 64, 64, 128};
    const int Os[4]   = {64, 64, 128, 256};
    const int offs[4] = {0, 64, 128, 256};

    for (int L = 0; L < 4; L++) {
        int C = Cs[L], O = Os[L];
        const float* w  = (const float*)d_in[1 + 4 * L];
        const float* g  = (const float*)d_in[3 + 4 * L];
        const float* bt = (const float*)d_in[4 + 4 * L];
        const float* x  = (L == 0) ? cloud : (xcat + offs[L - 1]);
        int lda = (L == 0) ? 3 : 512;

        sqnorm<<<(P_ + 255) / 256, 256, 0, stream>>>(x, lda, C, xx);
        dist_kernel<<<dim3(136, 16), 256, 0, stream>>>(x, lda, C, xx, dist);
        topk_kernel<<<(P_ * 64) / 256, 256, 0, stream>>>(dist, idx);

        if (L == 0) {
            prep_w2<<<(2 * O * C + 255) / 256, 256, 0, stream>>>(w, W2, O, C);
            gemm_wt<<<dim3(2 * O / 64, P_ / 64), 256, 0, stream>>>(x, lda, W2, C, uv, 2 * O, C);
        } else {
            int K3 = 3 * C, nkt = K3 / 64;
            conv_split<<<(P_ * (C / 4) + 255) / 256, 256, 0, stream>>>(x, lda, C, P_, xA, 0);
            prep_w2_split<<<(2 * O * (C / 4) + 255) / 256, 256, 0, stream>>>(w, WB2, O, C);
            gemm_mfma<0><<<dim3(2 * O / 128, 128), 256, 0, stream>>>(xA, WB2, K3, nkt, uv, 2 * O, nullptr);
        }

        gather_stats<<<1024, 256, 0, stream>>>(uv, idx, O, ymax, ymin, part, 16);
        finalize_t<<<O, 256, 0, stream>>>(part, O, g, bt, scale, shift, 1.0 / ((double)P_ * KNN));
        apply_edge<<<(P_ * (O / 4) + 255) / 256, 256, 0, stream>>>(ymax, ymin, scale, shift, xcat, O, offs[L]);
    }

    // final 1x1 conv via split-bf16 MFMA GEMM with fused (transposed) col stats
    conv_split<<<(P_ * 128 + 255) / 256, 256, 0, stream>>>(xcat, 512, 512, P_, A2, 0);
    conv_split<<<(1024 * 128 + 255) / 256, 256, 0, stream>>>(wf, 512, 512, 1024, B2, 1);
    gemm_mfma<2><<<dim3(8, 128), 256, 0, stream>>>(A2, B2, 1536, 24, hraw, 1024, partf);

    finalize_f_t<<<1024, 128, 0, stream>>>(partf, gf, btf, scale, shift, 1.0 / (double)P_);
    pool_part<<<dim3(16, 16, 4), 256, 0, stream>>>(hraw, scale, shift, ppmax, ppsum);
    pool_fin<<<dim3(16, 4), 256, 0, stream>>>(ppmax, ppsum, pooled);

    // MLP head
    fc_kernel<<<(16 * 512 * 64) / 256, 256, 0, stream>>>(pooled, 2048, wl1, 2048, bl1, z1, 16, 512, 2048);
    bn_rows<<<2, 256, 0, stream>>>(z1, 16, 512, gl1, btl1);
    fc_kernel<<<(16 * 256 * 64) / 256, 256, 0, stream>>>(z1, 512, wl2, 512, bl2, z2, 16, 256, 512);
    bn_rows<<<1, 256, 0, stream>>>(z2, 16, 256, gl2, btl2);
    fc_kernel<<<(16 * 40 * 64 + 255) / 256, 256, 0, stream>>>(z2, 256, wl3, 256, bl3, (float*)d_out, 16, 40, 256);
}

// Round 22
// 655.007 us; speedup vs baseline: 1.1764x; 1.0026x over previous
//
#include <hip/hip_runtime.h>

#define LEAKY(v) ((v) >= 0.f ? (v) : 0.2f*(v))

static const int B_ = 16;
static const int N_ = 1024;
static const int P_ = 16384;   // B*N
static const int KNN = 20;

typedef __attribute__((ext_vector_type(8))) short short8v;
typedef __attribute__((ext_vector_type(4))) float f32x4;

__device__ inline ushort f2bf(float f) {
    unsigned u = __float_as_uint(f);
    unsigned r = u + 0x7FFFu + ((u >> 16) & 1u);
    return (ushort)(r >> 16);
}
__device__ inline float bf2f(ushort h) {
    return __uint_as_float(((unsigned)h) << 16);
}

// ---------------- prep: W2 = [wA ; wB - wA] fp32 (layer-1 only) -------------
__global__ void prep_w2(const float* __restrict__ w, float* __restrict__ W2, int O, int C) {
    int i = blockIdx.x * 256 + threadIdx.x;
    int total = 2 * O * C;
    if (i < total) {
        int row = i / C, c = i % C;
        float val;
        if (row < O) val = w[row * 2 * C + c];
        else { int o = row - O; val = w[o * 2 * C + C + c] - w[o * 2 * C + c]; }
        W2[i] = val;
    }
}

// ---------------- prep W2 and split to bf16 [h|l] in one pass (L>=1) --------
__global__ void prep_w2_split(const float* __restrict__ w, ushort* __restrict__ WB2, int O, int C) {
    int i = blockIdx.x * 256 + threadIdx.x;
    int cpr = C >> 2;
    if (i >= 2 * O * cpr) return;
    int row = i / cpr, c4 = (i % cpr) * 4;
    float vv[4];
    #pragma unroll
    for (int j = 0; j < 4; j++) {
        int c = c4 + j;
        if (row < O) vv[j] = w[row * 2 * C + c];
        else { int o = row - O; vv[j] = w[o * 2 * C + C + c] - w[o * 2 * C + c]; }
    }
    ushort4 h, l;
    h.x = f2bf(vv[0]); l.x = f2bf(vv[0] - bf2f(h.x));
    h.y = f2bf(vv[1]); l.y = f2bf(vv[1] - bf2f(h.y));
    h.z = f2bf(vv[2]); l.z = f2bf(vv[2] - bf2f(h.z));
    h.w = f2bf(vv[3]); l.w = f2bf(vv[3] - bf2f(h.w));
    ushort* rowp = WB2 + (size_t)row * 2 * C + c4;
    *(ushort4*)(rowp)     = h;
    *(ushort4*)(rowp + C) = l;
}

// ---------------- squared norms (float4 path for C>=4) ----------------------
__global__ void sqnorm(const float* __restrict__ x, int lda, int C, float* __restrict__ xx) {
    int p = blockIdx.x * 256 + threadIdx.x;
    if (p >= P_) return;
    const float* r = x + (size_t)p * lda;
    float s = 0.f;
    if ((C & 3) == 0) {
        for (int c = 0; c < C; c += 4) {
            float4 v = *(const float4*)&r[c];
            s += v.x * v.x + v.y * v.y + v.z * v.z + v.w * v.w;
        }
    } else {
        for (int c = 0; c < C; c++) s += r[c] * r[c];
    }
    xx[p] = s;
}

// ---------------- fp32 -> split-bf16 rows, [h|l] layout (R22 dedup) ---------
__global__ void conv_split(const float* __restrict__ src, int ld, int C, int rows,
                           ushort* __restrict__ dst) {
    int i = blockIdx.x * 256 + threadIdx.x;
    int cpr = C >> 2;
    if (i >= rows * cpr) return;
    int p = i / cpr, c4 = (i % cpr) * 4;
    float4 v = *(const float4*)(src + (size_t)p * ld + c4);
    ushort4 h, l;
    h.x = f2bf(v.x); l.x = f2bf(v.x - bf2f(h.x));
    h.y = f2bf(v.y); l.y = f2bf(v.y - bf2f(h.y));
    h.z = f2bf(v.z); l.z = f2bf(v.z - bf2f(h.z));
    h.w = f2bf(v.w); l.w = f2bf(v.w - bf2f(h.w));
    ushort* row = dst + (size_t)p * 2 * C + c4;
    *(ushort4*)(row)     = h;
    *(ushort4*)(row + C) = l;
}

// ---------------- fp32 dist (all layers): 2*dot - xx_n - xx_m ---------------
// 64x64 tile, 4x4/thread, LDS-transposed mirror store; triangular linear grid.
// fp32 mandatory: split-bf16 dist flips near-tie kNN (R3).
__global__ void dist_kernel(const float* __restrict__ x, int lda, int C,
                            const float* __restrict__ xx, float* __restrict__ dist) {
    int t = blockIdx.x;
    int mi = (int)((sqrtf(8.f * (float)t + 1.f) - 1.f) * 0.5f);
    while ((mi + 1) * (mi + 2) / 2 <= t) mi++;
    while (mi * (mi + 1) / 2 > t) mi--;
    int nj = t - mi * (mi + 1) / 2;
    int m0 = mi * 64, n0 = nj * 64;
    __shared__ float As[16][68];
    __shared__ float Bs[16][68];
    __shared__ float Ts[64][68];
    int b = blockIdx.y;
    const float* xb = x + (size_t)b * N_ * lda;
    int tid = threadIdx.x;
    int tx = tid & 15, ty = tid >> 4;
    float acc[4][4] = {};
    for (int k0 = 0; k0 < C; k0 += 16) {
        for (int l = tid; l < 1024; l += 256) {
            int r = l >> 4, kk = l & 15, kg = k0 + kk;
            As[kk][r] = (kg < C) ? xb[(size_t)(n0 + r) * lda + kg] : 0.f;
            Bs[kk][r] = (kg < C) ? xb[(size_t)(m0 + r) * lda + kg] : 0.f;
        }
        __syncthreads();
        #pragma unroll
        for (int kk = 0; kk < 16; kk++) {
            float4 a4 = *(const float4*)&As[kk][ty * 4];
            float4 w4 = *(const float4*)&Bs[kk][tx * 4];
            float a[4] = {a4.x, a4.y, a4.z, a4.w};
            float w[4] = {w4.x, w4.y, w4.z, w4.w};
            #pragma unroll
            for (int i = 0; i < 4; i++)
                #pragma unroll
                for (int j = 0; j < 4; j++) acc[i][j] += a[i] * w[j];
        }
        __syncthreads();
    }
    size_t prow = (size_t)b * N_;
    #pragma unroll
    for (int i = 0; i < 4; i++) {
        int n = n0 + ty * 4 + i;
        float xn = xx[b * N_ + n];
        float4 v4;
        float vt[4];
        #pragma unroll
        for (int j = 0; j < 4; j++) {
            int m = m0 + tx * 4 + j;
            float v = 2.f * acc[i][j] - xn - xx[b * N_ + m];
            vt[j] = v;
            Ts[tx * 4 + j][ty * 4 + i] = v;   // Ts[m - m0][n - n0]
        }
        v4.x = vt[0]; v4.y = vt[1]; v4.z = vt[2]; v4.w = vt[3];
        *(float4*)&dist[(prow + n) * N_ + m0 + tx * 4] = v4;
    }
    if (m0 != n0) {
        __syncthreads();
        #pragma unroll
        for (int i = 0; i < 4; i++) {
            int mi2 = ty * 4 + i;
            float4 v4 = *(const float4*)&Ts[mi2][tx * 4];
            *(float4*)&dist[(prow + m0 + mi2) * N_ + n0 + tx * 4] = v4;
        }
    }
}

// ---------------- top-k=20 per row; one wave per row ------------------------
// R21 split butterfly: pure fmax reduce, then min-col among max-holders.
#define CE(a,b,up) { bool p_ = (v##b > v##a) || (v##b == v##a && c##b < c##a); \
                     bool s_ = (up) ? p_ : !p_; \
                     float tv_ = v##a; int tc_ = c##a; \
                     v##a = s_ ? v##b : v##a; c##a = s_ ? c##b : c##a; \
                     v##b = s_ ? tv_ : v##b;  c##b = s_ ? tc_ : c##b; }
__global__ __launch_bounds__(256, 4)
void topk_kernel(const float* __restrict__ dist, int* __restrict__ idx) {
    int wave = (blockIdx.x * 256 + threadIdx.x) >> 6;
    int lane = threadIdx.x & 63;
    if (wave >= P_) return;
    const float* row = dist + (size_t)wave * N_;
    int cb = lane * 4;
    float4 q0 = *(const float4*)&row[cb];
    float4 q1 = *(const float4*)&row[256 + cb];
    float4 q2 = *(const float4*)&row[512 + cb];
    float4 q3 = *(const float4*)&row[768 + cb];
    float v0 = q0.x, v1 = q0.y, v2 = q0.z, v3 = q0.w;
    float v4 = q1.x, v5 = q1.y, v6 = q1.z, v7 = q1.w;
    float v8 = q2.x, v9 = q2.y, v10 = q2.z, v11 = q2.w;
    float v12 = q3.x, v13 = q3.y, v14 = q3.z, v15 = q3.w;
    int c0 = cb, c1 = cb + 1, c2 = cb + 2, c3 = cb + 3;
    int c4 = 256 + cb, c5 = 256 + cb + 1, c6 = 256 + cb + 2, c7 = 256 + cb + 3;
    int c8 = 512 + cb, c9 = 512 + cb + 1, c10 = 512 + cb + 2, c11 = 512 + cb + 3;
    int c12 = 768 + cb, c13 = 768 + cb + 1, c14 = 768 + cb + 2, c15 = 768 + cb + 3;

    CE(0,1,true) CE(2,3,false) CE(4,5,true) CE(6,7,false)
    CE(8,9,true) CE(10,11,false) CE(12,13,true) CE(14,15,false)
    CE(0,2,true) CE(1,3,true) CE(4,6,false) CE(5,7,false)
    CE(8,10,true) CE(9,11,true) CE(12,14,false) CE(13,15,false)
    CE(0,1,true) CE(2,3,true) CE(4,5,false) CE(6,7,false)
    CE(8,9,true) CE(10,11,true) CE(12,13,false) CE(14,15,false)
    CE(0,4,true) CE(1,5,true) CE(2,6,true) CE(3,7,true)
    CE(8,12,false) CE(9,13,false) CE(10,14,false) CE(11,15,false)
    CE(0,2,true) CE(1,3,true) CE(4,6,true) CE(5,7,true)
    CE(8,10,false) CE(9,11,false) CE(12,14,false) CE(13,15,false)
    CE(0,1,true) CE(2,3,true) CE(4,5,true) CE(6,7,true)
    CE(8,9,false) CE(10,11,false) CE(12,13,false) CE(14,15,false)
    CE(0,8,true) CE(1,9,true) CE(2,10,true) CE(3,11,true)
    CE(4,12,true) CE(5,13,true) CE(6,14,true) CE(7,15,true)
    CE(0,4,true) CE(1,5,true) CE(2,6,true) CE(3,7,true)
    CE(8,12,true) CE(9,13,true) CE(10,14,true) CE(11,15,true)
    CE(0,2,true) CE(1,3,true) CE(4,6,true) CE(5,7,true)
    CE(8,10,true) CE(9,11,true) CE(12,14,true) CE(13,15,true)
    CE(0,1,true) CE(2,3,true) CE(4,5,true) CE(6,7,true)
    CE(8,9,true) CE(10,11,true) CE(12,13,true) CE(14,15,true)

    int* out = idx + (size_t)wave * KNN;
    #pragma unroll 1
    for (int it = 0; it < KNN; it++) {
        float sv = v0;
        #pragma unroll
        for (int off = 32; off > 0; off >>= 1)
            sv = fmaxf(sv, __shfl_xor(sv, off, 64));
        int cc = (v0 == sv) ? c0 : 0x7FFFFFFF;
        #pragma unroll
        for (int off = 32; off > 0; off >>= 1) {
            int oc = __shfl_xor(cc, off, 64);
            cc = (oc < cc) ? oc : cc;
        }
        if (lane == 0) out[it] = cc;
        int wc = __builtin_amdgcn_readfirstlane(cc);
        bool mine = (c0 == wc);
        v0 = mine ? v1 : v0;   c0 = mine ? c1 : c0;
        v1 = mine ? v2 : v1;   c1 = mine ? c2 : c1;
        v2 = mine ? v3 : v2;   c2 = mine ? c3 : c2;
        v3 = mine ? v4 : v3;   c3 = mine ? c4 : c3;
        v4 = mine ? v5 : v4;   c4 = mine ? c5 : c4;
        v5 = mine ? v6 : v5;   c5 = mine ? c6 : c5;
        v6 = mine ? v7 : v6;   c6 = mine ? c7 : c6;
        v7 = mine ? v8 : v7;   c7 = mine ? c8 : c7;
        v8 = mine ? v9 : v8;   c8 = mine ? c9 : c8;
        v9 = mine ? v10 : v9;  c9 = mine ? c10 : c9;
        v10 = mine ? v11 : v10; c10 = mine ? c11 : c10;
        v11 = mine ? v12 : v11; c11 = mine ? c12 : c11;
        v12 = mine ? v13 : v12; c12 = mine ? c13 : c12;
        v13 = mine ? v14 : v13; c13 = mine ? c14 : c13;
        v14 = mine ? v15 : v14; c14 = mine ? c15 : c14;
        v15 = mine ? -3.4e38f : v15;
    }
}
#undef CE

// ---------------- fp32 GEMM (layer-1 uv only, K=3) --------------------------
__global__ void gemm_wt(const float* __restrict__ A, int lda,
                        const float* __restrict__ W, int ldw,
                        float* __restrict__ out, int ldo, int K) {
    __shared__ float As[16][68];
    __shared__ float Ws[16][68];
    int m0 = blockIdx.y * 64, n0 = blockIdx.x * 64;
    int tid = threadIdx.x;
    int tx = tid & 15, ty = tid >> 4;
    float acc[4][4] = {};
    for (int k0 = 0; k0 < K; k0 += 16) {
        for (int l = tid; l < 1024; l += 256) {
            int r = l >> 4, kk = l & 15, kg = k0 + kk;
            As[kk][r] = (kg < K) ? A[(size_t)(m0 + r) * lda + kg] : 0.f;
            Ws[kk][r] = (kg < K) ? W[(size_t)(n0 + r) * ldw + kg] : 0.f;
        }
        __syncthreads();
        #pragma unroll
        for (int kk = 0; kk < 16; kk++) {
            float4 a4 = *(const float4*)&As[kk][ty * 4];
            float4 w4 = *(const float4*)&Ws[kk][tx * 4];
            float a[4] = {a4.x, a4.y, a4.z, a4.w};
            float w[4] = {w4.x, w4.y, w4.z, w4.w};
            #pragma unroll
            for (int i = 0; i < 4; i++)
                #pragma unroll
                for (int j = 0; j < 4; j++) acc[i][j] += a[i] * w[j];
        }
        __syncthreads();
    }
    for (int i = 0; i < 4; i++) {
        int m = m0 + ty * 4 + i;
        for (int j = 0; j < 4; j++) {
            int n = n0 + tx * 4 + j;
            out[(size_t)m * ldo + n] = acc[i][j];
        }
    }
}

// ---------------- unified split-bf16 MFMA GEMM (R22: [h|l] dedup) -----------
// A,B stored [h|l] (KA = 2*Ch). Virtual K walk = 3 segments of Ch:
// seg0 (Ah,Bh), seg1 (Ah,Bl), seg2 (Al,Bh) — same accumulation order as the
// old [h|h|l]x[h|l|h] K=3C walk, so results are bit-identical; A traffic
// drops 1/3 (second h pass is L2-resident).
// MODE 0: uv; MODE 2: final conv + fused transposed col stats.
// Bijective XCD swizzle (R12): each XCD owns a contiguous y-band.
template<int MODE>
__global__ __launch_bounds__(256, 2)
void gemm_mfma(const ushort* __restrict__ A, const ushort* __restrict__ Bw,
               int KA, int nkt, int Ch, int tps,
               float* __restrict__ out, int ldo, float* __restrict__ part) {
    __shared__ ushort lA[128 * 64];
    __shared__ ushort lB[128 * 64];
    int tid = threadIdx.x;
    int lane = tid & 63;
    int wid = tid >> 6;
    int wr = wid >> 1, wc = wid & 1;

    int nx = gridDim.x;
    int ypb = gridDim.y >> 3;
    int bid = blockIdx.y * nx + blockIdx.x;
    int xcd = bid & 7, pos = bid >> 3;
    int yy = xcd * ypb + pos / nx;
    int xx2 = pos % nx;
    int m0 = yy * 128, n0 = xx2 * 128;

    const ushort* pA = A + (size_t)m0 * KA;
    const ushort* pB = Bw + (size_t)n0 * KA;
    int rowu = tid >> 3, kcu = (tid & 7) * 8;

    f32x4 acc[4][4] = {};
    short8v ra[4], rb[4];
    #pragma unroll
    for (int j = 0; j < 4; j++) {
        int row = rowu + j * 32;
        ra[j] = *(const short8v*)(pA + (size_t)row * KA + kcu);
        rb[j] = *(const short8v*)(pB + (size_t)row * KA + kcu);
    }

    for (int kt = 0; kt < nkt; kt++) {
        __syncthreads();
        #pragma unroll
        for (int j = 0; j < 4; j++) {
            int row = rowu + j * 32;
            int off = (row * 128 + kcu * 2) ^ ((row & 7) << 4);
            *(short8v*)((char*)lA + off) = ra[j];
            *(short8v*)((char*)lB + off) = rb[j];
        }
        __syncthreads();
        if (kt < nkt - 1) {
            int kn = kt + 1;
            int seg = kn / tps, ktt = kn - seg * tps;
            int aoff = ((seg == 2) ? Ch : 0) + ktt * 64 + kcu;
            int boff = ((seg == 1) ? Ch : 0) + ktt * 64 + kcu;
            #pragma unroll
            for (int j = 0; j < 4; j++) {
                int row = rowu + j * 32;
                ra[j] = *(const short8v*)(pA + (size_t)row * KA + aoff);
                rb[j] = *(const short8v*)(pB + (size_t)row * KA + boff);
            }
        }
        #pragma unroll
        for (int ks = 0; ks < 2; ks++) {
            short8v af[4], bg[4];
            int kb2 = (ks * 32 + ((lane >> 4) << 3)) * 2;
            #pragma unroll
            for (int mb = 0; mb < 4; mb++) {
                int row = wr * 64 + mb * 16 + (lane & 15);
                int off = (row * 128 + kb2) ^ ((row & 7) << 4);
                af[mb] = *(const short8v*)((const char*)lA + off);
            }
            #pragma unroll
            for (int nb = 0; nb < 4; nb++) {
                int row = wc * 64 + nb * 16 + (lane & 15);
                int off = (row * 128 + kb2) ^ ((row & 7) << 4);
                bg[nb] = *(const short8v*)((const char*)lB + off);
            }
            #pragma unroll
            for (int mb = 0; mb < 4; mb++)
                #pragma unroll
                for (int nb = 0; nb < 4; nb++)
                    acc[mb][nb] = __builtin_amdgcn_mfma_f32_16x16x32_bf16(af[mb], bg[nb], acc[mb][nb], 0, 0, 0);
        }
    }

    int rbase = m0 + wr * 64 + ((lane >> 4) << 2);
    int cbase = n0 + wc * 64 + (lane & 15);

    if (MODE == 0) {
        #pragma unroll
        for (int mb = 0; mb < 4; mb++)
            #pragma unroll
            for (int nb = 0; nb < 4; nb++)
                #pragma unroll
                for (int r = 0; r < 4; r++)
                    out[(size_t)(rbase + mb * 16 + r) * ldo + cbase + nb * 16] = acc[mb][nb][r];
    } else {
        float* smS = (float*)lA;
        float* smQ = (float*)lB;
        __syncthreads();
        #pragma unroll
        for (int nb = 0; nb < 4; nb++) {
            float s = 0.f, q = 0.f;
            #pragma unroll
            for (int mb = 0; mb < 4; mb++)
                #pragma unroll
                for (int r = 0; r < 4; r++) {
                    float v = acc[mb][nb][r];
                    out[(size_t)(rbase + mb * 16 + r) * ldo + cbase + nb * 16] = v;
                    s += v; q += v * v;
                }
            s += __shfl_xor(s, 16, 64); s += __shfl_xor(s, 32, 64);
            q += __shfl_xor(q, 16, 64); q += __shfl_xor(q, 32, 64);
            if ((lane >> 4) == 0) {
                smS[wid * 64 + nb * 16 + lane] = s;
                smQ[wid * 64 + nb * 16 + lane] = q;
            }
        }
        __syncthreads();
        if (tid < 128) {
            int wcs = tid >> 6, c = tid & 63;
            float s = smS[wcs * 64 + c] + smS[(2 + wcs) * 64 + c];
            float q = smQ[wcs * 64 + c] + smQ[(2 + wcs) * 64 + c];
            int col = n0 + wcs * 64 + c;
            part[(size_t)col * 128 + yy] = s;
            part[131072 + (size_t)col * 128 + yy] = q;
        }
    }
}

// ---------------- gather neighbors, per-(p,o) max/min, per-channel stats ----
// int4-preloaded indices; gathers issued 4 at a time (R19, bit-identical).
__global__ void gather_stats(const float* __restrict__ uv, const int* __restrict__ idx, int O,
                             float* __restrict__ ymax, float* __restrict__ ymin,
                             double* __restrict__ part, int ppb) {
    __shared__ double sd[256], sd2[256];
    int t = threadIdx.x;
    int R = 256 / O;
    int o = t % O;
    int q = t / O;
    double s = 0.0, s2 = 0.0;
    int p0 = blockIdx.x * ppb;
    int ld = 2 * O;
    for (int lp = q; lp < ppb; lp += R) {
        int p = p0 + lp;
        int base = (p >> 10) << 10;
        const int* ir = idx + (size_t)p * KNN;
        int4 i0 = *(const int4*)(ir);
        int4 i1 = *(const int4*)(ir + 4);
        int4 i2 = *(const int4*)(ir + 8);
        int4 i3 = *(const int4*)(ir + 12);
        int4 i4 = *(const int4*)(ir + 16);
        float v = uv[(size_t)p * ld + O + o];
        float mx = -3.4e38f, mn = 3.4e38f;
        #define G4(iv) { \
            float u0_ = uv[(size_t)(base + (iv).x) * ld + o]; \
            float u1_ = uv[(size_t)(base + (iv).y) * ld + o]; \
            float u2_ = uv[(size_t)(base + (iv).z) * ld + o]; \
            float u3_ = uv[(size_t)(base + (iv).w) * ld + o]; \
            float y0_ = u0_ + v, y1_ = u1_ + v, y2_ = u2_ + v, y3_ = u3_ + v; \
            mx = fmaxf(mx, y0_); mn = fminf(mn, y0_); s += (double)y0_; s2 += (double)y0_ * (double)y0_; \
            mx = fmaxf(mx, y1_); mn = fminf(mn, y1_); s += (double)y1_; s2 += (double)y1_ * (double)y1_; \
            mx = fmaxf(mx, y2_); mn = fminf(mn, y2_); s += (double)y2_; s2 += (double)y2_ * (double)y2_; \
            mx = fmaxf(mx, y3_); mn = fminf(mn, y3_); s += (double)y3_; s2 += (double)y3_ * (double)y3_; }
        G4(i0) G4(i1) G4(i2) G4(i3) G4(i4)
        #undef G4
        ymax[(size_t)p * O + o] = mx;
        ymin[(size_t)p * O + o] = mn;
    }
    sd[t] = s; sd2[t] = s2;
    __syncthreads();
    if (t < O) {
        double a = 0.0, a2 = 0.0;
        for (int qq = 0; qq < R; qq++) { a += sd[qq * O + t]; a2 += sd2[qq * O + t]; }
        part[(size_t)t * 1024 + blockIdx.x] = a;
        part[(size_t)(O + t) * 1024 + blockIdx.x] = a2;
    }
}

// ---------------- parallel finalize: one block per channel ------------------
__global__ void finalize_t(const double* __restrict__ part, int O,
                           const float* __restrict__ g, const float* __restrict__ bt,
                           float* __restrict__ scale, float* __restrict__ shift, double invCount) {
    __shared__ double sa[4], sb[4];
    int o = blockIdx.x;
    int t = threadIdx.x;
    int lane = t & 63, w = t >> 6;
    const double* ps = part + (size_t)o * 1024;
    const double* pq = part + (size_t)(O + o) * 1024;
    double s = 0.0, s2 = 0.0;
    #pragma unroll
    for (int b = 0; b < 4; b++) { s += ps[t + b * 256]; s2 += pq[t + b * 256]; }
    #pragma unroll
    for (int off = 32; off > 0; off >>= 1) { s += __shfl_xor(s, off, 64); s2 += __shfl_xor(s2, off, 64); }
    if (lane == 0) { sa[w] = s; sb[w] = s2; }
    __syncthreads();
    if (t == 0) {
        s = sa[0] + sa[1] + sa[2] + sa[3];
        s2 = sb[0] + sb[1] + sb[2] + sb[3];
        double mean = s * invCount;
        double var = s2 * invCount - mean * mean;
        if (var < 0.0) var = 0.0;
        float sc = (float)(1.0 / sqrt(var + 1e-5)) * g[o];
        scale[o] = sc;
        shift[o] = bt[o] - (float)mean * sc;
    }
}

// ---------------- parallel finalize for float partials (final conv) ---------
__global__ void finalize_f_t(const float* __restrict__ part,
                             const float* __restrict__ g, const float* __restrict__ bt,
                             float* __restrict__ scale, float* __restrict__ shift, double invCount) {
    __shared__ double sa[2], sb[2];
    int o = blockIdx.x;
    int t = threadIdx.x;   // 128 threads
    int lane = t & 63, w = t >> 6;
    double s  = (double)part[(size_t)o * 128 + t];
    double s2 = (double)part[131072 + (size_t)o * 128 + t];
    #pragma unroll
    for (int off = 32; off > 0; off >>= 1) { s += __shfl_xor(s, off, 64); s2 += __shfl_xor(s2, off, 64); }
    if (lane == 0) { sa[w] = s; sb[w] = s2; }
    __syncthreads();
    if (t == 0) {
        s = sa[0] + sa[1];
        s2 = sb[0] + sb[1];
        double mean = s * invCount;
        double var = s2 * invCount - mean * mean;
        if (var < 0.0) var = 0.0;
        float sc = (float)(1.0 / sqrt(var + 1e-5)) * g[o];
        scale[o] = sc;
        shift[o] = bt[o] - (float)mean * sc;
    }
}

// ---------------- edge conv epilogue: BN + leaky, float4 --------------------
__global__ void apply_edge(const float* __restrict__ ymax, const float* __restrict__ ymin,
                           const float* __restrict__ scale, const float* __restrict__ shift,
                           float* __restrict__ xcat, int O, int off) {
    int i = blockIdx.x * 256 + threadIdx.x;
    int oq = O >> 2;
    if (i >= P_ * oq) return;
    int p = i / oq, o4 = (i % oq) * 4;
    float4 mx = *(const float4*)&ymax[(size_t)p * O + o4];
    float4 mn = *(const float4*)&ymin[(size_t)p * O + o4];
    float4 sc = *(const float4*)&scale[o4];
    float4 sh = *(const float4*)&shift[o4];
    float4 r;
    float y0 = (sc.x >= 0.f) ? mx.x : mn.x;
    float y1 = (sc.y >= 0.f) ? mx.y : mn.y;
    float y2 = (sc.z >= 0.f) ? mx.z : mn.z;
    float y3 = (sc.w >= 0.f) ? mx.w : mn.w;
    float a0 = y0 * sc.x + sh.x, a1 = y1 * sc.y + sh.y;
    float a2 = y2 * sc.z + sh.z, a3 = y3 * sc.w + sh.w;
    r.x = LEAKY(a0); r.y = LEAKY(a1); r.z = LEAKY(a2); r.w = LEAKY(a3);
    *(float4*)&xcat[(size_t)p * 512 + off + o4] = r;
}

// ---------------- pool partials: grid (16b, 16og, 4nz) = 1024 blocks --------
__global__ void pool_part(const float* __restrict__ h, const float* __restrict__ scale,
                          const float* __restrict__ shift,
                          float* __restrict__ pmax, double* __restrict__ psum) {
    __shared__ float smax[256];
    __shared__ double ssum[256];
    int b = blockIdx.x, og = blockIdx.y, nz = blockIdx.z;
    int t = threadIdx.x;
    int o = og * 64 + (t & 63);
    int ch = t >> 6;
    float sc = scale[o], sh = shift[o];
    float mx = -3.4e38f;
    double sm = 0.0;
    int n0 = nz * 256 + ch * 64;
    #pragma unroll 4
    for (int n = n0; n < n0 + 64; n++) {
        float y = h[((size_t)b * N_ + n) * 1024 + o] * sc + sh;
        y = LEAKY(y);
        mx = fmaxf(mx, y);
        sm += (double)y;
    }
    smax[t] = mx; ssum[t] = sm;
    __syncthreads();
    if (t < 64) {
        for (int c = 1; c < 4; c++) { mx = fmaxf(mx, smax[c * 64 + t]); sm += ssum[c * 64 + t]; }
        size_t pi = ((size_t)b * 4 + nz) * 1024 + o;
        pmax[pi] = mx;
        psum[pi] = sm;
    }
}

// ---------------- pool final: reduce 4 nz partials -> max / mean ------------
__global__ void pool_fin(const float* __restrict__ pmax, const double* __restrict__ psum,
                         float* __restrict__ pooled) {
    int b = blockIdx.x, og = blockIdx.y;
    int o = og * 256 + threadIdx.x;
    size_t base = (size_t)b * 4 * 1024 + o;
    float mx = pmax[base];
    double sm = psum[base];
    #pragma unroll
    for (int nz = 1; nz < 4; nz++) {
        mx = fmaxf(mx, pmax[base + nz * 1024]);
        sm += psum[base + nz * 1024];
    }
    pooled[(size_t)b * 2048 + o] = mx;
    pooled[(size_t)b * 2048 + 1024 + o] = (float)(sm * (1.0 / N_));
}

// ---------------- small FC: one wave per output -----------------------------
__global__ void fc_kernel(const float* __restrict__ in, int ldi,
                          const float* __restrict__ w, int ldw,
                          const float* __restrict__ bias,
                          float* __restrict__ out, int M, int Nn, int K) {
    int gw = (blockIdx.x * 256 + threadIdx.x) >> 6;
    int lane = threadIdx.x & 63;
    if (gw >= M * Nn) return;
    int m = gw / Nn, n = gw % Nn;
    const float* a = in + (size_t)m * ldi;
    const float* ww = w + (size_t)n * ldw;
    float s = 0.f;
    for (int kk = lane; kk < K; kk += 64) s += a[kk] * ww[kk];
    #pragma unroll
    for (int off = 32; off > 0; off >>= 1) s += __shfl_xor(s, off, 64);
    if (lane == 0) out[(size_t)m * Nn + n] = s + bias[n];
}

// ---------------- BN over batch axis (M=16) + leaky, in place ---------------
__global__ void bn_rows(float* __restrict__ z, int M, int O,
                        const float* __restrict__ g, const float* __restrict__ bt) {
    int o = blockIdx.x * 256 + threadIdx.x;
    if (o >= O) return;
    double s = 0.0, s2 = 0.0;
    for (int m = 0; m < M; m++) {
        float y = z[(size_t)m * O + o];
        s += (double)y; s2 += (double)y * (double)y;
    }
    double mean = s / M;
    double var = s2 / M - mean * mean;
    if (var < 0.0) var = 0.0;
    float sc = (float)(1.0 / sqrt(var + 1e-5)) * g[o];
    float sh = bt[o] - (float)mean * sc;
    for (int m = 0; m < M; m++) {
        float y = z[(size_t)m * O + o] * sc + sh;
        z[(size_t)m * O + o] = LEAKY(y);
    }
}

extern "C" void kernel_launch(void* const* d_in, const int* in_sizes, int n_in,
                              void* d_out, int out_size, void* d_ws, size_t ws_size,
                              hipStream_t stream) {
    const float* cloud = (const float*)d_in[0];
    const float* wf  = (const float*)d_in[17];
    const float* gf  = (const float*)d_in[19];
    const float* btf = (const float*)d_in[20];
    const float* wl1 = (const float*)d_in[21];
    const float* bl1 = (const float*)d_in[22];
    const float* gl1 = (const float*)d_in[23];
    const float* btl1= (const float*)d_in[24];
    const float* wl2 = (const float*)d_in[25];
    const float* bl2 = (const float*)d_in[26];
    const float* gl2 = (const float*)d_in[27];
    const float* btl2= (const float*)d_in[28];
    const float* wl3 = (const float*)d_in[29];
    const float* bl3 = (const float*)d_in[30];

    // workspace layout (bytes)
    const size_t OFF_XCAT  = 0;                        // 33554432
    const size_t OFF_UV    = 33554432;                 // 33554432 (A2 [h|l] = 32MB fits exactly)
    const size_t OFF_YMAX  = 67108864;                 // 16777216 (xA [h|l] <= 8.4MB)
    const size_t OFF_YMIN  = 83886080;                 // 16777216 (B2 alias, 2MB)
    const size_t OFF_DIST  = 100663296;                // 67108864 (aliased as hraw)
    const size_t OFF_IDX   = 167772160;                // 1310720
    const size_t OFF_XX    = 169082880;                // 65536
    const size_t OFF_W2    = 169148416;                // 524288
    const size_t OFF_PART  = 169676800;                // 4194304: part doubles / partf / pool partials
    const size_t OFF_SCALE = 173871104;                // 4096
    const size_t OFF_SHIFT = 173875200;                // 4096
    const size_t OFF_POOL  = 173879296;                // 131072
    const size_t OFF_Z1    = 174010368;                // 32768
    const size_t OFF_Z2    = 174043136;                // 16384
    const size_t TOTAL     = 174059520;
    if (ws_size < TOTAL) return;

    char* ws = (char*)d_ws;
    float* xcat  = (float*)(ws + OFF_XCAT);
    float* uv    = (float*)(ws + OFF_UV);
    float* ymax  = (float*)(ws + OFF_YMAX);
    float* ymin  = (float*)(ws + OFF_YMIN);
    float* dist  = (float*)(ws + OFF_DIST);
    float* hraw  = (float*)(ws + OFF_DIST);
    ushort* A2   = (ushort*)(ws + OFF_UV);     // final conv A [h|l]: 32MB
    ushort* B2   = (ushort*)(ws + OFF_YMIN);   // final conv B [h|l]: 2MB
    ushort* xA   = (ushort*)(ws + OFF_YMAX);   // per-layer split A [h|l]: ≤8.4MB
    ushort* WB2  = (ushort*)(ws + OFF_PART);   // per-layer split of W2 [h|l]: ≤256KB
    int*   idx   = (int*)  (ws + OFF_IDX);
    float* xx    = (float*)(ws + OFF_XX);
    float* W2    = (float*)(ws + OFF_W2);
    double* part = (double*)(ws + OFF_PART);
    float* partf = (float*)(ws + OFF_PART);
    float* ppmax = (float*)(ws + OFF_PART + 2097152);   // 256KB
    double* ppsum= (double*)(ws + OFF_PART + 2359296);  // 512KB
    float* scale = (float*)(ws + OFF_SCALE);
    float* shift = (float*)(ws + OFF_SHIFT);
    float* pooled= (float*)(ws + OFF_POOL);
    float* z1    = (float*)(ws + OFF_Z1);
    float* z2    = (float*)(ws + OFF_Z2);

    const int Cs[4]   = {3, 64, 64, 128};
    const int Os[4]   = {64, 64, 128, 256};
    const int offs[4] = {0, 64, 128, 256};

    for (int L = 0; L < 4; L++) {
        int C = Cs[L], O = Os[L];
        const float* w  = (const float*)d_in[1 + 4 * L];
        const float* g  = (const float*)d_in[3 + 4 * L];
        const float* bt = (const float*)d_in[4 + 4 * L];
        const float* x  = (L == 0) ? cloud : (xcat + offs[L - 1]);
        int lda = (L == 0) ? 3 : 512;

        sqnorm<<<(P_ + 255) / 256, 256, 0, stream>>>(x, lda, C, xx);
        dist_kernel<<<dim3(136, 16), 256, 0, stream>>>(x, lda, C, xx, dist);
        topk_kernel<<<(P_ * 64) / 256, 256, 0, stream>>>(dist, idx);

        if (L == 0) {
            prep_w2<<<(2 * O * C + 255) / 256, 256, 0, stream>>>(w, W2, O, C);
            gemm_wt<<<dim3(2 * O / 64, P_ / 64), 256, 0, stream>>>(x, lda, W2, C, uv, 2 * O, C);
        } else {
            int nkt = 3 * C / 64, tps = C / 64;
            conv_split<<<(P_ * (C / 4) + 255) / 256, 256, 0, stream>>>(x, lda, C, P_, xA);
            prep_w2_split<<<(2 * O * (C / 4) + 255) / 256, 256, 0, stream>>>(w, WB2, O, C);
            gemm_mfma<0><<<dim3(2 * O / 128, 128), 256, 0, stream>>>(xA, WB2, 2 * C, nkt, C, tps, uv, 2 * O, nullptr);
        }

        gather_stats<<<1024, 256, 0, stream>>>(uv, idx, O, ymax, ymin, part, 16);
        finalize_t<<<O, 256, 0, stream>>>(part, O, g, bt, scale, shift, 1.0 / ((double)P_ * KNN));
        apply_edge<<<(P_ * (O / 4) + 255) / 256, 256, 0, stream>>>(ymax, ymin, scale, shift, xcat, O, offs[L]);
    }

    // final 1x1 conv via dedup split-bf16 MFMA GEMM with fused col stats
    conv_split<<<(P_ * 128 + 255) / 256, 256, 0, stream>>>(xcat, 512, 512, P_, A2);
    conv_split<<<(1024 * 128 + 255) / 256, 256, 0, stream>>>(wf, 512, 512, 1024, B2);
    gemm_mfma<2><<<dim3(8, 128), 256, 0, stream>>>(A2, B2, 1024, 24, 512, 8, hraw, 1024, partf);

    finalize_f_t<<<1024, 128, 0, stream>>>(partf, gf, btf, scale, shift, 1.0 / (double)P_);
    pool_part<<<dim3(16, 16, 4), 256, 0, stream>>>(hraw, scale, shift, ppmax, ppsum);
    pool_fin<<<dim3(16, 4), 256, 0, stream>>>(ppmax, ppsum, pooled);

    // MLP head
    fc_kernel<<<(16 * 512 * 64) / 256, 256, 0, stream>>>(pooled, 2048, wl1, 2048, bl1, z1, 16, 512, 2048);
    bn_rows<<<2, 256, 0, stream>>>(z1, 16, 512, gl1, btl1);
    fc_kernel<<<(16 * 256 * 64) / 256, 256, 0, stream>>>(z1, 512, wl2, 512, bl2, z2, 16, 256, 512);
    bn_rows<<<1, 256, 0, stream>>>(z2, 16, 256, gl2, btl2);
    fc_kernel<<<(16 * 40 * 64 + 255) / 256, 256, 0, stream>>>(z2, 256, wl3, 256, bl3, (float*)d_out, 16, 40, 256);
}

// Round 23
// 653.117 us; speedup vs baseline: 1.1798x; 1.0029x over previous
//
#include <hip/hip_runtime.h>

#define LEAKY(v) ((v) >= 0.f ? (v) : 0.2f*(v))

static const int B_ = 16;
static const int N_ = 1024;
static const int P_ = 16384;   // B*N
static const int KNN = 20;

typedef __attribute__((ext_vector_type(8))) short short8v;
typedef __attribute__((ext_vector_type(4))) float f32x4;

__device__ inline ushort f2bf(float f) {
    unsigned u = __float_as_uint(f);
    unsigned r = u + 0x7FFFu + ((u >> 16) & 1u);
    return (ushort)(r >> 16);
}
__device__ inline float bf2f(ushort h) {
    return __uint_as_float(((unsigned)h) << 16);
}

// ---------------- prep: W2 = [wA ; wB - wA] fp32 (layer-1 only) -------------
__global__ void prep_w2(const float* __restrict__ w, float* __restrict__ W2, int O, int C) {
    int i = blockIdx.x * 256 + threadIdx.x;
    int total = 2 * O * C;
    if (i < total) {
        int row = i / C, c = i % C;
        float val;
        if (row < O) val = w[row * 2 * C + c];
        else { int o = row - O; val = w[o * 2 * C + C + c] - w[o * 2 * C + c]; }
        W2[i] = val;
    }
}

// ---------------- prep W2 and split to bf16 [h|l] in one pass (L>=1) --------
__global__ void prep_w2_split(const float* __restrict__ w, ushort* __restrict__ WB2, int O, int C) {
    int i = blockIdx.x * 256 + threadIdx.x;
    int cpr = C >> 2;
    if (i >= 2 * O * cpr) return;
    int row = i / cpr, c4 = (i % cpr) * 4;
    float vv[4];
    #pragma unroll
    for (int j = 0; j < 4; j++) {
        int c = c4 + j;
        if (row < O) vv[j] = w[row * 2 * C + c];
        else { int o = row - O; vv[j] = w[o * 2 * C + C + c] - w[o * 2 * C + c]; }
    }
    ushort4 h, l;
    h.x = f2bf(vv[0]); l.x = f2bf(vv[0] - bf2f(h.x));
    h.y = f2bf(vv[1]); l.y = f2bf(vv[1] - bf2f(h.y));
    h.z = f2bf(vv[2]); l.z = f2bf(vv[2] - bf2f(h.z));
    h.w = f2bf(vv[3]); l.w = f2bf(vv[3] - bf2f(h.w));
    ushort* rowp = WB2 + (size_t)row * 2 * C + c4;
    *(ushort4*)(rowp)     = h;
    *(ushort4*)(rowp + C) = l;
}

// ---------------- squared norms (float4 path for C>=4) ----------------------
__global__ void sqnorm(const float* __restrict__ x, int lda, int C, float* __restrict__ xx) {
    int p = blockIdx.x * 256 + threadIdx.x;
    if (p >= P_) return;
    const float* r = x + (size_t)p * lda;
    float s = 0.f;
    if ((C & 3) == 0) {
        for (int c = 0; c < C; c += 4) {
            float4 v = *(const float4*)&r[c];
            s += v.x * v.x + v.y * v.y + v.z * v.z + v.w * v.w;
        }
    } else {
        for (int c = 0; c < C; c++) s += r[c] * r[c];
    }
    xx[p] = s;
}

// ---------------- fp32 -> split-bf16 rows, [h|l] layout ---------------------
__global__ void conv_split(const float* __restrict__ src, int ld, int C, int rows,
                           ushort* __restrict__ dst) {
    int i = blockIdx.x * 256 + threadIdx.x;
    int cpr = C >> 2;
    if (i >= rows * cpr) return;
    int p = i / cpr, c4 = (i % cpr) * 4;
    float4 v = *(const float4*)(src + (size_t)p * ld + c4);
    ushort4 h, l;
    h.x = f2bf(v.x); l.x = f2bf(v.x - bf2f(h.x));
    h.y = f2bf(v.y); l.y = f2bf(v.y - bf2f(h.y));
    h.z = f2bf(v.z); l.z = f2bf(v.z - bf2f(h.z));
    h.w = f2bf(v.w); l.w = f2bf(v.w - bf2f(h.w));
    ushort* row = dst + (size_t)p * 2 * C + c4;
    *(ushort4*)(row)     = h;
    *(ushort4*)(row + C) = l;
}

// ---------------- fp32 dist (all layers): 2*dot - xx_n - xx_m ---------------
// 64x64 tile, 4x4/thread, LDS-transposed mirror store; triangular linear grid.
// fp32 mandatory: split-bf16 dist flips near-tie kNN (R3).
__global__ void dist_kernel(const float* __restrict__ x, int lda, int C,
                            const float* __restrict__ xx, float* __restrict__ dist) {
    int t = blockIdx.x;
    int mi = (int)((sqrtf(8.f * (float)t + 1.f) - 1.f) * 0.5f);
    while ((mi + 1) * (mi + 2) / 2 <= t) mi++;
    while (mi * (mi + 1) / 2 > t) mi--;
    int nj = t - mi * (mi + 1) / 2;
    int m0 = mi * 64, n0 = nj * 64;
    __shared__ float As[16][68];
    __shared__ float Bs[16][68];
    __shared__ float Ts[64][68];
    int b = blockIdx.y;
    const float* xb = x + (size_t)b * N_ * lda;
    int tid = threadIdx.x;
    int tx = tid & 15, ty = tid >> 4;
    float acc[4][4] = {};
    for (int k0 = 0; k0 < C; k0 += 16) {
        for (int l = tid; l < 1024; l += 256) {
            int r = l >> 4, kk = l & 15, kg = k0 + kk;
            As[kk][r] = (kg < C) ? xb[(size_t)(n0 + r) * lda + kg] : 0.f;
            Bs[kk][r] = (kg < C) ? xb[(size_t)(m0 + r) * lda + kg] : 0.f;
        }
        __syncthreads();
        #pragma unroll
        for (int kk = 0; kk < 16; kk++) {
            float4 a4 = *(const float4*)&As[kk][ty * 4];
            float4 w4 = *(const float4*)&Bs[kk][tx * 4];
            float a[4] = {a4.x, a4.y, a4.z, a4.w};
            float w[4] = {w4.x, w4.y, w4.z, w4.w};
            #pragma unroll
            for (int i = 0; i < 4; i++)
                #pragma unroll
                for (int j = 0; j < 4; j++) acc[i][j] += a[i] * w[j];
        }
        __syncthreads();
    }
    size_t prow = (size_t)b * N_;
    #pragma unroll
    for (int i = 0; i < 4; i++) {
        int n = n0 + ty * 4 + i;
        float xn = xx[b * N_ + n];
        float4 v4;
        float vt[4];
        #pragma unroll
        for (int j = 0; j < 4; j++) {
            int m = m0 + tx * 4 + j;
            float v = 2.f * acc[i][j] - xn - xx[b * N_ + m];
            vt[j] = v;
            Ts[tx * 4 + j][ty * 4 + i] = v;   // Ts[m - m0][n - n0]
        }
        v4.x = vt[0]; v4.y = vt[1]; v4.z = vt[2]; v4.w = vt[3];
        *(float4*)&dist[(prow + n) * N_ + m0 + tx * 4] = v4;
    }
    if (m0 != n0) {
        __syncthreads();
        #pragma unroll
        for (int i = 0; i < 4; i++) {
            int mi2 = ty * 4 + i;
            float4 v4 = *(const float4*)&Ts[mi2][tx * 4];
            *(float4*)&dist[(prow + m0 + mi2) * N_ + n0 + tx * 4] = v4;
        }
    }
}

// ---------------- top-k=20 per row; one wave per row ------------------------
// R23: bitonic sort (named scalars) -> slots 1..15 spill to lane-private LDS
// columns; head (hv,hc) stays in registers. Eviction = head-pointer advance
// (one predicated LDS read) instead of the 32-cndmask full-list shift (half
// of each round's VALU in R21). Sorted heads keep lax.top_k order exactly.
#define CE(a,b,up) { bool p_ = (v##b > v##a) || (v##b == v##a && c##b < c##a); \
                     bool s_ = (up) ? p_ : !p_; \
                     float tv_ = v##a; int tc_ = c##a; \
                     v##a = s_ ? v##b : v##a; c##a = s_ ? c##b : c##a; \
                     v##b = s_ ? tv_ : v##b;  c##b = s_ ? tc_ : c##b; }
__global__ __launch_bounds__(256, 4)
void topk_kernel(const float* __restrict__ dist, int* __restrict__ idx) {
    __shared__ float  Vv[4 * 16 * 64];
    __shared__ ushort Vc[4 * 16 * 64];
    int tid = threadIdx.x;
    int wv = tid >> 6, lane = tid & 63;
    int wave = blockIdx.x * 4 + wv;      // grid = P_/4 exactly
    const float* row = dist + (size_t)wave * N_;
    int cb = lane * 4;
    float4 q0 = *(const float4*)&row[cb];
    float4 q1 = *(const float4*)&row[256 + cb];
    float4 q2 = *(const float4*)&row[512 + cb];
    float4 q3 = *(const float4*)&row[768 + cb];
    float v0 = q0.x, v1 = q0.y, v2 = q0.z, v3 = q0.w;
    float v4 = q1.x, v5 = q1.y, v6 = q1.z, v7 = q1.w;
    float v8 = q2.x, v9 = q2.y, v10 = q2.z, v11 = q2.w;
    float v12 = q3.x, v13 = q3.y, v14 = q3.z, v15 = q3.w;
    int c0 = cb, c1 = cb + 1, c2 = cb + 2, c3 = cb + 3;
    int c4 = 256 + cb, c5 = 256 + cb + 1, c6 = 256 + cb + 2, c7 = 256 + cb + 3;
    int c8 = 512 + cb, c9 = 512 + cb + 1, c10 = 512 + cb + 2, c11 = 512 + cb + 3;
    int c12 = 768 + cb, c13 = 768 + cb + 1, c14 = 768 + cb + 2, c15 = 768 + cb + 3;

    // bitonic sort, best-first by (value desc, col asc)
    CE(0,1,true) CE(2,3,false) CE(4,5,true) CE(6,7,false)
    CE(8,9,true) CE(10,11,false) CE(12,13,true) CE(14,15,false)
    CE(0,2,true) CE(1,3,true) CE(4,6,false) CE(5,7,false)
    CE(8,10,true) CE(9,11,true) CE(12,14,false) CE(13,15,false)
    CE(0,1,true) CE(2,3,true) CE(4,5,false) CE(6,7,false)
    CE(8,9,true) CE(10,11,true) CE(12,13,false) CE(14,15,false)
    CE(0,4,true) CE(1,5,true) CE(2,6,true) CE(3,7,true)
    CE(8,12,false) CE(9,13,false) CE(10,14,false) CE(11,15,false)
    CE(0,2,true) CE(1,3,true) CE(4,6,true) CE(5,7,true)
    CE(8,10,false) CE(9,11,false) CE(12,14,false) CE(13,15,false)
    CE(0,1,true) CE(2,3,true) CE(4,5,true) CE(6,7,true)
    CE(8,9,false) CE(10,11,false) CE(12,13,false) CE(14,15,false)
    CE(0,8,true) CE(1,9,true) CE(2,10,true) CE(3,11,true)
    CE(4,12,true) CE(5,13,true) CE(6,14,true) CE(7,15,true)
    CE(0,4,true) CE(1,5,true) CE(2,6,true) CE(3,7,true)
    CE(8,12,true) CE(9,13,true) CE(10,14,true) CE(11,15,true)
    CE(0,2,true) CE(1,3,true) CE(4,6,true) CE(5,7,true)
    CE(8,10,true) CE(9,11,true) CE(12,14,true) CE(13,15,true)
    CE(0,1,true) CE(2,3,true) CE(4,5,true) CE(6,7,true)
    CE(8,9,true) CE(10,11,true) CE(12,13,true) CE(14,15,true)

    // spill sorted slots 1..15 to lane-private LDS columns
    float*  Wvp = &Vv[wv * 16 * 64];
    ushort* Wcp = &Vc[wv * 16 * 64];
    #define ST(s) { Wvp[s * 64 + lane] = v##s; Wcp[s * 64 + lane] = (ushort)c##s; }
    ST(1) ST(2) ST(3) ST(4) ST(5) ST(6) ST(7) ST(8)
    ST(9) ST(10) ST(11) ST(12) ST(13) ST(14) ST(15)
    #undef ST

    float hv = v0; int hc = c0;
    int n = 1;
    int* out = idx + (size_t)wave * KNN;
    #pragma unroll 1
    for (int it = 0; it < KNN; it++) {
        float sv = hv;
        #pragma unroll
        for (int off = 32; off > 0; off >>= 1)
            sv = fmaxf(sv, __shfl_xor(sv, off, 64));
        int cc = (hv == sv) ? hc : 0x7FFFFFFF;
        #pragma unroll
        for (int off = 32; off > 0; off >>= 1) {
            int oc = __shfl_xor(cc, off, 64);
            cc = (oc < cc) ? oc : cc;
        }
        if (lane == 0) out[it] = cc;
        int wc = __builtin_amdgcn_readfirstlane(cc);
        if (hc == wc) {              // winner lane (cols unique)
            if (n < 16) {
                hv = Wvp[n * 64 + lane];
                hc = (int)Wcp[n * 64 + lane];
            } else {
                hv = -3.4e38f;
                hc = -1;
            }
            n++;
        }
    }
}
#undef CE

// ---------------- fp32 GEMM (layer-1 uv only, K=3) --------------------------
__global__ void gemm_wt(const float* __restrict__ A, int lda,
                        const float* __restrict__ W, int ldw,
                        float* __restrict__ out, int ldo, int K) {
    __shared__ float As[16][68];
    __shared__ float Ws[16][68];
    int m0 = blockIdx.y * 64, n0 = blockIdx.x * 64;
    int tid = threadIdx.x;
    int tx = tid & 15, ty = tid >> 4;
    float acc[4][4] = {};
    for (int k0 = 0; k0 < K; k0 += 16) {
        for (int l = tid; l < 1024; l += 256) {
            int r = l >> 4, kk = l & 15, kg = k0 + kk;
            As[kk][r] = (kg < K) ? A[(size_t)(m0 + r) * lda + kg] : 0.f;
            Ws[kk][r] = (kg < K) ? W[(size_t)(n0 + r) * ldw + kg] : 0.f;
        }
        __syncthreads();
        #pragma unroll
        for (int kk = 0; kk < 16; kk++) {
            float4 a4 = *(const float4*)&As[kk][ty * 4];
            float4 w4 = *(const float4*)&Ws[kk][tx * 4];
            float a[4] = {a4.x, a4.y, a4.z, a4.w};
            float w[4] = {w4.x, w4.y, w4.z, w4.w};
            #pragma unroll
            for (int i = 0; i < 4; i++)
                #pragma unroll
                for (int j = 0; j < 4; j++) acc[i][j] += a[i] * w[j];
        }
        __syncthreads();
    }
    for (int i = 0; i < 4; i++) {
        int m = m0 + ty * 4 + i;
        for (int j = 0; j < 4; j++) {
            int n = n0 + tx * 4 + j;
            out[(size_t)m * ldo + n] = acc[i][j];
        }
    }
}

// ---------------- unified split-bf16 MFMA GEMM ([h|l] dedup) ----------------
// A,B stored [h|l] (KA = 2*Ch). Virtual K walk = 3 segments of Ch:
// seg0 (Ah,Bh), seg1 (Ah,Bl), seg2 (Al,Bh) — bit-identical to old K=3C walk.
// MODE 0: uv; MODE 2: final conv + fused transposed col stats.
// Bijective XCD swizzle (R12): each XCD owns a contiguous y-band.
template<int MODE>
__global__ __launch_bounds__(256, 2)
void gemm_mfma(const ushort* __restrict__ A, const ushort* __restrict__ Bw,
               int KA, int nkt, int Ch, int tps,
               float* __restrict__ out, int ldo, float* __restrict__ part) {
    __shared__ ushort lA[128 * 64];
    __shared__ ushort lB[128 * 64];
    int tid = threadIdx.x;
    int lane = tid & 63;
    int wid = tid >> 6;
    int wr = wid >> 1, wc = wid & 1;

    int nx = gridDim.x;
    int ypb = gridDim.y >> 3;
    int bid = blockIdx.y * nx + blockIdx.x;
    int xcd = bid & 7, pos = bid >> 3;
    int yy = xcd * ypb + pos / nx;
    int xx2 = pos % nx;
    int m0 = yy * 128, n0 = xx2 * 128;

    const ushort* pA = A + (size_t)m0 * KA;
    const ushort* pB = Bw + (size_t)n0 * KA;
    int rowu = tid >> 3, kcu = (tid & 7) * 8;

    f32x4 acc[4][4] = {};
    short8v ra[4], rb[4];
    #pragma unroll
    for (int j = 0; j < 4; j++) {
        int row = rowu + j * 32;
        ra[j] = *(const short8v*)(pA + (size_t)row * KA + kcu);
        rb[j] = *(const short8v*)(pB + (size_t)row * KA + kcu);
    }

    for (int kt = 0; kt < nkt; kt++) {
        __syncthreads();
        #pragma unroll
        for (int j = 0; j < 4; j++) {
            int row = rowu + j * 32;
            int off = (row * 128 + kcu * 2) ^ ((row & 7) << 4);
            *(short8v*)((char*)lA + off) = ra[j];
            *(short8v*)((char*)lB + off) = rb[j];
        }
        __syncthreads();
        if (kt < nkt - 1) {
            int kn = kt + 1;
            int seg = kn / tps, ktt = kn - seg * tps;
            int aoff = ((seg == 2) ? Ch : 0) + ktt * 64 + kcu;
            int boff = ((seg == 1) ? Ch : 0) + ktt * 64 + kcu;
            #pragma unroll
            for (int j = 0; j < 4; j++) {
                int row = rowu + j * 32;
                ra[j] = *(const short8v*)(pA + (size_t)row * KA + aoff);
                rb[j] = *(const short8v*)(pB + (size_t)row * KA + boff);
            }
        }
        #pragma unroll
        for (int ks = 0; ks < 2; ks++) {
            short8v af[4], bg[4];
            int kb2 = (ks * 32 + ((lane >> 4) << 3)) * 2;
            #pragma unroll
            for (int mb = 0; mb < 4; mb++) {
                int row = wr * 64 + mb * 16 + (lane & 15);
                int off = (row * 128 + kb2) ^ ((row & 7) << 4);
                af[mb] = *(const short8v*)((const char*)lA + off);
            }
            #pragma unroll
            for (int nb = 0; nb < 4; nb++) {
                int row = wc * 64 + nb * 16 + (lane & 15);
                int off = (row * 128 + kb2) ^ ((row & 7) << 4);
                bg[nb] = *(const short8v*)((const char*)lB + off);
            }
            #pragma unroll
            for (int mb = 0; mb < 4; mb++)
                #pragma unroll
                for (int nb = 0; nb < 4; nb++)
                    acc[mb][nb] = __builtin_amdgcn_mfma_f32_16x16x32_bf16(af[mb], bg[nb], acc[mb][nb], 0, 0, 0);
        }
    }

    int rbase = m0 + wr * 64 + ((lane >> 4) << 2);
    int cbase = n0 + wc * 64 + (lane & 15);

    if (MODE == 0) {
        #pragma unroll
        for (int mb = 0; mb < 4; mb++)
            #pragma unroll
            for (int nb = 0; nb < 4; nb++)
                #pragma unroll
                for (int r = 0; r < 4; r++)
                    out[(size_t)(rbase + mb * 16 + r) * ldo + cbase + nb * 16] = acc[mb][nb][r];
    } else {
        float* smS = (float*)lA;
        float* smQ = (float*)lB;
        __syncthreads();
        #pragma unroll
        for (int nb = 0; nb < 4; nb++) {
            float s = 0.f, q = 0.f;
            #pragma unroll
            for (int mb = 0; mb < 4; mb++)
                #pragma unroll
                for (int r = 0; r < 4; r++) {
                    float v = acc[mb][nb][r];
                    out[(size_t)(rbase + mb * 16 + r) * ldo + cbase + nb * 16] = v;
                    s += v; q += v * v;
                }
            s += __shfl_xor(s, 16, 64); s += __shfl_xor(s, 32, 64);
            q += __shfl_xor(q, 16, 64); q += __shfl_xor(q, 32, 64);
            if ((lane >> 4) == 0) {
                smS[wid * 64 + nb * 16 + lane] = s;
                smQ[wid * 64 + nb * 16 + lane] = q;
            }
        }
        __syncthreads();
        if (tid < 128) {
            int wcs = tid >> 6, c = tid & 63;
            float s = smS[wcs * 64 + c] + smS[(2 + wcs) * 64 + c];
            float q = smQ[wcs * 64 + c] + smQ[(2 + wcs) * 64 + c];
            int col = n0 + wcs * 64 + c;
            part[(size_t)col * 128 + yy] = s;
            part[131072 + (size_t)col * 128 + yy] = q;
        }
    }
}

// ---------------- gather neighbors, per-(p,o) max/min, per-channel stats ----
// int4-preloaded indices; gathers issued 4 at a time (R19, bit-identical).
__global__ void gather_stats(const float* __restrict__ uv, const int* __restrict__ idx, int O,
                             float* __restrict__ ymax, float* __restrict__ ymin,
                             double* __restrict__ part, int ppb) {
    __shared__ double sd[256], sd2[256];
    int t = threadIdx.x;
    int R = 256 / O;
    int o = t % O;
    int q = t / O;
    double s = 0.0, s2 = 0.0;
    int p0 = blockIdx.x * ppb;
    int ld = 2 * O;
    for (int lp = q; lp < ppb; lp += R) {
        int p = p0 + lp;
        int base = (p >> 10) << 10;
        const int* ir = idx + (size_t)p * KNN;
        int4 i0 = *(const int4*)(ir);
        int4 i1 = *(const int4*)(ir + 4);
        int4 i2 = *(const int4*)(ir + 8);
        int4 i3 = *(const int4*)(ir + 12);
        int4 i4 = *(const int4*)(ir + 16);
        float v = uv[(size_t)p * ld + O + o];
        float mx = -3.4e38f, mn = 3.4e38f;
        #define G4(iv) { \
            float u0_ = uv[(size_t)(base + (iv).x) * ld + o]; \
            float u1_ = uv[(size_t)(base + (iv).y) * ld + o]; \
            float u2_ = uv[(size_t)(base + (iv).z) * ld + o]; \
            float u3_ = uv[(size_t)(base + (iv).w) * ld + o]; \
            float y0_ = u0_ + v, y1_ = u1_ + v, y2_ = u2_ + v, y3_ = u3_ + v; \
            mx = fmaxf(mx, y0_); mn = fminf(mn, y0_); s += (double)y0_; s2 += (double)y0_ * (double)y0_; \
            mx = fmaxf(mx, y1_); mn = fminf(mn, y1_); s += (double)y1_; s2 += (double)y1_ * (double)y1_; \
            mx = fmaxf(mx, y2_); mn = fminf(mn, y2_); s += (double)y2_; s2 += (double)y2_ * (double)y2_; \
            mx = fmaxf(mx, y3_); mn = fminf(mn, y3_); s += (double)y3_; s2 += (double)y3_ * (double)y3_; }
        G4(i0) G4(i1) G4(i2) G4(i3) G4(i4)
        #undef G4
        ymax[(size_t)p * O + o] = mx;
        ymin[(size_t)p * O + o] = mn;
    }
    sd[t] = s; sd2[t] = s2;
    __syncthreads();
    if (t < O) {
        double a = 0.0, a2 = 0.0;
        for (int qq = 0; qq < R; qq++) { a += sd[qq * O + t]; a2 += sd2[qq * O + t]; }
        part[(size_t)t * 1024 + blockIdx.x] = a;
        part[(size_t)(O + t) * 1024 + blockIdx.x] = a2;
    }
}

// ---------------- parallel finalize: one block per channel ------------------
__global__ void finalize_t(const double* __restrict__ part, int O,
                           const float* __restrict__ g, const float* __restrict__ bt,
                           float* __restrict__ scale, float* __restrict__ shift, double invCount) {
    __shared__ double sa[4], sb[4];
    int o = blockIdx.x;
    int t = threadIdx.x;
    int lane = t & 63, w = t >> 6;
    const double* ps = part + (size_t)o * 1024;
    const double* pq = part + (size_t)(O + o) * 1024;
    double s = 0.0, s2 = 0.0;
    #pragma unroll
    for (int b = 0; b < 4; b++) { s += ps[t + b * 256]; s2 += pq[t + b * 256]; }
    #pragma unroll
    for (int off = 32; off > 0; off >>= 1) { s += __shfl_xor(s, off, 64); s2 += __shfl_xor(s2, off, 64); }
    if (lane == 0) { sa[w] = s; sb[w] = s2; }
    __syncthreads();
    if (t == 0) {
        s = sa[0] + sa[1] + sa[2] + sa[3];
        s2 = sb[0] + sb[1] + sb[2] + sb[3];
        double mean = s * invCount;
        double var = s2 * invCount - mean * mean;
        if (var < 0.0) var = 0.0;
        float sc = (float)(1.0 / sqrt(var + 1e-5)) * g[o];
        scale[o] = sc;
        shift[o] = bt[o] - (float)mean * sc;
    }
}

// ---------------- parallel finalize for float partials (final conv) ---------
__global__ void finalize_f_t(const float* __restrict__ part,
                             const float* __restrict__ g, const float* __restrict__ bt,
                             float* __restrict__ scale, float* __restrict__ shift, double invCount) {
    __shared__ double sa[2], sb[2];
    int o = blockIdx.x;
    int t = threadIdx.x;   // 128 threads
    int lane = t & 63, w = t >> 6;
    double s  = (double)part[(size_t)o * 128 + t];
    double s2 = (double)part[131072 + (size_t)o * 128 + t];
    #pragma unroll
    for (int off = 32; off > 0; off >>= 1) { s += __shfl_xor(s, off, 64); s2 += __shfl_xor(s2, off, 64); }
    if (lane == 0) { sa[w] = s; sb[w] = s2; }
    __syncthreads();
    if (t == 0) {
        s = sa[0] + sa[1];
        s2 = sb[0] + sb[1];
        double mean = s * invCount;
        double var = s2 * invCount - mean * mean;
        if (var < 0.0) var = 0.0;
        float sc = (float)(1.0 / sqrt(var + 1e-5)) * g[o];
        scale[o] = sc;
        shift[o] = bt[o] - (float)mean * sc;
    }
}

// ---------------- edge conv epilogue: BN + leaky, float4 --------------------
__global__ void apply_edge(const float* __restrict__ ymax, const float* __restrict__ ymin,
                           const float* __restrict__ scale, const float* __restrict__ shift,
                           float* __restrict__ xcat, int O, int off) {
    int i = blockIdx.x * 256 + threadIdx.x;
    int oq = O >> 2;
    if (i >= P_ * oq) return;
    int p = i / oq, o4 = (i % oq) * 4;
    float4 mx = *(const float4*)&ymax[(size_t)p * O + o4];
    float4 mn = *(const float4*)&ymin[(size_t)p * O + o4];
    float4 sc = *(const float4*)&scale[o4];
    float4 sh = *(const float4*)&shift[o4];
    float4 r;
    float y0 = (sc.x >= 0.f) ? mx.x : mn.x;
    float y1 = (sc.y >= 0.f) ? mx.y : mn.y;
    float y2 = (sc.z >= 0.f) ? mx.z : mn.z;
    float y3 = (sc.w >= 0.f) ? mx.w : mn.w;
    float a0 = y0 * sc.x + sh.x, a1 = y1 * sc.y + sh.y;
    float a2 = y2 * sc.z + sh.z, a3 = y3 * sc.w + sh.w;
    r.x = LEAKY(a0); r.y = LEAKY(a1); r.z = LEAKY(a2); r.w = LEAKY(a3);
    *(float4*)&xcat[(size_t)p * 512 + off + o4] = r;
}

// ---------------- pool partials: grid (16b, 16og, 4nz) = 1024 blocks --------
__global__ void pool_part(const float* __restrict__ h, const float* __restrict__ scale,
                          const float* __restrict__ shift,
                          float* __restrict__ pmax, double* __restrict__ psum) {
    __shared__ float smax[256];
    __shared__ double ssum[256];
    int b = blockIdx.x, og = blockIdx.y, nz = blockIdx.z;
    int t = threadIdx.x;
    int o = og * 64 + (t & 63);
    int ch = t >> 6;
    float sc = scale[o], sh = shift[o];
    float mx = -3.4e38f;
    double sm = 0.0;
    int n0 = nz * 256 + ch * 64;
    #pragma unroll 4
    for (int n = n0; n < n0 + 64; n++) {
        float y = h[((size_t)b * N_ + n) * 1024 + o] * sc + sh;
        y = LEAKY(y);
        mx = fmaxf(mx, y);
        sm += (double)y;
    }
    smax[t] = mx; ssum[t] = sm;
    __syncthreads();
    if (t < 64) {
        for (int c = 1; c < 4; c++) { mx = fmaxf(mx, smax[c * 64 + t]); sm += ssum[c * 64 + t]; }
        size_t pi = ((size_t)b * 4 + nz) * 1024 + o;
        pmax[pi] = mx;
        psum[pi] = sm;
    }
}

// ---------------- pool final: reduce 4 nz partials -> max / mean ------------
__global__ void pool_fin(const float* __restrict__ pmax, const double* __restrict__ psum,
                         float* __restrict__ pooled) {
    int b = blockIdx.x, og = blockIdx.y;
    int o = og * 256 + threadIdx.x;
    size_t base = (size_t)b * 4 * 1024 + o;
    float mx = pmax[base];
    double sm = psum[base];
    #pragma unroll
    for (int nz = 1; nz < 4; nz++) {
        mx = fmaxf(mx, pmax[base + nz * 1024]);
        sm += psum[base + nz * 1024];
    }
    pooled[(size_t)b * 2048 + o] = mx;
    pooled[(size_t)b * 2048 + 1024 + o] = (float)(sm * (1.0 / N_));
}

// ---------------- small FC: one wave per output -----------------------------
__global__ void fc_kernel(const float* __restrict__ in, int ldi,
                          const float* __restrict__ w, int ldw,
                          const float* __restrict__ bias,
                          float* __restrict__ out, int M, int Nn, int K) {
    int gw = (blockIdx.x * 256 + threadIdx.x) >> 6;
    int lane = threadIdx.x & 63;
    if (gw >= M * Nn) return;
    int m = gw / Nn, n = gw % Nn;
    const float* a = in + (size_t)m * ldi;
    const float* ww = w + (size_t)n * ldw;
    float s = 0.f;
    for (int kk = lane; kk < K; kk += 64) s += a[kk] * ww[kk];
    #pragma unroll
    for (int off = 32; off > 0; off >>= 1) s += __shfl_xor(s, off, 64);
    if (lane == 0) out[(size_t)m * Nn + n] = s + bias[n];
}

// ---------------- BN over batch axis (M=16) + leaky, in place ---------------
__global__ void bn_rows(float* __restrict__ z, int M, int O,
                        const float* __restrict__ g, const float* __restrict__ bt) {
    int o = blockIdx.x * 256 + threadIdx.x;
    if (o >= O) return;
    double s = 0.0, s2 = 0.0;
    for (int m = 0; m < M; m++) {
        float y = z[(size_t)m * O + o];
        s += (double)y; s2 += (double)y * (double)y;
    }
    double mean = s / M;
    double var = s2 / M - mean * mean;
    if (var < 0.0) var = 0.0;
    float sc = (float)(1.0 / sqrt(var + 1e-5)) * g[o];
    float sh = bt[o] - (float)mean * sc;
    for (int m = 0; m < M; m++) {
        float y = z[(size_t)m * O + o] * sc + sh;
        z[(size_t)m * O + o] = LEAKY(y);
    }
}

extern "C" void kernel_launch(void* const* d_in, const int* in_sizes, int n_in,
                              void* d_out, int out_size, void* d_ws, size_t ws_size,
                              hipStream_t stream) {
    const float* cloud = (const float*)d_in[0];
    const float* wf  = (const float*)d_in[17];
    const float* gf  = (const float*)d_in[19];
    const float* btf = (const float*)d_in[20];
    const float* wl1 = (const float*)d_in[21];
    const float* bl1 = (const float*)d_in[22];
    const float* gl1 = (const float*)d_in[23];
    const float* btl1= (const float*)d_in[24];
    const float* wl2 = (const float*)d_in[25];
    const float* bl2 = (const float*)d_in[26];
    const float* gl2 = (const float*)d_in[27];
    const float* btl2= (const float*)d_in[28];
    const float* wl3 = (const float*)d_in[29];
    const float* bl3 = (const float*)d_in[30];

    // workspace layout (bytes)
    const size_t OFF_XCAT  = 0;                        // 33554432
    const size_t OFF_UV    = 33554432;                 // 33554432 (A2 [h|l] = 32MB fits exactly)
    const size_t OFF_YMAX  = 67108864;                 // 16777216 (xA [h|l] <= 8.4MB)
    const size_t OFF_YMIN  = 83886080;                 // 16777216 (B2 alias, 2MB)
    const size_t OFF_DIST  = 100663296;                // 67108864 (aliased as hraw)
    const size_t OFF_IDX   = 167772160;                // 1310720
    const size_t OFF_XX    = 169082880;                // 65536
    const size_t OFF_W2    = 169148416;                // 524288
    const size_t OFF_PART  = 169676800;                // 4194304: part doubles / partf / pool partials
    const size_t OFF_SCALE = 173871104;                // 4096
    const size_t OFF_SHIFT = 173875200;                // 4096
    const size_t OFF_POOL  = 173879296;                // 131072
    const size_t OFF_Z1    = 174010368;                // 32768
    const size_t OFF_Z2    = 174043136;                // 16384
    const size_t TOTAL     = 174059520;
    if (ws_size < TOTAL) return;

    char* ws = (char*)d_ws;
    float* xcat  = (float*)(ws + OFF_XCAT);
    float* uv    = (float*)(ws + OFF_UV);
    float* ymax  = (float*)(ws + OFF_YMAX);
    float* ymin  = (float*)(ws + OFF_YMIN);
    float* dist  = (float*)(ws + OFF_DIST);
    float* hraw  = (float*)(ws + OFF_DIST);
    ushort* A2   = (ushort*)(ws + OFF_UV);     // final conv A [h|l]: 32MB
    ushort* B2   = (ushort*)(ws + OFF_YMIN);   // final conv B [h|l]: 2MB
    ushort* xA   = (ushort*)(ws + OFF_YMAX);   // per-layer split A [h|l]: ≤8.4MB
    ushort* WB2  = (ushort*)(ws + OFF_PART);   // per-layer split of W2 [h|l]: ≤256KB
    int*   idx   = (int*)  (ws + OFF_IDX);
    float* xx    = (float*)(ws + OFF_XX);
    float* W2    = (float*)(ws + OFF_W2);
    double* part = (double*)(ws + OFF_PART);
    float* partf = (float*)(ws + OFF_PART);
    float* ppmax = (float*)(ws + OFF_PART + 2097152);   // 256KB
    double* ppsum= (double*)(ws + OFF_PART + 2359296);  // 512KB
    float* scale = (float*)(ws + OFF_SCALE);
    float* shift = (float*)(ws + OFF_SHIFT);
    float* pooled= (float*)(ws + OFF_POOL);
    float* z1    = (float*)(ws + OFF_Z1);
    float* z2    = (float*)(ws + OFF_Z2);

    const int Cs[4]   = {3, 64, 64, 128};
    const int Os[4]   = {64, 64, 128, 256};
    const int offs[4] = {0, 64, 128, 256};

    for (int L = 0; L < 4; L++) {
        int C = Cs[L], O = Os[L];
        const float* w  = (const float*)d_in[1 + 4 * L];
        const float* g  = (const float*)d_in[3 + 4 * L];
        const float* bt = (const float*)d_in[4 + 4 * L];
        const float* x  = (L == 0) ? cloud : (xcat + offs[L - 1]);
        int lda = (L == 0) ? 3 : 512;

        sqnorm<<<(P_ + 255) / 256, 256, 0, stream>>>(x, lda, C, xx);
        dist_kernel<<<dim3(136, 16), 256, 0, stream>>>(x, lda, C, xx, dist);
        topk_kernel<<<P_ / 4, 256, 0, stream>>>(dist, idx);

        if (L == 0) {
            prep_w2<<<(2 * O * C + 255) / 256, 256, 0, stream>>>(w, W2, O, C);
            gemm_wt<<<dim3(2 * O / 64, P_ / 64), 256, 0, stream>>>(x, lda, W2, C, uv, 2 * O, C);
        } else {
            int nkt = 3 * C / 64, tps = C / 64;
            conv_split<<<(P_ * (C / 4) + 255) / 256, 256, 0, stream>>>(x, lda, C, P_, xA);
            prep_w2_split<<<(2 * O * (C / 4) + 255) / 256, 256, 0, stream>>>(w, WB2, O, C);
            gemm_mfma<0><<<dim3(2 * O / 128, 128), 256, 0, stream>>>(xA, WB2, 2 * C, nkt, C, tps, uv, 2 * O, nullptr);
        }

        gather_stats<<<1024, 256, 0, stream>>>(uv, idx, O, ymax, ymin, part, 16);
        finalize_t<<<O, 256, 0, stream>>>(part, O, g, bt, scale, shift, 1.0 / ((double)P_ * KNN));
        apply_edge<<<(P_ * (O / 4) + 255) / 256, 256, 0, stream>>>(ymax, ymin, scale, shift, xcat, O, offs[L]);
    }

    // final 1x1 conv via dedup split-bf16 MFMA GEMM with fused col stats
    conv_split<<<(P_ * 128 + 255) / 256, 256, 0, stream>>>(xcat, 512, 512, P_, A2);
    conv_split<<<(1024 * 128 + 255) / 256, 256, 0, stream>>>(wf, 512, 512, 1024, B2);
    gemm_mfma<2><<<dim3(8, 128), 256, 0, stream>>>(A2, B2, 1024, 24, 512, 8, hraw, 1024, partf);

    finalize_f_t<<<1024, 128, 0, stream>>>(partf, gf, btf, scale, shift, 1.0 / (double)P_);
    pool_part<<<dim3(16, 16, 4), 256, 0, stream>>>(hraw, scale, shift, ppmax, ppsum);
    pool_fin<<<dim3(16, 4), 256, 0, stream>>>(ppmax, ppsum, pooled);

    // MLP head
    fc_kernel<<<(16 * 512 * 64) / 256, 256, 0, stream>>>(pooled, 2048, wl1, 2048, bl1, z1, 16, 512, 2048);
    bn_rows<<<2, 256, 0, stream>>>(z1, 16, 512, gl1, btl1);
    fc_kernel<<<(16 * 256 * 64) / 256, 256, 0, stream>>>(z1, 512, wl2, 512, bl2, z2, 16, 256, 512);
    bn_rows<<<1, 256, 0, stream>>>(z2, 16, 256, gl2, btl2);
    fc_kernel<<<(16 * 40 * 64 + 255) / 256, 256, 0, stream>>>(z2, 256, wl3, 256, bl3, (float*)d_out, 16, 40, 256);
}